// Round 1
// baseline (442.729 us; speedup 1.0000x reference)
//
#include <hip/hip_runtime.h>

#define HH_ 128
#define WW_ 128
#define LL_ (HH_*WW_)     // 16384
#define NH 8
#define DHD 12
#define KD 256
#define BB_ 2
#define NROW (BB_*LL_)    // 32768

__device__ __forceinline__ float4 ld4(const float* p) {
    return *reinterpret_cast<const float4*>(p);
}

// ---------------- K1: qkv = x @ Wqkv  (32768x96 @ 96x288) ----------------
__global__ __launch_bounds__(256) void k_qkv(const float* __restrict__ x,
                                             const float* __restrict__ Wq,
                                             float* __restrict__ qkv) {
    __shared__ float xT[96][36];      // [k][row], padded for b128 conflict-free
    __shared__ float Wl[32*288];
    const int tid = threadIdx.x;
    const int r0 = blockIdx.x * 32;
    for (int i = tid; i < 32*96; i += 256) {
        int r = i / 96, c = i % 96;
        xT[c][r] = x[(r0 + r)*96 + c];
    }
    const int cg = tid & 31, rg = tid >> 5;
    const int c0 = cg*9, rr = rg*4;
    float acc[4][9];
#pragma unroll
    for (int a = 0; a < 4; ++a)
#pragma unroll
        for (int j = 0; j < 9; ++j) acc[a][j] = 0.f;
    for (int kc = 0; kc < 3; ++kc) {
        __syncthreads();
        for (int i = tid; i < 32*288; i += 256) Wl[i] = Wq[kc*32*288 + i];
        __syncthreads();
#pragma unroll 2
        for (int k = 0; k < 32; ++k) {
            float4 a4 = ld4(&xT[kc*32 + k][rr]);
            float av[4] = {a4.x, a4.y, a4.z, a4.w};
#pragma unroll
            for (int j = 0; j < 9; ++j) {
                float w = Wl[k*288 + c0 + j];
#pragma unroll
                for (int a = 0; a < 4; ++a) acc[a][j] = fmaf(av[a], w, acc[a][j]);
            }
        }
    }
#pragma unroll
    for (int a = 0; a < 4; ++a)
#pragma unroll
        for (int j = 0; j < 9; ++j)
            qkv[(r0 + rr + a)*288 + c0 + j] = acc[a][j];
}

// ---------------- K2a: depthwise 5x5, pad 2 (channels-last) ----------------
__global__ __launch_bounds__(256) void k_dw5(const float* __restrict__ xin,
                                             const float* __restrict__ w,
                                             const float* __restrict__ bias,
                                             float* __restrict__ out) {
    __shared__ float wl[25][96];
    const int tid = threadIdx.x;
    for (int i = tid; i < 25*96; i += 256) {
        int c = i / 25, t = i % 25;
        wl[t][c] = w[i];
    }
    __syncthreads();
    const int c4 = (tid & 7)*4;
    const int px = tid >> 3;
    const int pix0 = blockIdx.x * 32;
    const int b = pix0 >> 14;
    const int y = (pix0 & 16383) >> 7;
    const int xx = (pix0 & 127) + px;
    float4 acc[3];
#pragma unroll
    for (int ch = 0; ch < 3; ++ch) { acc[ch].x=0.f; acc[ch].y=0.f; acc[ch].z=0.f; acc[ch].w=0.f; }
#pragma unroll
    for (int iy = 0; iy < 5; ++iy) {
        int y2 = y + iy - 2;
        if (y2 < 0 || y2 >= HH_) continue;
#pragma unroll
        for (int ix = 0; ix < 5; ++ix) {
            int x2 = xx + ix - 2;
            if (x2 < 0 || x2 >= WW_) continue;
            const float* src = xin + ((b << 14) + y2*WW_ + x2)*96;
            const float* wt = &wl[iy*5 + ix][0];
#pragma unroll
            for (int ch = 0; ch < 3; ++ch) {
                float4 xv = ld4(src + ch*32 + c4);
                float4 wv = ld4(wt + ch*32 + c4);
                acc[ch].x = fmaf(xv.x, wv.x, acc[ch].x);
                acc[ch].y = fmaf(xv.y, wv.y, acc[ch].y);
                acc[ch].z = fmaf(xv.z, wv.z, acc[ch].z);
                acc[ch].w = fmaf(xv.w, wv.w, acc[ch].w);
            }
        }
    }
    float* dst = out + (long)(pix0 + px)*96;
#pragma unroll
    for (int ch = 0; ch < 3; ++ch) {
        float4 bv = ld4(bias + ch*32 + c4);
        float4 r;
        r.x = acc[ch].x + bv.x; r.y = acc[ch].y + bv.y;
        r.z = acc[ch].z + bv.z; r.w = acc[ch].w + bv.w;
        *reinterpret_cast<float4*>(dst + ch*32 + c4) = r;
    }
}

// ---------------- K2b: depthwise 7x7, dilation 3, pad 9 ----------------
__global__ __launch_bounds__(256) void k_dw7(const float* __restrict__ xin,
                                             const float* __restrict__ w,
                                             const float* __restrict__ bias,
                                             float* __restrict__ out) {
    __shared__ float wl[49][96];
    const int tid = threadIdx.x;
    for (int i = tid; i < 49*96; i += 256) {
        int c = i / 49, t = i % 49;
        wl[t][c] = w[i];
    }
    __syncthreads();
    const int c4 = (tid & 7)*4;
    const int px = tid >> 3;
    const int pix0 = blockIdx.x * 32;
    const int b = pix0 >> 14;
    const int y = (pix0 & 16383) >> 7;
    const int xx = (pix0 & 127) + px;
    float4 acc[3];
#pragma unroll
    for (int ch = 0; ch < 3; ++ch) { acc[ch].x=0.f; acc[ch].y=0.f; acc[ch].z=0.f; acc[ch].w=0.f; }
#pragma unroll
    for (int iy = 0; iy < 7; ++iy) {
        int y2 = y + iy*3 - 9;
        if (y2 < 0 || y2 >= HH_) continue;
#pragma unroll
        for (int ix = 0; ix < 7; ++ix) {
            int x2 = xx + ix*3 - 9;
            if (x2 < 0 || x2 >= WW_) continue;
            const float* src = xin + ((b << 14) + y2*WW_ + x2)*96;
            const float* wt = &wl[iy*7 + ix][0];
#pragma unroll
            for (int ch = 0; ch < 3; ++ch) {
                float4 xv = ld4(src + ch*32 + c4);
                float4 wv = ld4(wt + ch*32 + c4);
                acc[ch].x = fmaf(xv.x, wv.x, acc[ch].x);
                acc[ch].y = fmaf(xv.y, wv.y, acc[ch].y);
                acc[ch].z = fmaf(xv.z, wv.z, acc[ch].z);
                acc[ch].w = fmaf(xv.w, wv.w, acc[ch].w);
            }
        }
    }
    float* dst = out + (long)(pix0 + px)*96;
#pragma unroll
    for (int ch = 0; ch < 3; ++ch) {
        float4 bv = ld4(bias + ch*32 + c4);
        float4 r;
        r.x = acc[ch].x + bv.x; r.y = acc[ch].y + bv.y;
        r.z = acc[ch].z + bv.z; r.w = acc[ch].w + bv.w;
        *reinterpret_cast<float4*>(dst + ch*32 + c4) = r;
    }
}

// ------- K2c: a3 = a2 @ w1^T + b1 ; vf = x * a3 * v  (v = qkv slice 2) -------
__global__ __launch_bounds__(256) void k_pw_gate(const float* __restrict__ a2,
        const float* __restrict__ w1, const float* __restrict__ b1,
        const float* __restrict__ xin, const float* __restrict__ qkv,
        float* __restrict__ vf) {
    __shared__ float aT[96][36];
    __shared__ float wT[96][100];    // wT[ci][o] = w1[o*96+ci]
    const int tid = threadIdx.x;
    const int r0 = blockIdx.x * 32;
    for (int i = tid; i < 32*96; i += 256) {
        int r = i / 96, c = i % 96;
        aT[c][r] = a2[(r0 + r)*96 + c];
    }
    for (int i = tid; i < 96*96; i += 256) {
        int o = i / 96, ci = i % 96;
        wT[ci][o] = w1[i];
    }
    __syncthreads();
    const int cg = tid & 31, rg = tid >> 5;
    const int c0 = cg*3, rr = rg*4;
    float acc[4][3];
#pragma unroll
    for (int r = 0; r < 4; ++r)
#pragma unroll
        for (int j = 0; j < 3; ++j) acc[r][j] = 0.f;
#pragma unroll 4
    for (int k = 0; k < 96; ++k) {
        float4 a4 = ld4(&aT[k][rr]);
        float av[4] = {a4.x, a4.y, a4.z, a4.w};
#pragma unroll
        for (int j = 0; j < 3; ++j) {
            float w = wT[k][c0 + j];
#pragma unroll
            for (int r = 0; r < 4; ++r) acc[r][j] = fmaf(av[r], w, acc[r][j]);
        }
    }
#pragma unroll
    for (int r = 0; r < 4; ++r) {
        int row = r0 + rr + r;
#pragma unroll
        for (int j = 0; j < 3; ++j) {
            int c = c0 + j;
            float g = acc[r][j] + b1[c];
            vf[row*96 + c] = xin[row*96 + c] * qkv[row*288 + 192 + c] * g;
        }
    }
}

// ------- K3a: partial E-reduction: part[b][jc][m][kk][c] over 128-row chunk -------
// grid.x = b*256 + jc*2 + m  (2*128*2 = 512 blocks), thread = kk
__global__ __launch_bounds__(256) void k_ered(const float* __restrict__ E,
        const float* __restrict__ qkv, const float* __restrict__ vf,
        float* __restrict__ part) {
    __shared__ float El[64][256];
    const int tid = threadIdx.x;
    const int bid = blockIdx.x;
    const int m  = bid & 1;
    const int jc = (bid >> 1) & 127;
    const int b  = bid >> 8;
    const int j0 = jc * 128;
    float acc[12][8] = {};
    for (int js = 0; js < 2; ++js) {
        __syncthreads();
        for (int i = tid; i < 64*256; i += 256)
            El[i >> 8][i & 255] = E[(j0 + (js << 6) + (i >> 8))*256 + (i & 255)];
        __syncthreads();
        for (int j = 0; j < 64; ++j) {
            float e = El[j][tid];
            int row = b*LL_ + j0 + (js << 6) + j;
            const float* xr = (m == 0) ? (qkv + row*288 + 96) : (vf + row*96);
#pragma unroll
            for (int cg = 0; cg < 12; ++cg) {
                float4 xa = ld4(xr + cg*8);
                float4 xb = ld4(xr + cg*8 + 4);
                acc[cg][0] = fmaf(e, xa.x, acc[cg][0]);
                acc[cg][1] = fmaf(e, xa.y, acc[cg][1]);
                acc[cg][2] = fmaf(e, xa.z, acc[cg][2]);
                acc[cg][3] = fmaf(e, xa.w, acc[cg][3]);
                acc[cg][4] = fmaf(e, xb.x, acc[cg][4]);
                acc[cg][5] = fmaf(e, xb.y, acc[cg][5]);
                acc[cg][6] = fmaf(e, xb.z, acc[cg][6]);
                acc[cg][7] = fmaf(e, xb.w, acc[cg][7]);
            }
        }
    }
    float* dst = part + ((((b*128 + jc)*2 + m)*256 + tid)*96);
#pragma unroll
    for (int cg = 0; cg < 12; ++cg)
#pragma unroll
        for (int i = 0; i < 8; ++i) dst[cg*8 + i] = acc[cg][i];
}

// ------- K3b: reduce partials -> kp[b][h][kk][d], vp[b][h][kk][d] -------
__global__ __launch_bounds__(256) void k_ered_fin(const float* __restrict__ part,
        float* __restrict__ kp, float* __restrict__ vp) {
    const int idx = blockIdx.x*256 + threadIdx.x;  // 2*2*256*96 = 98304
    const int c  = idx % 96;
    const int kk = (idx / 96) % 256;
    const int m  = (idx / (96*256)) % 2;
    const int b  = idx / (96*256*2);
    float s = 0.f;
    const long off = ((long)((b*128)*2 + m)*256 + kk)*96 + c;
    for (int jc = 0; jc < 128; ++jc)
        s += part[off + (long)jc*(2*256*96)];
    const int h = c / DHD, d = c % DHD;
    float* dst = (m == 0) ? kp : vp;
    dst[((b*NH + h)*256 + kk)*DHD + d] = s;
}

// ------- K4: fused attention (qk'^T -> softmax -> @v') + W0 epilogue -------
__global__ __launch_bounds__(256) void k_attn(const float* __restrict__ qkv,
        const float* __restrict__ kp, const float* __restrict__ vp,
        const float* __restrict__ W0, float* __restrict__ out) {
    __shared__ float qT[96][36];
    __shared__ float kvbuf[2*12*260];   // kpT | vpT ; reused for W0 tiles
    __shared__ float oT[96][36];
    const int tid = threadIdx.x;
    const int r0 = blockIdx.x * 32;
    const int b = r0 >> 14;
    for (int i = tid; i < 32*96; i += 256) {
        int r = i / 96, c = i % 96;
        qT[c][r] = qkv[(r0 + r)*288 + c];
    }
    const int kg = tid & 31, rg = tid >> 5;
    const int rr = rg*4;
    const float scale = 0.28867513459481287f;  // 1/sqrt(12)
    float* kpT = kvbuf;
    float* vpT = kvbuf + 12*260;
    for (int h = 0; h < NH; ++h) {
        __syncthreads();
        for (int i = tid; i < 256*12; i += 256) {
            int kk = i / 12, d = i % 12;
            int src = ((b*NH + h)*256 + kk)*DHD + d;
            kpT[d*260 + kk] = kp[src];
            vpT[d*260 + kk] = vp[src];
        }
        __syncthreads();
        float s[4][8];
#pragma unroll
        for (int r = 0; r < 4; ++r)
#pragma unroll
            for (int j = 0; j < 8; ++j) s[r][j] = 0.f;
#pragma unroll 4
        for (int d = 0; d < 12; ++d) {
            float4 qa = ld4(&qT[h*12 + d][rr]);
            float qv[4] = {qa.x, qa.y, qa.z, qa.w};
            float4 ka = ld4(&kpT[d*260 + kg*8]);
            float4 kb = ld4(&kpT[d*260 + kg*8 + 4]);
            float kvv[8] = {ka.x, ka.y, ka.z, ka.w, kb.x, kb.y, kb.z, kb.w};
#pragma unroll
            for (int r = 0; r < 4; ++r)
#pragma unroll
                for (int j = 0; j < 8; ++j)
                    s[r][j] = fmaf(qv[r], kvv[j], s[r][j]);
        }
        float p[4][8];
#pragma unroll
        for (int r = 0; r < 4; ++r) {
            float mx = s[r][0];
#pragma unroll
            for (int j = 1; j < 8; ++j) mx = fmaxf(mx, s[r][j]);
#pragma unroll
            for (int off = 16; off >= 1; off >>= 1)
                mx = fmaxf(mx, __shfl_xor(mx, off, 64));
            float msc = mx * scale;
            float ssum = 0.f;
#pragma unroll
            for (int j = 0; j < 8; ++j) {
                p[r][j] = __expf(fmaf(s[r][j], scale, -msc));
                ssum += p[r][j];
            }
#pragma unroll
            for (int off = 16; off >= 1; off >>= 1)
                ssum += __shfl_xor(ssum, off, 64);
            float rinv = 1.0f / ssum;
#pragma unroll
            for (int j = 0; j < 8; ++j) p[r][j] *= rinv;
        }
#pragma unroll 4
        for (int d = 0; d < 12; ++d) {
            float4 va = ld4(&vpT[d*260 + kg*8]);
            float4 vb = ld4(&vpT[d*260 + kg*8 + 4]);
            float vv[8] = {va.x, va.y, va.z, va.w, vb.x, vb.y, vb.z, vb.w};
            float po[4];
#pragma unroll
            for (int r = 0; r < 4; ++r) {
                float t = 0.f;
#pragma unroll
                for (int j = 0; j < 8; ++j) t = fmaf(p[r][j], vv[j], t);
                po[r] = t;
            }
#pragma unroll
            for (int off = 16; off >= 1; off >>= 1) {
#pragma unroll
                for (int r = 0; r < 4; ++r) po[r] += __shfl_xor(po[r], off, 64);
            }
            if (kg == 0) {
#pragma unroll
                for (int r = 0; r < 4; ++r) oT[h*12 + d][rr + r] = po[r];
            }
        }
    }
    // epilogue: out(rows x 96) = o @ W0, W0 staged 48 rows at a time in kvbuf
    const int c0 = kg*3;
    float acc[4][3];
#pragma unroll
    for (int r = 0; r < 4; ++r)
#pragma unroll
        for (int j = 0; j < 3; ++j) acc[r][j] = 0.f;
    for (int half = 0; half < 2; ++half) {
        __syncthreads();
        for (int i = tid; i < 48*96; i += 256)
            kvbuf[i] = W0[half*48*96 + i];
        __syncthreads();
#pragma unroll 2
        for (int k = 0; k < 48; ++k) {
            float4 o4 = ld4(&oT[half*48 + k][rr]);
            float ov[4] = {o4.x, o4.y, o4.z, o4.w};
#pragma unroll
            for (int j = 0; j < 3; ++j) {
                float wv = kvbuf[k*96 + c0 + j];
#pragma unroll
                for (int r = 0; r < 4; ++r)
                    acc[r][j] = fmaf(ov[r], wv, acc[r][j]);
            }
        }
    }
#pragma unroll
    for (int r = 0; r < 4; ++r)
#pragma unroll
        for (int j = 0; j < 3; ++j)
            out[(r0 + rr + r)*96 + c0 + j] = acc[r][j];
}

extern "C" void kernel_launch(void* const* d_in, const int* in_sizes, int n_in,
                              void* d_out, int out_size, void* d_ws, size_t ws_size,
                              hipStream_t stream) {
    (void)in_sizes; (void)n_in; (void)out_size; (void)ws_size;
    const float* x    = (const float*)d_in[0];
    const float* Wqkv = (const float*)d_in[1];
    const float* W0   = (const float*)d_in[2];
    const float* E    = (const float*)d_in[3];
    const float* c0w  = (const float*)d_in[4];
    const float* c0b  = (const float*)d_in[5];
    const float* cspw = (const float*)d_in[6];
    const float* cspb = (const float*)d_in[7];
    const float* c1w  = (const float*)d_in[8];
    const float* c1b  = (const float*)d_in[9];
    float* out = (float*)d_out;
    float* ws  = (float*)d_ws;

    // workspace layout (floats); part overlaps a1/a2 (dead by the time K3a runs)
    float* qkv  = ws;                   // 9,437,184
    float* vf   = ws + 9437184;         // 3,145,728
    float* a1   = ws + 12582912;        // 3,145,728
    float* a2   = ws + 15728640;        // 3,145,728
    float* part = ws + 12582912;        // 12,582,912 (reuses a1+a2 region)
    float* kp   = ws + 25165824;        // 49,152
    float* vp   = ws + 25214976;        // 49,152  (total ~101 MB)

    k_qkv<<<dim3(NROW/32), dim3(256), 0, stream>>>(x, Wqkv, qkv);
    k_dw5<<<dim3(NROW/32), dim3(256), 0, stream>>>(x, c0w, c0b, a1);
    k_dw7<<<dim3(NROW/32), dim3(256), 0, stream>>>(a1, cspw, cspb, a2);
    k_pw_gate<<<dim3(NROW/32), dim3(256), 0, stream>>>(a2, c1w, c1b, x, qkv, vf);
    k_ered<<<dim3(512), dim3(256), 0, stream>>>(E, qkv, vf, part);
    k_ered_fin<<<dim3(384), dim3(256), 0, stream>>>(part, kp, vp);
    k_attn<<<dim3(NROW/32), dim3(256), 0, stream>>>(qkv, kp, vp, W0, out);
}

// Round 2
// 405.724 us; speedup vs baseline: 1.0912x; 1.0912x over previous
//
#include <hip/hip_runtime.h>

#define HH_ 128
#define WW_ 128
#define LL_ (HH_*WW_)     // 16384
#define NH 8
#define DHD 12
#define KD 256
#define BB_ 2
#define NROW (BB_*LL_)    // 32768

__device__ __forceinline__ float4 ld4(const float* p) {
    return *reinterpret_cast<const float4*>(p);
}

// ---------------- K1: qkv = x @ Wqkv  (32768x96 @ 96x288) ----------------
__global__ __launch_bounds__(256) void k_qkv(const float* __restrict__ x,
                                             const float* __restrict__ Wq,
                                             float* __restrict__ qkv) {
    __shared__ float xT[96][36];      // [k][row], padded for b128 conflict-free
    __shared__ float Wl[32*288];
    const int tid = threadIdx.x;
    const int r0 = blockIdx.x * 32;
    for (int i = tid; i < 32*96; i += 256) {
        int r = i / 96, c = i % 96;
        xT[c][r] = x[(r0 + r)*96 + c];
    }
    const int cg = tid & 31, rg = tid >> 5;
    const int c0 = cg*9, rr = rg*4;
    float acc[4][9];
#pragma unroll
    for (int a = 0; a < 4; ++a)
#pragma unroll
        for (int j = 0; j < 9; ++j) acc[a][j] = 0.f;
    for (int kc = 0; kc < 3; ++kc) {
        __syncthreads();
        for (int i = tid; i < 32*288; i += 256) Wl[i] = Wq[kc*32*288 + i];
        __syncthreads();
#pragma unroll 2
        for (int k = 0; k < 32; ++k) {
            float4 a4 = ld4(&xT[kc*32 + k][rr]);
            float av[4] = {a4.x, a4.y, a4.z, a4.w};
#pragma unroll
            for (int j = 0; j < 9; ++j) {
                float w = Wl[k*288 + c0 + j];
#pragma unroll
                for (int a = 0; a < 4; ++a) acc[a][j] = fmaf(av[a], w, acc[a][j]);
            }
        }
    }
#pragma unroll
    for (int a = 0; a < 4; ++a)
#pragma unroll
        for (int j = 0; j < 9; ++j)
            qkv[(r0 + rr + a)*288 + c0 + j] = acc[a][j];
}

// ---------------- K2a: depthwise 5x5, pad 2 (channels-last) ----------------
__global__ __launch_bounds__(256) void k_dw5(const float* __restrict__ xin,
                                             const float* __restrict__ w,
                                             const float* __restrict__ bias,
                                             float* __restrict__ out) {
    __shared__ float wl[25][96];
    const int tid = threadIdx.x;
    for (int i = tid; i < 25*96; i += 256) {
        int c = i / 25, t = i % 25;
        wl[t][c] = w[i];
    }
    __syncthreads();
    const int c4 = (tid & 7)*4;
    const int px = tid >> 3;
    const int pix0 = blockIdx.x * 32;
    const int b = pix0 >> 14;
    const int y = (pix0 & 16383) >> 7;
    const int xx = (pix0 & 127) + px;
    float4 acc[3];
#pragma unroll
    for (int ch = 0; ch < 3; ++ch) { acc[ch].x=0.f; acc[ch].y=0.f; acc[ch].z=0.f; acc[ch].w=0.f; }
#pragma unroll
    for (int iy = 0; iy < 5; ++iy) {
        int y2 = y + iy - 2;
        if (y2 < 0 || y2 >= HH_) continue;
#pragma unroll
        for (int ix = 0; ix < 5; ++ix) {
            int x2 = xx + ix - 2;
            if (x2 < 0 || x2 >= WW_) continue;
            const float* src = xin + ((b << 14) + y2*WW_ + x2)*96;
            const float* wt = &wl[iy*5 + ix][0];
#pragma unroll
            for (int ch = 0; ch < 3; ++ch) {
                float4 xv = ld4(src + ch*32 + c4);
                float4 wv = ld4(wt + ch*32 + c4);
                acc[ch].x = fmaf(xv.x, wv.x, acc[ch].x);
                acc[ch].y = fmaf(xv.y, wv.y, acc[ch].y);
                acc[ch].z = fmaf(xv.z, wv.z, acc[ch].z);
                acc[ch].w = fmaf(xv.w, wv.w, acc[ch].w);
            }
        }
    }
    float* dst = out + (long)(pix0 + px)*96;
#pragma unroll
    for (int ch = 0; ch < 3; ++ch) {
        float4 bv = ld4(bias + ch*32 + c4);
        float4 r;
        r.x = acc[ch].x + bv.x; r.y = acc[ch].y + bv.y;
        r.z = acc[ch].z + bv.z; r.w = acc[ch].w + bv.w;
        *reinterpret_cast<float4*>(dst + ch*32 + c4) = r;
    }
}

// ---------------- K2b: depthwise 7x7, dilation 3, pad 9 ----------------
__global__ __launch_bounds__(256) void k_dw7(const float* __restrict__ xin,
                                             const float* __restrict__ w,
                                             const float* __restrict__ bias,
                                             float* __restrict__ out) {
    __shared__ float wl[49][96];
    const int tid = threadIdx.x;
    for (int i = tid; i < 49*96; i += 256) {
        int c = i / 49, t = i % 49;
        wl[t][c] = w[i];
    }
    __syncthreads();
    const int c4 = (tid & 7)*4;
    const int px = tid >> 3;
    const int pix0 = blockIdx.x * 32;
    const int b = pix0 >> 14;
    const int y = (pix0 & 16383) >> 7;
    const int xx = (pix0 & 127) + px;
    float4 acc[3];
#pragma unroll
    for (int ch = 0; ch < 3; ++ch) { acc[ch].x=0.f; acc[ch].y=0.f; acc[ch].z=0.f; acc[ch].w=0.f; }
#pragma unroll
    for (int iy = 0; iy < 7; ++iy) {
        int y2 = y + iy*3 - 9;
        if (y2 < 0 || y2 >= HH_) continue;
#pragma unroll
        for (int ix = 0; ix < 7; ++ix) {
            int x2 = xx + ix*3 - 9;
            if (x2 < 0 || x2 >= WW_) continue;
            const float* src = xin + ((b << 14) + y2*WW_ + x2)*96;
            const float* wt = &wl[iy*7 + ix][0];
#pragma unroll
            for (int ch = 0; ch < 3; ++ch) {
                float4 xv = ld4(src + ch*32 + c4);
                float4 wv = ld4(wt + ch*32 + c4);
                acc[ch].x = fmaf(xv.x, wv.x, acc[ch].x);
                acc[ch].y = fmaf(xv.y, wv.y, acc[ch].y);
                acc[ch].z = fmaf(xv.z, wv.z, acc[ch].z);
                acc[ch].w = fmaf(xv.w, wv.w, acc[ch].w);
            }
        }
    }
    float* dst = out + (long)(pix0 + px)*96;
#pragma unroll
    for (int ch = 0; ch < 3; ++ch) {
        float4 bv = ld4(bias + ch*32 + c4);
        float4 r;
        r.x = acc[ch].x + bv.x; r.y = acc[ch].y + bv.y;
        r.z = acc[ch].z + bv.z; r.w = acc[ch].w + bv.w;
        *reinterpret_cast<float4*>(dst + ch*32 + c4) = r;
    }
}

// ------- K2c: a3 = a2 @ w1^T + b1 ; vf = x * a3 * v  (v = qkv slice 2) -------
__global__ __launch_bounds__(256) void k_pw_gate(const float* __restrict__ a2,
        const float* __restrict__ w1, const float* __restrict__ b1,
        const float* __restrict__ xin, const float* __restrict__ qkv,
        float* __restrict__ vf) {
    __shared__ float aT[96][36];
    __shared__ float wT[96][100];    // wT[ci][o] = w1[o*96+ci]
    const int tid = threadIdx.x;
    const int r0 = blockIdx.x * 32;
    for (int i = tid; i < 32*96; i += 256) {
        int r = i / 96, c = i % 96;
        aT[c][r] = a2[(r0 + r)*96 + c];
    }
    for (int i = tid; i < 96*96; i += 256) {
        int o = i / 96, ci = i % 96;
        wT[ci][o] = w1[i];
    }
    __syncthreads();
    const int cg = tid & 31, rg = tid >> 5;
    const int c0 = cg*3, rr = rg*4;
    float acc[4][3];
#pragma unroll
    for (int r = 0; r < 4; ++r)
#pragma unroll
        for (int j = 0; j < 3; ++j) acc[r][j] = 0.f;
#pragma unroll 4
    for (int k = 0; k < 96; ++k) {
        float4 a4 = ld4(&aT[k][rr]);
        float av[4] = {a4.x, a4.y, a4.z, a4.w};
#pragma unroll
        for (int j = 0; j < 3; ++j) {
            float w = wT[k][c0 + j];
#pragma unroll
            for (int r = 0; r < 4; ++r) acc[r][j] = fmaf(av[r], w, acc[r][j]);
        }
    }
#pragma unroll
    for (int r = 0; r < 4; ++r) {
        int row = r0 + rr + r;
#pragma unroll
        for (int j = 0; j < 3; ++j) {
            int c = c0 + j;
            float g = acc[r][j] + b1[c];
            vf[row*96 + c] = xin[row*96 + c] * qkv[row*288 + 192 + c] * g;
        }
    }
}

// ------- K3a: partial E-reduction: part[b][jc][m][kk][c] over 128-row chunk -------
__global__ __launch_bounds__(256) void k_ered(const float* __restrict__ E,
        const float* __restrict__ qkv, const float* __restrict__ vf,
        float* __restrict__ part) {
    __shared__ float El[64][256];
    const int tid = threadIdx.x;
    const int bid = blockIdx.x;
    const int m  = bid & 1;
    const int jc = (bid >> 1) & 127;
    const int b  = bid >> 8;
    const int j0 = jc * 128;
    float acc[12][8] = {};
    for (int js = 0; js < 2; ++js) {
        __syncthreads();
        for (int i = tid; i < 64*256; i += 256)
            El[i >> 8][i & 255] = E[(j0 + (js << 6) + (i >> 8))*256 + (i & 255)];
        __syncthreads();
        for (int j = 0; j < 64; ++j) {
            float e = El[j][tid];
            int row = b*LL_ + j0 + (js << 6) + j;
            const float* xr = (m == 0) ? (qkv + row*288 + 96) : (vf + row*96);
#pragma unroll
            for (int cg = 0; cg < 12; ++cg) {
                float4 xa = ld4(xr + cg*8);
                float4 xb = ld4(xr + cg*8 + 4);
                acc[cg][0] = fmaf(e, xa.x, acc[cg][0]);
                acc[cg][1] = fmaf(e, xa.y, acc[cg][1]);
                acc[cg][2] = fmaf(e, xa.z, acc[cg][2]);
                acc[cg][3] = fmaf(e, xa.w, acc[cg][3]);
                acc[cg][4] = fmaf(e, xb.x, acc[cg][4]);
                acc[cg][5] = fmaf(e, xb.y, acc[cg][5]);
                acc[cg][6] = fmaf(e, xb.z, acc[cg][6]);
                acc[cg][7] = fmaf(e, xb.w, acc[cg][7]);
            }
        }
    }
    float* dst = part + ((((b*128 + jc)*2 + m)*256 + tid)*96);
#pragma unroll
    for (int cg = 0; cg < 12; ++cg)
#pragma unroll
        for (int i = 0; i < 8; ++i) dst[cg*8 + i] = acc[cg][i];
}

// ------- K3b: reduce partials -> kp[b][h][d][kk], vp[b][h][d][kk] (transposed!) -------
__global__ __launch_bounds__(256) void k_ered_fin(const float* __restrict__ part,
        float* __restrict__ kp, float* __restrict__ vp) {
    const int idx = blockIdx.x*256 + threadIdx.x;  // 2*2*256*96 = 98304
    const int c  = idx % 96;
    const int kk = (idx / 96) % 256;
    const int m  = (idx / (96*256)) % 2;
    const int b  = idx / (96*256*2);
    float s = 0.f;
    const long off = ((long)((b*128)*2 + m)*256 + kk)*96 + c;
    for (int jc = 0; jc < 128; ++jc)
        s += part[off + (long)jc*(2*256*96)];
    const int h = c / DHD, d = c % DHD;
    float* dst = (m == 0) ? kp : vp;
    dst[((b*NH + h)*DHD + d)*256 + kk] = s;
}

// ------- K4: fused attention: scores -> softmax -> P in LDS -> PV -> W0 -------
// block = 32 rows, 8 heads serial. No cross-lane PV reduction.
__global__ __launch_bounds__(256) void k_attn(const float* __restrict__ qkv,
        const float* __restrict__ kp, const float* __restrict__ vp,
        const float* __restrict__ W0, float* __restrict__ out) {
    __shared__ float qT[96*36];      // qT[c][r], 13824B
    __shared__ float Pbuf[32*264];   // union: kpT[12][264] (phase A) / P[32][264]; 33792B
    __shared__ float vpT[12*264];    // 12672B
    __shared__ float oh[32*13];      // 1664B
    __shared__ float rinv[32];
    const int tid = threadIdx.x;
    const int r0 = blockIdx.x * 32;
    const int b = r0 >> 14;
    for (int i = tid; i < 32*96; i += 256) {
        int r = i / 96, c = i % 96;
        qT[c*36 + r] = qkv[(r0 + r)*288 + c];
    }
    const int kg = tid & 31, rg = tid >> 5;
    const int rr = rg*4;
    const int rB = tid >> 3, dg = tid & 7;   // phase B mapping
    const float scale = 0.28867513459481287f;  // 1/sqrt(12)
    float acc_out[4][3];
#pragma unroll
    for (int r = 0; r < 4; ++r)
#pragma unroll
        for (int j = 0; j < 3; ++j) acc_out[r][j] = 0.f;

    for (int h = 0; h < NH; ++h) {
        __syncthreads();   // previous head's readers of Pbuf/vpT/oh done
        // ---- stage kpT (into Pbuf rows 0..11) and vpT, coalesced float4 ----
        {
            const float* srck = kp + (long)(b*NH + h)*12*256;
            const float* srcv = vp + (long)(b*NH + h)*12*256;
            for (int i = tid; i < 768; i += 256) {
                int d = i >> 6, c4 = (i & 63) << 2;
                *reinterpret_cast<float4*>(&Pbuf[d*264 + c4]) = ld4(srck + (i << 2));
                *reinterpret_cast<float4*>(&vpT[d*264 + c4]) = ld4(srcv + (i << 2));
            }
        }
        __syncthreads();
        // ---- phase A: scores. thread (rg,kg): rows rr..rr+3, cols {kg*4..+3, 128+kg*4..+3} ----
        float s[4][8];
#pragma unroll
        for (int r = 0; r < 4; ++r)
#pragma unroll
            for (int j = 0; j < 8; ++j) s[r][j] = 0.f;
#pragma unroll
        for (int d = 0; d < 12; ++d) {
            float4 qa = ld4(&qT[(h*12 + d)*36 + rr]);
            float qv[4] = {qa.x, qa.y, qa.z, qa.w};
            float4 ka = ld4(&Pbuf[d*264 + kg*4]);
            float4 kb = ld4(&Pbuf[d*264 + 128 + kg*4]);
            float kv8[8] = {ka.x, ka.y, ka.z, ka.w, kb.x, kb.y, kb.z, kb.w};
#pragma unroll
            for (int r = 0; r < 4; ++r)
#pragma unroll
                for (int j = 0; j < 8; ++j)
                    s[r][j] = fmaf(qv[r], kv8[j], s[r][j]);
        }
        // ---- softmax (unnormalized p; 1/sum via rinv LDS) ----
        float p[4][8];
        float rin[4];
#pragma unroll
        for (int r = 0; r < 4; ++r) {
            float mx = s[r][0];
#pragma unroll
            for (int j = 1; j < 8; ++j) mx = fmaxf(mx, s[r][j]);
#pragma unroll
            for (int off = 16; off >= 1; off >>= 1)
                mx = fmaxf(mx, __shfl_xor(mx, off, 64));
            float ssum = 0.f;
#pragma unroll
            for (int j = 0; j < 8; ++j) {
                p[r][j] = __expf((s[r][j] - mx) * scale);
                ssum += p[r][j];
            }
#pragma unroll
            for (int off = 16; off >= 1; off >>= 1)
                ssum += __shfl_xor(ssum, off, 64);
            rin[r] = 1.0f / ssum;
        }
        __syncthreads();   // all kpT reads done; safe to overwrite with P
#pragma unroll
        for (int r = 0; r < 4; ++r) {
            *reinterpret_cast<float4*>(&Pbuf[(rr + r)*264 + kg*4]) =
                make_float4(p[r][0], p[r][1], p[r][2], p[r][3]);
            *reinterpret_cast<float4*>(&Pbuf[(rr + r)*264 + 128 + kg*4]) =
                make_float4(p[r][4], p[r][5], p[r][6], p[r][7]);
        }
        if (kg == 0) {
#pragma unroll
            for (int r = 0; r < 4; ++r) rinv[rr + r] = rin[r];
        }
        __syncthreads();
        // ---- phase B: O[rB][d] = sum_k P[rB][k]*vpT[d][k]; thread owns d=dg (+dg+8 if dg<4) ----
        float4 ac1 = make_float4(0.f, 0.f, 0.f, 0.f);
        float4 ac2 = make_float4(0.f, 0.f, 0.f, 0.f);
#pragma unroll 8
        for (int k0 = 0; k0 < 256; k0 += 4) {
            float4 pv = ld4(&Pbuf[rB*264 + k0]);
            float4 v1 = ld4(&vpT[dg*264 + k0]);
            ac1.x = fmaf(pv.x, v1.x, ac1.x);
            ac1.y = fmaf(pv.y, v1.y, ac1.y);
            ac1.z = fmaf(pv.z, v1.z, ac1.z);
            ac1.w = fmaf(pv.w, v1.w, ac1.w);
            if (dg < 4) {
                float4 v2 = ld4(&vpT[(dg + 8)*264 + k0]);
                ac2.x = fmaf(pv.x, v2.x, ac2.x);
                ac2.y = fmaf(pv.y, v2.y, ac2.y);
                ac2.z = fmaf(pv.z, v2.z, ac2.z);
                ac2.w = fmaf(pv.w, v2.w, ac2.w);
            }
        }
        {
            float ri = rinv[rB];
            oh[rB*13 + dg] = (ac1.x + ac1.y + ac1.z + ac1.w) * ri;
            if (dg < 4) oh[rB*13 + dg + 8] = (ac2.x + ac2.y + ac2.z + ac2.w) * ri;
        }
        __syncthreads();
        // ---- phase C: acc_out += oh @ W0[h*12..h*12+11, :], W0 from global (L2) ----
        {
            const int c0 = kg*3;
            const float* w0p = W0 + h*12*96;
#pragma unroll
            for (int d = 0; d < 12; ++d) {
                float wa = w0p[d*96 + c0];
                float wb = w0p[d*96 + c0 + 1];
                float wc = w0p[d*96 + c0 + 2];
#pragma unroll
                for (int r = 0; r < 4; ++r) {
                    float o = oh[(rr + r)*13 + d];
                    acc_out[r][0] = fmaf(o, wa, acc_out[r][0]);
                    acc_out[r][1] = fmaf(o, wb, acc_out[r][1]);
                    acc_out[r][2] = fmaf(o, wc, acc_out[r][2]);
                }
            }
        }
    }
    const int c0 = kg*3;
#pragma unroll
    for (int r = 0; r < 4; ++r)
#pragma unroll
        for (int j = 0; j < 3; ++j)
            out[(r0 + rr + r)*96 + c0 + j] = acc_out[r][j];
}

extern "C" void kernel_launch(void* const* d_in, const int* in_sizes, int n_in,
                              void* d_out, int out_size, void* d_ws, size_t ws_size,
                              hipStream_t stream) {
    (void)in_sizes; (void)n_in; (void)out_size; (void)ws_size;
    const float* x    = (const float*)d_in[0];
    const float* Wqkv = (const float*)d_in[1];
    const float* W0   = (const float*)d_in[2];
    const float* E    = (const float*)d_in[3];
    const float* c0w  = (const float*)d_in[4];
    const float* c0b  = (const float*)d_in[5];
    const float* cspw = (const float*)d_in[6];
    const float* cspb = (const float*)d_in[7];
    const float* c1w  = (const float*)d_in[8];
    const float* c1b  = (const float*)d_in[9];
    float* out = (float*)d_out;
    float* ws  = (float*)d_ws;

    // workspace layout (floats); part overlaps a1/a2 (dead by the time K3a runs)
    float* qkv  = ws;                   // 9,437,184
    float* vf   = ws + 9437184;         // 3,145,728
    float* a1   = ws + 12582912;        // 3,145,728
    float* a2   = ws + 15728640;        // 3,145,728
    float* part = ws + 12582912;        // 12,582,912 (reuses a1+a2 region)
    float* kp   = ws + 25165824;        // 49,152
    float* vp   = ws + 25214976;        // 49,152  (total ~101 MB)

    k_qkv<<<dim3(NROW/32), dim3(256), 0, stream>>>(x, Wqkv, qkv);
    k_dw5<<<dim3(NROW/32), dim3(256), 0, stream>>>(x, c0w, c0b, a1);
    k_dw7<<<dim3(NROW/32), dim3(256), 0, stream>>>(a1, cspw, cspb, a2);
    k_pw_gate<<<dim3(NROW/32), dim3(256), 0, stream>>>(a2, c1w, c1b, x, qkv, vf);
    k_ered<<<dim3(512), dim3(256), 0, stream>>>(E, qkv, vf, part);
    k_ered_fin<<<dim3(384), dim3(256), 0, stream>>>(part, kp, vp);
    k_attn<<<dim3(NROW/32), dim3(256), 0, stream>>>(qkv, kp, vp, W0, out);
}

// Round 3
// 313.967 us; speedup vs baseline: 1.4101x; 1.2922x over previous
//
#include <hip/hip_runtime.h>

#define HH_ 128
#define WW_ 128
#define LL_ (HH_*WW_)     // 16384
#define NH 8
#define DHD 12
#define KD 256
#define BB_ 2
#define NROW (BB_*LL_)    // 32768

__device__ __forceinline__ float4 ld4(const float* p) {
    return *reinterpret_cast<const float4*>(p);
}

// ---------------- K1: qkv = x @ Wqkv  (32768x96 @ 96x288) ----------------
__global__ __launch_bounds__(256) void k_qkv(const float* __restrict__ x,
                                             const float* __restrict__ Wq,
                                             float* __restrict__ qkv) {
    __shared__ float xT[96][36];      // [k][row], padded for b128 conflict-free
    __shared__ float Wl[32*288];
    const int tid = threadIdx.x;
    const int r0 = blockIdx.x * 32;
    for (int i = tid; i < 32*96; i += 256) {
        int r = i / 96, c = i % 96;
        xT[c][r] = x[(r0 + r)*96 + c];
    }
    const int cg = tid & 31, rg = tid >> 5;
    const int c0 = cg*9, rr = rg*4;
    float acc[4][9];
#pragma unroll
    for (int a = 0; a < 4; ++a)
#pragma unroll
        for (int j = 0; j < 9; ++j) acc[a][j] = 0.f;
    for (int kc = 0; kc < 3; ++kc) {
        __syncthreads();
        for (int i = tid; i < 32*288; i += 256) Wl[i] = Wq[kc*32*288 + i];
        __syncthreads();
#pragma unroll 2
        for (int k = 0; k < 32; ++k) {
            float4 a4 = ld4(&xT[kc*32 + k][rr]);
            float av[4] = {a4.x, a4.y, a4.z, a4.w};
#pragma unroll
            for (int j = 0; j < 9; ++j) {
                float w = Wl[k*288 + c0 + j];
#pragma unroll
                for (int a = 0; a < 4; ++a) acc[a][j] = fmaf(av[a], w, acc[a][j]);
            }
        }
    }
#pragma unroll
    for (int a = 0; a < 4; ++a)
#pragma unroll
        for (int j = 0; j < 9; ++j)
            qkv[(r0 + rr + a)*288 + c0 + j] = acc[a][j];
}

// ---------------- K2a: depthwise 5x5, pad 2 (channels-last) ----------------
__global__ __launch_bounds__(256) void k_dw5(const float* __restrict__ xin,
                                             const float* __restrict__ w,
                                             const float* __restrict__ bias,
                                             float* __restrict__ out) {
    __shared__ float wl[25][96];
    const int tid = threadIdx.x;
    for (int i = tid; i < 25*96; i += 256) {
        int c = i / 25, t = i % 25;
        wl[t][c] = w[i];
    }
    __syncthreads();
    const int c4 = (tid & 7)*4;
    const int px = tid >> 3;
    const int pix0 = blockIdx.x * 32;
    const int b = pix0 >> 14;
    const int y = (pix0 & 16383) >> 7;
    const int xx = (pix0 & 127) + px;
    float4 acc[3];
#pragma unroll
    for (int ch = 0; ch < 3; ++ch) { acc[ch].x=0.f; acc[ch].y=0.f; acc[ch].z=0.f; acc[ch].w=0.f; }
#pragma unroll
    for (int iy = 0; iy < 5; ++iy) {
        int y2 = y + iy - 2;
        if (y2 < 0 || y2 >= HH_) continue;
#pragma unroll
        for (int ix = 0; ix < 5; ++ix) {
            int x2 = xx + ix - 2;
            if (x2 < 0 || x2 >= WW_) continue;
            const float* src = xin + ((b << 14) + y2*WW_ + x2)*96;
            const float* wt = &wl[iy*5 + ix][0];
#pragma unroll
            for (int ch = 0; ch < 3; ++ch) {
                float4 xv = ld4(src + ch*32 + c4);
                float4 wv = ld4(wt + ch*32 + c4);
                acc[ch].x = fmaf(xv.x, wv.x, acc[ch].x);
                acc[ch].y = fmaf(xv.y, wv.y, acc[ch].y);
                acc[ch].z = fmaf(xv.z, wv.z, acc[ch].z);
                acc[ch].w = fmaf(xv.w, wv.w, acc[ch].w);
            }
        }
    }
    float* dst = out + (long)(pix0 + px)*96;
#pragma unroll
    for (int ch = 0; ch < 3; ++ch) {
        float4 bv = ld4(bias + ch*32 + c4);
        float4 r;
        r.x = acc[ch].x + bv.x; r.y = acc[ch].y + bv.y;
        r.z = acc[ch].z + bv.z; r.w = acc[ch].w + bv.w;
        *reinterpret_cast<float4*>(dst + ch*32 + c4) = r;
    }
}

// ---------------- K2b: depthwise 7x7, dilation 3, pad 9 ----------------
__global__ __launch_bounds__(256) void k_dw7(const float* __restrict__ xin,
                                             const float* __restrict__ w,
                                             const float* __restrict__ bias,
                                             float* __restrict__ out) {
    __shared__ float wl[49][96];
    const int tid = threadIdx.x;
    for (int i = tid; i < 49*96; i += 256) {
        int c = i / 49, t = i % 49;
        wl[t][c] = w[i];
    }
    __syncthreads();
    const int c4 = (tid & 7)*4;
    const int px = tid >> 3;
    const int pix0 = blockIdx.x * 32;
    const int b = pix0 >> 14;
    const int y = (pix0 & 16383) >> 7;
    const int xx = (pix0 & 127) + px;
    float4 acc[3];
#pragma unroll
    for (int ch = 0; ch < 3; ++ch) { acc[ch].x=0.f; acc[ch].y=0.f; acc[ch].z=0.f; acc[ch].w=0.f; }
#pragma unroll
    for (int iy = 0; iy < 7; ++iy) {
        int y2 = y + iy*3 - 9;
        if (y2 < 0 || y2 >= HH_) continue;
#pragma unroll
        for (int ix = 0; ix < 7; ++ix) {
            int x2 = xx + ix*3 - 9;
            if (x2 < 0 || x2 >= WW_) continue;
            const float* src = xin + ((b << 14) + y2*WW_ + x2)*96;
            const float* wt = &wl[iy*7 + ix][0];
#pragma unroll
            for (int ch = 0; ch < 3; ++ch) {
                float4 xv = ld4(src + ch*32 + c4);
                float4 wv = ld4(wt + ch*32 + c4);
                acc[ch].x = fmaf(xv.x, wv.x, acc[ch].x);
                acc[ch].y = fmaf(xv.y, wv.y, acc[ch].y);
                acc[ch].z = fmaf(xv.z, wv.z, acc[ch].z);
                acc[ch].w = fmaf(xv.w, wv.w, acc[ch].w);
            }
        }
    }
    float* dst = out + (long)(pix0 + px)*96;
#pragma unroll
    for (int ch = 0; ch < 3; ++ch) {
        float4 bv = ld4(bias + ch*32 + c4);
        float4 r;
        r.x = acc[ch].x + bv.x; r.y = acc[ch].y + bv.y;
        r.z = acc[ch].z + bv.z; r.w = acc[ch].w + bv.w;
        *reinterpret_cast<float4*>(dst + ch*32 + c4) = r;
    }
}

// ------- K2c: a3 = a2 @ w1^T + b1 ; vf = x * a3 * v  (v = qkv slice 2) -------
__global__ __launch_bounds__(256) void k_pw_gate(const float* __restrict__ a2,
        const float* __restrict__ w1, const float* __restrict__ b1,
        const float* __restrict__ xin, const float* __restrict__ qkv,
        float* __restrict__ vf) {
    __shared__ float aT[96][36];
    __shared__ float wT[96][100];    // wT[ci][o] = w1[o*96+ci]
    const int tid = threadIdx.x;
    const int r0 = blockIdx.x * 32;
    for (int i = tid; i < 32*96; i += 256) {
        int r = i / 96, c = i % 96;
        aT[c][r] = a2[(r0 + r)*96 + c];
    }
    for (int i = tid; i < 96*96; i += 256) {
        int o = i / 96, ci = i % 96;
        wT[ci][o] = w1[i];
    }
    __syncthreads();
    const int cg = tid & 31, rg = tid >> 5;
    const int c0 = cg*3, rr = rg*4;
    float acc[4][3];
#pragma unroll
    for (int r = 0; r < 4; ++r)
#pragma unroll
        for (int j = 0; j < 3; ++j) acc[r][j] = 0.f;
#pragma unroll 4
    for (int k = 0; k < 96; ++k) {
        float4 a4 = ld4(&aT[k][rr]);
        float av[4] = {a4.x, a4.y, a4.z, a4.w};
#pragma unroll
        for (int j = 0; j < 3; ++j) {
            float w = wT[k][c0 + j];
#pragma unroll
            for (int r = 0; r < 4; ++r) acc[r][j] = fmaf(av[r], w, acc[r][j]);
        }
    }
#pragma unroll
    for (int r = 0; r < 4; ++r) {
        int row = r0 + rr + r;
#pragma unroll
        for (int j = 0; j < 3; ++j) {
            int c = c0 + j;
            float g = acc[r][j] + b1[c];
            vf[row*96 + c] = xin[row*96 + c] * qkv[row*288 + 192 + c] * g;
        }
    }
}

// ------- K3a: E-reduction, retiled. grid 256 = b(2) x jc(128 chunks of 128 rows),
// 512 threads = kkg(64) x cg(8); thread owns 4kk x 12c for BOTH k and vf. -------
__global__ __launch_bounds__(512) void k_ered(const float* __restrict__ E,
        const float* __restrict__ qkv, const float* __restrict__ vf,
        float* __restrict__ part) {
    __shared__ float El[32*256];    // [jj][kk]
    __shared__ float Xk[32*96];     // [jj][c]
    __shared__ float Xv[32*96];
    const int tid = threadIdx.x;
    const int b  = blockIdx.x >> 7;
    const int jc = blockIdx.x & 127;
    const int j0 = jc * 128;
    const int cg = tid & 7, kkg = tid >> 3;
    const int kk0 = kkg*4, c0 = cg*12;
    float acck[4][12];
    float accv[4][12];
#pragma unroll
    for (int a = 0; a < 4; ++a)
#pragma unroll
        for (int c = 0; c < 12; ++c) { acck[a][c] = 0.f; accv[a][c] = 0.f; }
    for (int st = 0; st < 4; ++st) {
        __syncthreads();
        for (int i = tid; i < 32*64; i += 512) {
            int row = i >> 6, c4 = (i & 63) << 2;
            *reinterpret_cast<float4*>(&El[row*256 + c4]) =
                ld4(&E[(j0 + st*32 + row)*256 + c4]);
        }
        for (int i = tid; i < 768; i += 512) {
            int row = i / 24, c4 = (i % 24) << 2;
            int grow = b*LL_ + j0 + st*32 + row;
            *reinterpret_cast<float4*>(&Xk[row*96 + c4]) = ld4(&qkv[(long)grow*288 + 96 + c4]);
            *reinterpret_cast<float4*>(&Xv[row*96 + c4]) = ld4(&vf[(long)grow*96 + c4]);
        }
        __syncthreads();
#pragma unroll 2
        for (int j = 0; j < 32; ++j) {
            float4 e4 = ld4(&El[j*256 + kk0]);
            float ev[4] = {e4.x, e4.y, e4.z, e4.w};
            float xk[12], xv[12];
            *reinterpret_cast<float4*>(&xk[0]) = ld4(&Xk[j*96 + c0]);
            *reinterpret_cast<float4*>(&xk[4]) = ld4(&Xk[j*96 + c0 + 4]);
            *reinterpret_cast<float4*>(&xk[8]) = ld4(&Xk[j*96 + c0 + 8]);
            *reinterpret_cast<float4*>(&xv[0]) = ld4(&Xv[j*96 + c0]);
            *reinterpret_cast<float4*>(&xv[4]) = ld4(&Xv[j*96 + c0 + 4]);
            *reinterpret_cast<float4*>(&xv[8]) = ld4(&Xv[j*96 + c0 + 8]);
#pragma unroll
            for (int a = 0; a < 4; ++a) {
                float e = ev[a];
#pragma unroll
                for (int c = 0; c < 12; ++c) {
                    acck[a][c] = fmaf(e, xk[c], acck[a][c]);
                    accv[a][c] = fmaf(e, xv[c], accv[a][c]);
                }
            }
        }
    }
    // part[b][jc][m][kk][c]
#pragma unroll
    for (int a = 0; a < 4; ++a) {
        float* dk = part + ((long)(((b*128 + jc)*2 + 0)*256 + kk0 + a))*96 + c0;
        *reinterpret_cast<float4*>(dk)     = make_float4(acck[a][0], acck[a][1], acck[a][2], acck[a][3]);
        *reinterpret_cast<float4*>(dk + 4) = make_float4(acck[a][4], acck[a][5], acck[a][6], acck[a][7]);
        *reinterpret_cast<float4*>(dk + 8) = make_float4(acck[a][8], acck[a][9], acck[a][10], acck[a][11]);
        float* dv = part + ((long)(((b*128 + jc)*2 + 1)*256 + kk0 + a))*96 + c0;
        *reinterpret_cast<float4*>(dv)     = make_float4(accv[a][0], accv[a][1], accv[a][2], accv[a][3]);
        *reinterpret_cast<float4*>(dv + 4) = make_float4(accv[a][4], accv[a][5], accv[a][6], accv[a][7]);
        *reinterpret_cast<float4*>(dv + 8) = make_float4(accv[a][8], accv[a][9], accv[a][10], accv[a][11]);
    }
}

// ------- K3b: reduce partials -> kp[b][h][d][kk], vp[b][h][d][kk] (transposed!) -------
__global__ __launch_bounds__(256) void k_ered_fin(const float* __restrict__ part,
        float* __restrict__ kp, float* __restrict__ vp) {
    const int idx = blockIdx.x*256 + threadIdx.x;  // 2*2*256*96 = 98304
    const int c  = idx % 96;
    const int kk = (idx / 96) % 256;
    const int m  = (idx / (96*256)) % 2;
    const int b  = idx / (96*256*2);
    float s = 0.f;
    const long off = ((long)((b*128)*2 + m)*256 + kk)*96 + c;
    for (int jc = 0; jc < 128; ++jc)
        s += part[off + (long)jc*(2*256*96)];
    const int h = c / DHD, d = c % DHD;
    float* dst = (m == 0) ? kp : vp;
    dst[((b*NH + h)*DHD + d)*256 + kk] = s;
}

// ------- K4: fused attention: scores -> softmax -> P in LDS -> PV -> W0 -------
// block = 32 rows; LDS ~48.8KB -> 3 blocks/CU. Per-head q staged (1.7KB).
__global__ __launch_bounds__(256) void k_attn(const float* __restrict__ qkv,
        const float* __restrict__ kp, const float* __restrict__ vp,
        const float* __restrict__ W0, float* __restrict__ out) {
    __shared__ float Pbuf[32*264];   // union: kpT[12][264] (phase A) / P[32][264]
    __shared__ float vpT[12*264];
    __shared__ float qh[12*36];      // per-head q, [d][row]
    __shared__ float oh[32*13];
    __shared__ float rinv[32];
    const int tid = threadIdx.x;
    const int r0 = blockIdx.x * 32;
    const int b = r0 >> 14;
    const int kg = tid & 31, rg = tid >> 5;
    const int rr = rg*4;
    const int rB = tid >> 3, dg = tid & 7;   // phase B mapping
    const float scale = 0.28867513459481287f;  // 1/sqrt(12)
    float acc_out[4][3];
#pragma unroll
    for (int r = 0; r < 4; ++r)
#pragma unroll
        for (int j = 0; j < 3; ++j) acc_out[r][j] = 0.f;

    for (int h = 0; h < NH; ++h) {
        __syncthreads();   // previous head's readers of Pbuf/vpT/oh done
        // ---- stage kpT (rows 0..11 of Pbuf), vpT, and qh ----
        {
            const float* srck = kp + (long)(b*NH + h)*12*256;
            const float* srcv = vp + (long)(b*NH + h)*12*256;
            for (int i = tid; i < 768; i += 256) {
                int d = i >> 6, c4 = (i & 63) << 2;
                *reinterpret_cast<float4*>(&Pbuf[d*264 + c4]) = ld4(srck + (i << 2));
                *reinterpret_cast<float4*>(&vpT[d*264 + c4]) = ld4(srcv + (i << 2));
            }
            if (tid < 96) {
                int row = tid / 3, cp = (tid % 3) << 2;
                float4 q4 = ld4(&qkv[(long)(r0 + row)*288 + h*12 + cp]);
                qh[(cp + 0)*36 + row] = q4.x;
                qh[(cp + 1)*36 + row] = q4.y;
                qh[(cp + 2)*36 + row] = q4.z;
                qh[(cp + 3)*36 + row] = q4.w;
            }
        }
        __syncthreads();
        // ---- phase A: scores. thread (rg,kg): rows rr..rr+3, cols {kg*4..+3, 128+kg*4..+3} ----
        float s[4][8];
#pragma unroll
        for (int r = 0; r < 4; ++r)
#pragma unroll
            for (int j = 0; j < 8; ++j) s[r][j] = 0.f;
#pragma unroll
        for (int d = 0; d < 12; ++d) {
            float4 qa = ld4(&qh[d*36 + rr]);
            float qv[4] = {qa.x, qa.y, qa.z, qa.w};
            float4 ka = ld4(&Pbuf[d*264 + kg*4]);
            float4 kb = ld4(&Pbuf[d*264 + 128 + kg*4]);
            float kv8[8] = {ka.x, ka.y, ka.z, ka.w, kb.x, kb.y, kb.z, kb.w};
#pragma unroll
            for (int r = 0; r < 4; ++r)
#pragma unroll
                for (int j = 0; j < 8; ++j)
                    s[r][j] = fmaf(qv[r], kv8[j], s[r][j]);
        }
        // ---- softmax (unnormalized p; 1/sum via rinv LDS) ----
        float p[4][8];
        float rin[4];
#pragma unroll
        for (int r = 0; r < 4; ++r) {
            float mx = s[r][0];
#pragma unroll
            for (int j = 1; j < 8; ++j) mx = fmaxf(mx, s[r][j]);
#pragma unroll
            for (int off = 16; off >= 1; off >>= 1)
                mx = fmaxf(mx, __shfl_xor(mx, off, 64));
            float ssum = 0.f;
#pragma unroll
            for (int j = 0; j < 8; ++j) {
                p[r][j] = __expf((s[r][j] - mx) * scale);
                ssum += p[r][j];
            }
#pragma unroll
            for (int off = 16; off >= 1; off >>= 1)
                ssum += __shfl_xor(ssum, off, 64);
            rin[r] = 1.0f / ssum;
        }
        __syncthreads();   // all kpT reads done; safe to overwrite with P
#pragma unroll
        for (int r = 0; r < 4; ++r) {
            *reinterpret_cast<float4*>(&Pbuf[(rr + r)*264 + kg*4]) =
                make_float4(p[r][0], p[r][1], p[r][2], p[r][3]);
            *reinterpret_cast<float4*>(&Pbuf[(rr + r)*264 + 128 + kg*4]) =
                make_float4(p[r][4], p[r][5], p[r][6], p[r][7]);
        }
        if (kg == 0) {
#pragma unroll
            for (int r = 0; r < 4; ++r) rinv[rr + r] = rin[r];
        }
        __syncthreads();
        // ---- phase B: O[rB][d] = sum_k P[rB][k]*vpT[d][k]; thread owns d=dg (+dg+8 if dg<4) ----
        float4 ac1 = make_float4(0.f, 0.f, 0.f, 0.f);
        float4 ac2 = make_float4(0.f, 0.f, 0.f, 0.f);
#pragma unroll 8
        for (int k0 = 0; k0 < 256; k0 += 4) {
            float4 pv = ld4(&Pbuf[rB*264 + k0]);
            float4 v1 = ld4(&vpT[dg*264 + k0]);
            ac1.x = fmaf(pv.x, v1.x, ac1.x);
            ac1.y = fmaf(pv.y, v1.y, ac1.y);
            ac1.z = fmaf(pv.z, v1.z, ac1.z);
            ac1.w = fmaf(pv.w, v1.w, ac1.w);
            if (dg < 4) {
                float4 v2 = ld4(&vpT[(dg + 8)*264 + k0]);
                ac2.x = fmaf(pv.x, v2.x, ac2.x);
                ac2.y = fmaf(pv.y, v2.y, ac2.y);
                ac2.z = fmaf(pv.z, v2.z, ac2.z);
                ac2.w = fmaf(pv.w, v2.w, ac2.w);
            }
        }
        {
            float ri = rinv[rB];
            oh[rB*13 + dg] = (ac1.x + ac1.y + ac1.z + ac1.w) * ri;
            if (dg < 4) oh[rB*13 + dg + 8] = (ac2.x + ac2.y + ac2.z + ac2.w) * ri;
        }
        __syncthreads();
        // ---- phase C: acc_out += oh @ W0[h*12..h*12+11, :], W0 from global (L2) ----
        {
            const int c0 = kg*3;
            const float* w0p = W0 + h*12*96;
#pragma unroll
            for (int d = 0; d < 12; ++d) {
                float wa = w0p[d*96 + c0];
                float wb = w0p[d*96 + c0 + 1];
                float wc = w0p[d*96 + c0 + 2];
#pragma unroll
                for (int r = 0; r < 4; ++r) {
                    float o = oh[(rr + r)*13 + d];
                    acc_out[r][0] = fmaf(o, wa, acc_out[r][0]);
                    acc_out[r][1] = fmaf(o, wb, acc_out[r][1]);
                    acc_out[r][2] = fmaf(o, wc, acc_out[r][2]);
                }
            }
        }
    }
    const int c0 = kg*3;
#pragma unroll
    for (int r = 0; r < 4; ++r)
#pragma unroll
        for (int j = 0; j < 3; ++j)
            out[(r0 + rr + r)*96 + c0 + j] = acc_out[r][j];
}

extern "C" void kernel_launch(void* const* d_in, const int* in_sizes, int n_in,
                              void* d_out, int out_size, void* d_ws, size_t ws_size,
                              hipStream_t stream) {
    (void)in_sizes; (void)n_in; (void)out_size; (void)ws_size;
    const float* x    = (const float*)d_in[0];
    const float* Wqkv = (const float*)d_in[1];
    const float* W0   = (const float*)d_in[2];
    const float* E    = (const float*)d_in[3];
    const float* c0w  = (const float*)d_in[4];
    const float* c0b  = (const float*)d_in[5];
    const float* cspw = (const float*)d_in[6];
    const float* cspb = (const float*)d_in[7];
    const float* c1w  = (const float*)d_in[8];
    const float* c1b  = (const float*)d_in[9];
    float* out = (float*)d_out;
    float* ws  = (float*)d_ws;

    // workspace layout (floats); part overlaps a1/a2 (dead by the time K3a runs)
    float* qkv  = ws;                   // 9,437,184
    float* vf   = ws + 9437184;         // 3,145,728
    float* a1   = ws + 12582912;        // 3,145,728
    float* a2   = ws + 15728640;        // 3,145,728
    float* part = ws + 12582912;        // 12,582,912 (reuses a1+a2 region)
    float* kp   = ws + 25165824;        // 49,152
    float* vp   = ws + 25214976;        // 49,152  (total ~101 MB)

    k_qkv<<<dim3(NROW/32), dim3(256), 0, stream>>>(x, Wqkv, qkv);
    k_dw5<<<dim3(NROW/32), dim3(256), 0, stream>>>(x, c0w, c0b, a1);
    k_dw7<<<dim3(NROW/32), dim3(256), 0, stream>>>(a1, cspw, cspb, a2);
    k_pw_gate<<<dim3(NROW/32), dim3(256), 0, stream>>>(a2, c1w, c1b, x, qkv, vf);
    k_ered<<<dim3(256), dim3(512), 0, stream>>>(E, qkv, vf, part);
    k_ered_fin<<<dim3(384), dim3(256), 0, stream>>>(part, kp, vp);
    k_attn<<<dim3(NROW/32), dim3(256), 0, stream>>>(qkv, kp, vp, W0, out);
}

// Round 4
// 247.686 us; speedup vs baseline: 1.7875x; 1.2676x over previous
//
#include <hip/hip_runtime.h>

#define HH_ 128
#define WW_ 128
#define LL_ (HH_*WW_)     // 16384
#define NH 8
#define DHD 12
#define KD 256
#define BB_ 2
#define NROW (BB_*LL_)    // 32768

typedef __attribute__((ext_vector_type(8))) short short8v;
typedef __attribute__((ext_vector_type(4))) float f32x4;

__device__ __forceinline__ float4 ld4(const float* p) {
    return *reinterpret_cast<const float4*>(p);
}
__device__ __forceinline__ unsigned int pk2(float a, float b) {
    unsigned int ua = __float_as_uint(a);
    unsigned int ub = __float_as_uint(b);
    ua = (ua + 0x7FFFu + ((ua >> 16) & 1u)) >> 16;
    ub = (ub + 0x7FFFu + ((ub >> 16) & 1u)) >> 16;
    return ua | (ub << 16);
}

// ---------------- K1: qkv = x @ Wqkv  (32768x96 @ 96x288) ----------------
__global__ __launch_bounds__(256) void k_qkv(const float* __restrict__ x,
                                             const float* __restrict__ Wq,
                                             float* __restrict__ qkv) {
    __shared__ float xT[96][36];      // [k][row], padded for b128 conflict-free
    __shared__ float Wl[32*288];
    const int tid = threadIdx.x;
    const int r0 = blockIdx.x * 32;
    for (int i = tid; i < 32*96; i += 256) {
        int r = i / 96, c = i % 96;
        xT[c][r] = x[(r0 + r)*96 + c];
    }
    const int cg = tid & 31, rg = tid >> 5;
    const int c0 = cg*9, rr = rg*4;
    float acc[4][9];
#pragma unroll
    for (int a = 0; a < 4; ++a)
#pragma unroll
        for (int j = 0; j < 9; ++j) acc[a][j] = 0.f;
    for (int kc = 0; kc < 3; ++kc) {
        __syncthreads();
        for (int i = tid; i < 32*288; i += 256) Wl[i] = Wq[kc*32*288 + i];
        __syncthreads();
#pragma unroll 2
        for (int k = 0; k < 32; ++k) {
            float4 a4 = ld4(&xT[kc*32 + k][rr]);
            float av[4] = {a4.x, a4.y, a4.z, a4.w};
#pragma unroll
            for (int j = 0; j < 9; ++j) {
                float w = Wl[k*288 + c0 + j];
#pragma unroll
                for (int a = 0; a < 4; ++a) acc[a][j] = fmaf(av[a], w, acc[a][j]);
            }
        }
    }
#pragma unroll
    for (int a = 0; a < 4; ++a)
#pragma unroll
        for (int j = 0; j < 9; ++j)
            qkv[(r0 + rr + a)*288 + c0 + j] = acc[a][j];
}

// ---------------- K2a: depthwise 5x5, pad 2 (channels-last) ----------------
__global__ __launch_bounds__(256) void k_dw5(const float* __restrict__ xin,
                                             const float* __restrict__ w,
                                             const float* __restrict__ bias,
                                             float* __restrict__ out) {
    __shared__ float wl[25][96];
    const int tid = threadIdx.x;
    for (int i = tid; i < 25*96; i += 256) {
        int c = i / 25, t = i % 25;
        wl[t][c] = w[i];
    }
    __syncthreads();
    const int c4 = (tid & 7)*4;
    const int px = tid >> 3;
    const int pix0 = blockIdx.x * 32;
    const int b = pix0 >> 14;
    const int y = (pix0 & 16383) >> 7;
    const int xx = (pix0 & 127) + px;
    float4 acc[3];
#pragma unroll
    for (int ch = 0; ch < 3; ++ch) { acc[ch].x=0.f; acc[ch].y=0.f; acc[ch].z=0.f; acc[ch].w=0.f; }
#pragma unroll
    for (int iy = 0; iy < 5; ++iy) {
        int y2 = y + iy - 2;
        if (y2 < 0 || y2 >= HH_) continue;
#pragma unroll
        for (int ix = 0; ix < 5; ++ix) {
            int x2 = xx + ix - 2;
            if (x2 < 0 || x2 >= WW_) continue;
            const float* src = xin + ((b << 14) + y2*WW_ + x2)*96;
            const float* wt = &wl[iy*5 + ix][0];
#pragma unroll
            for (int ch = 0; ch < 3; ++ch) {
                float4 xv = ld4(src + ch*32 + c4);
                float4 wv = ld4(wt + ch*32 + c4);
                acc[ch].x = fmaf(xv.x, wv.x, acc[ch].x);
                acc[ch].y = fmaf(xv.y, wv.y, acc[ch].y);
                acc[ch].z = fmaf(xv.z, wv.z, acc[ch].z);
                acc[ch].w = fmaf(xv.w, wv.w, acc[ch].w);
            }
        }
    }
    float* dst = out + (long)(pix0 + px)*96;
#pragma unroll
    for (int ch = 0; ch < 3; ++ch) {
        float4 bv = ld4(bias + ch*32 + c4);
        float4 r;
        r.x = acc[ch].x + bv.x; r.y = acc[ch].y + bv.y;
        r.z = acc[ch].z + bv.z; r.w = acc[ch].w + bv.w;
        *reinterpret_cast<float4*>(dst + ch*32 + c4) = r;
    }
}

// ---------------- K2b: depthwise 7x7, dilation 3, pad 9 ----------------
__global__ __launch_bounds__(256) void k_dw7(const float* __restrict__ xin,
                                             const float* __restrict__ w,
                                             const float* __restrict__ bias,
                                             float* __restrict__ out) {
    __shared__ float wl[49][96];
    const int tid = threadIdx.x;
    for (int i = tid; i < 49*96; i += 256) {
        int c = i / 49, t = i % 49;
        wl[t][c] = w[i];
    }
    __syncthreads();
    const int c4 = (tid & 7)*4;
    const int px = tid >> 3;
    const int pix0 = blockIdx.x * 32;
    const int b = pix0 >> 14;
    const int y = (pix0 & 16383) >> 7;
    const int xx = (pix0 & 127) + px;
    float4 acc[3];
#pragma unroll
    for (int ch = 0; ch < 3; ++ch) { acc[ch].x=0.f; acc[ch].y=0.f; acc[ch].z=0.f; acc[ch].w=0.f; }
#pragma unroll
    for (int iy = 0; iy < 7; ++iy) {
        int y2 = y + iy*3 - 9;
        if (y2 < 0 || y2 >= HH_) continue;
#pragma unroll
        for (int ix = 0; ix < 7; ++ix) {
            int x2 = xx + ix*3 - 9;
            if (x2 < 0 || x2 >= WW_) continue;
            const float* src = xin + ((b << 14) + y2*WW_ + x2)*96;
            const float* wt = &wl[iy*7 + ix][0];
#pragma unroll
            for (int ch = 0; ch < 3; ++ch) {
                float4 xv = ld4(src + ch*32 + c4);
                float4 wv = ld4(wt + ch*32 + c4);
                acc[ch].x = fmaf(xv.x, wv.x, acc[ch].x);
                acc[ch].y = fmaf(xv.y, wv.y, acc[ch].y);
                acc[ch].z = fmaf(xv.z, wv.z, acc[ch].z);
                acc[ch].w = fmaf(xv.w, wv.w, acc[ch].w);
            }
        }
    }
    float* dst = out + (long)(pix0 + px)*96;
#pragma unroll
    for (int ch = 0; ch < 3; ++ch) {
        float4 bv = ld4(bias + ch*32 + c4);
        float4 r;
        r.x = acc[ch].x + bv.x; r.y = acc[ch].y + bv.y;
        r.z = acc[ch].z + bv.z; r.w = acc[ch].w + bv.w;
        *reinterpret_cast<float4*>(dst + ch*32 + c4) = r;
    }
}

// ------- K2c: a3 = a2 @ w1^T + b1 ; vf = x * a3 * v  (v = qkv slice 2) -------
__global__ __launch_bounds__(256) void k_pw_gate(const float* __restrict__ a2,
        const float* __restrict__ w1, const float* __restrict__ b1,
        const float* __restrict__ xin, const float* __restrict__ qkv,
        float* __restrict__ vf) {
    __shared__ float aT[96][36];
    __shared__ float wT[96][100];    // wT[ci][o] = w1[o*96+ci]
    const int tid = threadIdx.x;
    const int r0 = blockIdx.x * 32;
    for (int i = tid; i < 32*96; i += 256) {
        int r = i / 96, c = i % 96;
        aT[c][r] = a2[(r0 + r)*96 + c];
    }
    for (int i = tid; i < 96*96; i += 256) {
        int o = i / 96, ci = i % 96;
        wT[ci][o] = w1[i];
    }
    __syncthreads();
    const int cg = tid & 31, rg = tid >> 5;
    const int c0 = cg*3, rr = rg*4;
    float acc[4][3];
#pragma unroll
    for (int r = 0; r < 4; ++r)
#pragma unroll
        for (int j = 0; j < 3; ++j) acc[r][j] = 0.f;
#pragma unroll 4
    for (int k = 0; k < 96; ++k) {
        float4 a4 = ld4(&aT[k][rr]);
        float av[4] = {a4.x, a4.y, a4.z, a4.w};
#pragma unroll
        for (int j = 0; j < 3; ++j) {
            float w = wT[k][c0 + j];
#pragma unroll
            for (int r = 0; r < 4; ++r) acc[r][j] = fmaf(av[r], w, acc[r][j]);
        }
    }
#pragma unroll
    for (int r = 0; r < 4; ++r) {
        int row = r0 + rr + r;
#pragma unroll
        for (int j = 0; j < 3; ++j) {
            int c = c0 + j;
            float g = acc[r][j] + b1[c];
            vf[row*96 + c] = xin[row*96 + c] * qkv[row*288 + 192 + c] * g;
        }
    }
}

// ------- K3a: E-reduction, retiled. grid 256 = b(2) x jc(128 chunks of 128 rows),
// 512 threads = kkg(64) x cg(8); thread owns 4kk x 12c for BOTH k and vf. -------
__global__ __launch_bounds__(512) void k_ered(const float* __restrict__ E,
        const float* __restrict__ qkv, const float* __restrict__ vf,
        float* __restrict__ part) {
    __shared__ float El[32*256];    // [jj][kk]
    __shared__ float Xk[32*96];     // [jj][c]
    __shared__ float Xv[32*96];
    const int tid = threadIdx.x;
    const int b  = blockIdx.x >> 7;
    const int jc = blockIdx.x & 127;
    const int j0 = jc * 128;
    const int cg = tid & 7, kkg = tid >> 3;
    const int kk0 = kkg*4, c0 = cg*12;
    float acck[4][12];
    float accv[4][12];
#pragma unroll
    for (int a = 0; a < 4; ++a)
#pragma unroll
        for (int c = 0; c < 12; ++c) { acck[a][c] = 0.f; accv[a][c] = 0.f; }
    for (int st = 0; st < 4; ++st) {
        __syncthreads();
        for (int i = tid; i < 32*64; i += 512) {
            int row = i >> 6, c4 = (i & 63) << 2;
            *reinterpret_cast<float4*>(&El[row*256 + c4]) =
                ld4(&E[(j0 + st*32 + row)*256 + c4]);
        }
        for (int i = tid; i < 768; i += 512) {
            int row = i / 24, c4 = (i % 24) << 2;
            int grow = b*LL_ + j0 + st*32 + row;
            *reinterpret_cast<float4*>(&Xk[row*96 + c4]) = ld4(&qkv[(long)grow*288 + 96 + c4]);
            *reinterpret_cast<float4*>(&Xv[row*96 + c4]) = ld4(&vf[(long)grow*96 + c4]);
        }
        __syncthreads();
#pragma unroll 2
        for (int j = 0; j < 32; ++j) {
            float4 e4 = ld4(&El[j*256 + kk0]);
            float ev[4] = {e4.x, e4.y, e4.z, e4.w};
            float xk[12], xv[12];
            *reinterpret_cast<float4*>(&xk[0]) = ld4(&Xk[j*96 + c0]);
            *reinterpret_cast<float4*>(&xk[4]) = ld4(&Xk[j*96 + c0 + 4]);
            *reinterpret_cast<float4*>(&xk[8]) = ld4(&Xk[j*96 + c0 + 8]);
            *reinterpret_cast<float4*>(&xv[0]) = ld4(&Xv[j*96 + c0]);
            *reinterpret_cast<float4*>(&xv[4]) = ld4(&Xv[j*96 + c0 + 4]);
            *reinterpret_cast<float4*>(&xv[8]) = ld4(&Xv[j*96 + c0 + 8]);
#pragma unroll
            for (int a = 0; a < 4; ++a) {
                float e = ev[a];
#pragma unroll
                for (int c = 0; c < 12; ++c) {
                    acck[a][c] = fmaf(e, xk[c], acck[a][c]);
                    accv[a][c] = fmaf(e, xv[c], accv[a][c]);
                }
            }
        }
    }
    // part[b][jc][m][kk][c]
#pragma unroll
    for (int a = 0; a < 4; ++a) {
        float* dk = part + ((long)(((b*128 + jc)*2 + 0)*256 + kk0 + a))*96 + c0;
        *reinterpret_cast<float4*>(dk)     = make_float4(acck[a][0], acck[a][1], acck[a][2], acck[a][3]);
        *reinterpret_cast<float4*>(dk + 4) = make_float4(acck[a][4], acck[a][5], acck[a][6], acck[a][7]);
        *reinterpret_cast<float4*>(dk + 8) = make_float4(acck[a][8], acck[a][9], acck[a][10], acck[a][11]);
        float* dv = part + ((long)(((b*128 + jc)*2 + 1)*256 + kk0 + a))*96 + c0;
        *reinterpret_cast<float4*>(dv)     = make_float4(accv[a][0], accv[a][1], accv[a][2], accv[a][3]);
        *reinterpret_cast<float4*>(dv + 4) = make_float4(accv[a][4], accv[a][5], accv[a][6], accv[a][7]);
        *reinterpret_cast<float4*>(dv + 8) = make_float4(accv[a][8], accv[a][9], accv[a][10], accv[a][11]);
    }
}

// ------- K3b: reduce partials.
// kp -> [b][h][kk][d] (kk-major, for MFMA A staging); vp -> [b][h][d][kk] -------
__global__ __launch_bounds__(256) void k_ered_fin(const float* __restrict__ part,
        float* __restrict__ kp, float* __restrict__ vp) {
    const int idx = blockIdx.x*256 + threadIdx.x;  // 2*2*256*96 = 98304
    const int c  = idx % 96;
    const int kk = (idx / 96) % 256;
    const int m  = (idx / (96*256)) % 2;
    const int b  = idx / (96*256*2);
    float s = 0.f;
    const long off = ((long)((b*128)*2 + m)*256 + kk)*96 + c;
    for (int jc = 0; jc < 128; ++jc)
        s += part[off + (long)jc*(2*256*96)];
    const int h = c / DHD, d = c % DHD;
    if (m == 0) kp[((b*NH + h)*256 + kk)*DHD + d] = s;
    else        vp[((b*NH + h)*DHD + d)*256 + kk] = s;
}

// ------- K4: fused attention via bf16 MFMA.
// Per block: 32 q-rows, 4 waves cooperate per head (8 heads serial).
// QK^T swapped (S^T = K'.Q^T, K=12 padded to 32), exp (no max-sub: |s*scale|<1),
// P packed bf16 -> LDS, PV = P.V' with K-split across waves, W0 epilogue fused.
__global__ __launch_bounds__(256) void k_attn(const float* __restrict__ qkv,
        const float* __restrict__ kpg, const float* __restrict__ vpg,
        const float* __restrict__ W0, float* __restrict__ out) {
    // LDS layout (shorts): P[32][264] @0 (16896B) | vp[16][264] @8448 (8448B)
    // | q[32][40] @12672 (2560B) | kp[256][16]+pad @13952 (8224B, aliased:
    //   opart f32[4][32][16] @13952, oh f32[32][13] @18048, rinv f32[32] @18880)
    // | ws f32[128] @18944 ; total 19200 shorts = 38400B
    __shared__ short lds[19200];
    const int P_off  = 0;
    const int vp_off = 8448;
    const int q_off  = 12672;
    const int kp_off = 13952;
    const int oh_sh  = 18048;
    const int ri_sh  = 18880;
    const int ws_sh  = 18944;

    const int tid = threadIdx.x;
    const int lane = tid & 63, wv = tid >> 6;
    const int r0 = blockIdx.x * 32;
    const int b = r0 >> 14;
    const int kg = tid & 31, rg = tid >> 5;
    const int rr = rg*4;
    const float scale = 0.28867513459481287f;  // 1/sqrt(12)
    const int l15 = lane & 15, l4 = lane >> 4;

    float acc_out[4][3];
#pragma unroll
    for (int r = 0; r < 4; ++r)
#pragma unroll
        for (int j = 0; j < 3; ++j) acc_out[r][j] = 0.f;

    // once: zero q pad slots 12..39 (staging only writes 0..11; zeros persist)
    {
        unsigned int* qz = (unsigned int*)(lds + q_off);
        for (int i = tid; i < 448; i += 256) {
            int r = i / 14, s = i % 14;
            qz[r*20 + 6 + s] = 0u;
        }
    }

    for (int h = 0; h < NH; ++h) {
        __syncthreads();   // prior head readers done (oh/P/vp/q safe to overwrite)
        // ---- stage kp[256][16] bf16 (thread=kk), vp[12][264] bf16, q[32][40] bf16 ----
        {
            const float* src = kpg + ((long)(b*NH + h)*256 + tid)*12;
            float4 x0 = ld4(src); float4 x1 = ld4(src + 4); float4 x2 = ld4(src + 8);
            unsigned int* dst = (unsigned int*)(lds + kp_off) + tid*8;
            dst[0] = pk2(x0.x, x0.y); dst[1] = pk2(x0.z, x0.w);
            dst[2] = pk2(x1.x, x1.y); dst[3] = pk2(x1.z, x1.w);
            dst[4] = pk2(x2.x, x2.y); dst[5] = pk2(x2.z, x2.w);
            dst[6] = 0u; dst[7] = 0u;
            if (tid == 255) {   // zero trailing pad row (A-frag overreach)
#pragma unroll
                for (int z = 8; z < 16; ++z) dst[z] = 0u;
            }
        }
        {
            unsigned int* vpd = (unsigned int*)(lds + vp_off);
            const float* vsrc = vpg + (long)(b*NH + h)*12*256;
            for (int i = tid; i < 1536; i += 256) {
                int d = i >> 7, kq = i & 127;
                const float* s = vsrc + d*256 + kq*2;
                vpd[d*132 + kq] = pk2(s[0], s[1]);
            }
        }
        if (tid < 192) {
            int r = tid / 6, dp = tid % 6;
            const float* s = qkv + (long)(r0 + r)*288 + h*12 + dp*2;
            ((unsigned int*)(lds + q_off))[r*20 + dp] = pk2(s[0], s[1]);
        }
        __syncthreads();
        // ---- mfma1: S^T tiles (wave w: mt=4w..4w+3, nt=0,1), exp, pack P, row-sums ----
        {
            const short* qb = lds + q_off + l15*40 + l4*8;
            short8v bq0 = *(const short8v*)(qb);
            short8v bq1 = *(const short8v*)(qb + 16*40);
            const short* ab = lds + kp_off + l15*16 + l4*8;
            unsigned int* Pw = (unsigned int*)(lds + P_off);
            float ps0 = 0.f, ps1 = 0.f;
            f32x4 z = {0.f, 0.f, 0.f, 0.f};
#pragma unroll
            for (int mi = 0; mi < 4; ++mi) {
                int mt = wv*4 + mi;
                short8v a = *(const short8v*)(ab + mt*256);
                f32x4 s0 = __builtin_amdgcn_mfma_f32_16x16x32_bf16(a, bq0, z, 0, 0, 0);
                f32x4 s1 = __builtin_amdgcn_mfma_f32_16x16x32_bf16(a, bq1, z, 0, 0, 0);
                float p0[4], p1[4];
#pragma unroll
                for (int r = 0; r < 4; ++r) {
                    p0[r] = __expf(s0[r] * scale);
                    p1[r] = __expf(s1[r] * scale);
                }
                ps0 += p0[0] + p0[1] + p0[2] + p0[3];
                ps1 += p1[0] + p1[1] + p1[2] + p1[3];
                int kkb = mt*16 + l4*4;
                unsigned int u0 = (l15*264 + kkb) >> 1;
                unsigned int u1 = ((l15 + 16)*264 + kkb) >> 1;
                Pw[u0]     = pk2(p0[0], p0[1]);
                Pw[u0 + 1] = pk2(p0[2], p0[3]);
                Pw[u1]     = pk2(p1[0], p1[1]);
                Pw[u1 + 1] = pk2(p1[2], p1[3]);
            }
            ps0 += __shfl_xor(ps0, 16, 64); ps0 += __shfl_xor(ps0, 32, 64);
            ps1 += __shfl_xor(ps1, 16, 64); ps1 += __shfl_xor(ps1, 32, 64);
            float* wsf = (float*)(lds + ws_sh);
            if (lane < 16) { wsf[wv*32 + lane] = ps0; wsf[wv*32 + 16 + lane] = ps1; }
        }
        __syncthreads();
        // ---- rinv (32 threads) in parallel with PV (K-split: wave w ksteps 2w,2w+1) ----
        {
            float* wsf = (float*)(lds + ws_sh);
            float* rin = (float*)(lds + ri_sh);
            if (tid < 32)
                rin[tid] = 1.0f / (wsf[tid] + wsf[32 + tid] + wsf[64 + tid] + wsf[96 + tid]);
            f32x4 o0 = {0.f, 0.f, 0.f, 0.f}, o1 = {0.f, 0.f, 0.f, 0.f};
#pragma unroll
            for (int kq = 0; kq < 2; ++kq) {
                int ks = wv*2 + kq;
                short8v bvf = *(const short8v*)(lds + vp_off + l15*264 + ks*32 + l4*8);
                short8v a0 = *(const short8v*)(lds + P_off + l15*264 + ks*32 + l4*8);
                short8v a1 = *(const short8v*)(lds + P_off + (16 + l15)*264 + ks*32 + l4*8);
                o0 = __builtin_amdgcn_mfma_f32_16x16x32_bf16(a0, bvf, o0, 0, 0, 0);
                o1 = __builtin_amdgcn_mfma_f32_16x16x32_bf16(a1, bvf, o1, 0, 0, 0);
            }
            float* op = (float*)(lds + kp_off);   // opart[4][32][16] (kp dead)
            int rowb = l4*4;
#pragma unroll
            for (int r = 0; r < 4; ++r) {
                op[wv*512 + (rowb + r)*16 + l15] = o0[r];
                op[wv*512 + (16 + rowb + r)*16 + l15] = o1[r];
            }
        }
        __syncthreads();
        // ---- reduce partial O across waves, normalize -> oh[32][13] ----
        {
            float* op = (float*)(lds + kp_off);
            float* rin = (float*)(lds + ri_sh);
            float* ohf = (float*)(lds + oh_sh);
            for (int t = tid; t < 384; t += 256) {
                int i = t / 12, d = t - i*12;
                float s = op[i*16 + d] + op[512 + i*16 + d]
                        + op[1024 + i*16 + d] + op[1536 + i*16 + d];
                ohf[i*13 + d] = s * rin[i];
            }
        }
        __syncthreads();
        // ---- phase C: acc_out += oh @ W0[h*12 .. h*12+11, :] ----
        {
            float* ohf = (float*)(lds + oh_sh);
            const int c0 = kg*3;
            const float* w0p = W0 + h*12*96;
#pragma unroll
            for (int d = 0; d < 12; ++d) {
                float wa = w0p[d*96 + c0];
                float wb = w0p[d*96 + c0 + 1];
                float wc = w0p[d*96 + c0 + 2];
#pragma unroll
                for (int r = 0; r < 4; ++r) {
                    float o = ohf[(rr + r)*13 + d];
                    acc_out[r][0] = fmaf(o, wa, acc_out[r][0]);
                    acc_out[r][1] = fmaf(o, wb, acc_out[r][1]);
                    acc_out[r][2] = fmaf(o, wc, acc_out[r][2]);
                }
            }
        }
    }
    const int c0 = kg*3;
#pragma unroll
    for (int r = 0; r < 4; ++r)
#pragma unroll
        for (int j = 0; j < 3; ++j)
            out[(r0 + rr + r)*96 + c0 + j] = acc_out[r][j];
}

extern "C" void kernel_launch(void* const* d_in, const int* in_sizes, int n_in,
                              void* d_out, int out_size, void* d_ws, size_t ws_size,
                              hipStream_t stream) {
    (void)in_sizes; (void)n_in; (void)out_size; (void)ws_size;
    const float* x    = (const float*)d_in[0];
    const float* Wqkv = (const float*)d_in[1];
    const float* W0   = (const float*)d_in[2];
    const float* E    = (const float*)d_in[3];
    const float* c0w  = (const float*)d_in[4];
    const float* c0b  = (const float*)d_in[5];
    const float* cspw = (const float*)d_in[6];
    const float* cspb = (const float*)d_in[7];
    const float* c1w  = (const float*)d_in[8];
    const float* c1b  = (const float*)d_in[9];
    float* out = (float*)d_out;
    float* ws  = (float*)d_ws;

    // workspace layout (floats); part overlaps a1/a2 (dead by the time K3a runs)
    float* qkv  = ws;                   // 9,437,184
    float* vf   = ws + 9437184;         // 3,145,728
    float* a1   = ws + 12582912;        // 3,145,728
    float* a2   = ws + 15728640;        // 3,145,728
    float* part = ws + 12582912;        // 12,582,912 (reuses a1+a2 region)
    float* kp   = ws + 25165824;        // 49,152
    float* vp   = ws + 25214976;        // 49,152  (total ~101 MB)

    k_qkv<<<dim3(NROW/32), dim3(256), 0, stream>>>(x, Wqkv, qkv);
    k_dw5<<<dim3(NROW/32), dim3(256), 0, stream>>>(x, c0w, c0b, a1);
    k_dw7<<<dim3(NROW/32), dim3(256), 0, stream>>>(a1, cspw, cspb, a2);
    k_pw_gate<<<dim3(NROW/32), dim3(256), 0, stream>>>(a2, c1w, c1b, x, qkv, vf);
    k_ered<<<dim3(256), dim3(512), 0, stream>>>(E, qkv, vf, part);
    k_ered_fin<<<dim3(384), dim3(256), 0, stream>>>(part, kp, vp);
    k_attn<<<dim3(NROW/32), dim3(256), 0, stream>>>(qkv, kp, vp, W0, out);
}

// Round 5
// 205.761 us; speedup vs baseline: 2.1517x; 1.2038x over previous
//
#include <hip/hip_runtime.h>

#define HH_ 128
#define WW_ 128
#define LL_ (HH_*WW_)     // 16384
#define NH 8
#define DHD 12
#define KD 256
#define BB_ 2
#define NROW (BB_*LL_)    // 32768

typedef __attribute__((ext_vector_type(8))) short short8v;
typedef __attribute__((ext_vector_type(4))) float f32x4;
typedef unsigned short ushortT;

__device__ __forceinline__ float4 ld4(const float* p) {
    return *reinterpret_cast<const float4*>(p);
}
__device__ __forceinline__ unsigned int pk2(float a, float b) {
    unsigned int ua = __float_as_uint(a);
    unsigned int ub = __float_as_uint(b);
    ua = (ua + 0x7FFFu + ((ua >> 16) & 1u)) >> 16;
    ub = (ub + 0x7FFFu + ((ub >> 16) & 1u)) >> 16;
    return ua | (ub << 16);
}
__device__ __forceinline__ ushortT bf1(float a) {
    unsigned int u = __float_as_uint(a);
    return (ushortT)((u + 0x7FFFu + ((u >> 16) & 1u)) >> 16);
}
__device__ __forceinline__ float ubf(ushortT v) {
    return __uint_as_float(((unsigned int)v) << 16);
}

// ---------------- K1: qkv = x @ Wqkv  (32768x96 @ 96x288) ----------------
__global__ __launch_bounds__(256) void k_qkv(const float* __restrict__ x,
                                             const float* __restrict__ Wq,
                                             float* __restrict__ qkv) {
    __shared__ float xT[96][36];
    __shared__ float Wl[32*288];
    const int tid = threadIdx.x;
    const int r0 = blockIdx.x * 32;
    for (int i = tid; i < 32*96; i += 256) {
        int r = i / 96, c = i % 96;
        xT[c][r] = x[(r0 + r)*96 + c];
    }
    const int cg = tid & 31, rg = tid >> 5;
    const int c0 = cg*9, rr = rg*4;
    float acc[4][9];
#pragma unroll
    for (int a = 0; a < 4; ++a)
#pragma unroll
        for (int j = 0; j < 9; ++j) acc[a][j] = 0.f;
    for (int kc = 0; kc < 3; ++kc) {
        __syncthreads();
        for (int i = tid; i < 32*288; i += 256) Wl[i] = Wq[kc*32*288 + i];
        __syncthreads();
#pragma unroll 2
        for (int k = 0; k < 32; ++k) {
            float4 a4 = ld4(&xT[kc*32 + k][rr]);
            float av[4] = {a4.x, a4.y, a4.z, a4.w};
#pragma unroll
            for (int j = 0; j < 9; ++j) {
                float w = Wl[k*288 + c0 + j];
#pragma unroll
                for (int a = 0; a < 4; ++a) acc[a][j] = fmaf(av[a], w, acc[a][j]);
            }
        }
    }
#pragma unroll
    for (int a = 0; a < 4; ++a)
#pragma unroll
        for (int j = 0; j < 9; ++j)
            qkv[(r0 + rr + a)*288 + c0 + j] = acc[a][j];
}

// ---------------- K2a: depthwise 5x5, pad 2 (channels-last) ----------------
__global__ __launch_bounds__(256) void k_dw5(const float* __restrict__ xin,
                                             const float* __restrict__ w,
                                             const float* __restrict__ bias,
                                             float* __restrict__ out) {
    __shared__ float wl[25][96];
    const int tid = threadIdx.x;
    for (int i = tid; i < 25*96; i += 256) {
        int c = i / 25, t = i % 25;
        wl[t][c] = w[i];
    }
    __syncthreads();
    const int c4 = (tid & 7)*4;
    const int px = tid >> 3;
    const int pix0 = blockIdx.x * 32;
    const int b = pix0 >> 14;
    const int y = (pix0 & 16383) >> 7;
    const int xx = (pix0 & 127) + px;
    float4 acc[3];
#pragma unroll
    for (int ch = 0; ch < 3; ++ch) { acc[ch].x=0.f; acc[ch].y=0.f; acc[ch].z=0.f; acc[ch].w=0.f; }
#pragma unroll
    for (int iy = 0; iy < 5; ++iy) {
        int y2 = y + iy - 2;
        if (y2 < 0 || y2 >= HH_) continue;
#pragma unroll
        for (int ix = 0; ix < 5; ++ix) {
            int x2 = xx + ix - 2;
            if (x2 < 0 || x2 >= WW_) continue;
            const float* src = xin + ((b << 14) + y2*WW_ + x2)*96;
            const float* wt = &wl[iy*5 + ix][0];
#pragma unroll
            for (int ch = 0; ch < 3; ++ch) {
                float4 xv = ld4(src + ch*32 + c4);
                float4 wv = ld4(wt + ch*32 + c4);
                acc[ch].x = fmaf(xv.x, wv.x, acc[ch].x);
                acc[ch].y = fmaf(xv.y, wv.y, acc[ch].y);
                acc[ch].z = fmaf(xv.z, wv.z, acc[ch].z);
                acc[ch].w = fmaf(xv.w, wv.w, acc[ch].w);
            }
        }
    }
    float* dst = out + (long)(pix0 + px)*96;
#pragma unroll
    for (int ch = 0; ch < 3; ++ch) {
        float4 bv = ld4(bias + ch*32 + c4);
        float4 r;
        r.x = acc[ch].x + bv.x; r.y = acc[ch].y + bv.y;
        r.z = acc[ch].z + bv.z; r.w = acc[ch].w + bv.w;
        *reinterpret_cast<float4*>(dst + ch*32 + c4) = r;
    }
}

// ---------------- K2b: depthwise 7x7, dilation 3, pad 9 ----------------
__global__ __launch_bounds__(256) void k_dw7(const float* __restrict__ xin,
                                             const float* __restrict__ w,
                                             const float* __restrict__ bias,
                                             float* __restrict__ out) {
    __shared__ float wl[49][96];
    const int tid = threadIdx.x;
    for (int i = tid; i < 49*96; i += 256) {
        int c = i / 49, t = i % 49;
        wl[t][c] = w[i];
    }
    __syncthreads();
    const int c4 = (tid & 7)*4;
    const int px = tid >> 3;
    const int pix0 = blockIdx.x * 32;
    const int b = pix0 >> 14;
    const int y = (pix0 & 16383) >> 7;
    const int xx = (pix0 & 127) + px;
    float4 acc[3];
#pragma unroll
    for (int ch = 0; ch < 3; ++ch) { acc[ch].x=0.f; acc[ch].y=0.f; acc[ch].z=0.f; acc[ch].w=0.f; }
#pragma unroll
    for (int iy = 0; iy < 7; ++iy) {
        int y2 = y + iy*3 - 9;
        if (y2 < 0 || y2 >= HH_) continue;
#pragma unroll
        for (int ix = 0; ix < 7; ++ix) {
            int x2 = xx + ix*3 - 9;
            if (x2 < 0 || x2 >= WW_) continue;
            const float* src = xin + ((b << 14) + y2*WW_ + x2)*96;
            const float* wt = &wl[iy*7 + ix][0];
#pragma unroll
            for (int ch = 0; ch < 3; ++ch) {
                float4 xv = ld4(src + ch*32 + c4);
                float4 wv = ld4(wt + ch*32 + c4);
                acc[ch].x = fmaf(xv.x, wv.x, acc[ch].x);
                acc[ch].y = fmaf(xv.y, wv.y, acc[ch].y);
                acc[ch].z = fmaf(xv.z, wv.z, acc[ch].z);
                acc[ch].w = fmaf(xv.w, wv.w, acc[ch].w);
            }
        }
    }
    float* dst = out + (long)(pix0 + px)*96;
#pragma unroll
    for (int ch = 0; ch < 3; ++ch) {
        float4 bv = ld4(bias + ch*32 + c4);
        float4 r;
        r.x = acc[ch].x + bv.x; r.y = acc[ch].y + bv.y;
        r.z = acc[ch].z + bv.z; r.w = acc[ch].w + bv.w;
        *reinterpret_cast<float4*>(dst + ch*32 + c4) = r;
    }
}

// ------- K2c: a3 = a2 @ w1^T + b1 ; vf = x * a3 * v  (v = qkv slice 2) -------
__global__ __launch_bounds__(256) void k_pw_gate(const float* __restrict__ a2,
        const float* __restrict__ w1, const float* __restrict__ b1,
        const float* __restrict__ xin, const float* __restrict__ qkv,
        float* __restrict__ vf) {
    __shared__ float aT[96][36];
    __shared__ float wT[96][100];
    const int tid = threadIdx.x;
    const int r0 = blockIdx.x * 32;
    for (int i = tid; i < 32*96; i += 256) {
        int r = i / 96, c = i % 96;
        aT[c][r] = a2[(r0 + r)*96 + c];
    }
    for (int i = tid; i < 96*96; i += 256) {
        int o = i / 96, ci = i % 96;
        wT[ci][o] = w1[i];
    }
    __syncthreads();
    const int cg = tid & 31, rg = tid >> 5;
    const int c0 = cg*3, rr = rg*4;
    float acc[4][3];
#pragma unroll
    for (int r = 0; r < 4; ++r)
#pragma unroll
        for (int j = 0; j < 3; ++j) acc[r][j] = 0.f;
#pragma unroll 4
    for (int k = 0; k < 96; ++k) {
        float4 a4 = ld4(&aT[k][rr]);
        float av[4] = {a4.x, a4.y, a4.z, a4.w};
#pragma unroll
        for (int j = 0; j < 3; ++j) {
            float w = wT[k][c0 + j];
#pragma unroll
            for (int r = 0; r < 4; ++r) acc[r][j] = fmaf(av[r], w, acc[r][j]);
        }
    }
#pragma unroll
    for (int r = 0; r < 4; ++r) {
        int row = r0 + rr + r;
#pragma unroll
        for (int j = 0; j < 3; ++j) {
            int c = c0 + j;
            float g = acc[r][j] + b1[c];
            vf[row*96 + c] = xin[row*96 + c] * qkv[row*288 + 192 + c] * g;
        }
    }
}

// ------- K3a: E-reduction; partials written in bf16 (halves traffic) -------
__global__ __launch_bounds__(512) void k_ered(const float* __restrict__ E,
        const float* __restrict__ qkv, const float* __restrict__ vf,
        ushortT* __restrict__ part16) {
    __shared__ float El[32*256];
    __shared__ float Xk[32*96];
    __shared__ float Xv[32*96];
    const int tid = threadIdx.x;
    const int b  = blockIdx.x >> 7;
    const int jc = blockIdx.x & 127;
    const int j0 = jc * 128;
    const int cg = tid & 7, kkg = tid >> 3;
    const int kk0 = kkg*4, c0 = cg*12;
    float acck[4][12];
    float accv[4][12];
#pragma unroll
    for (int a = 0; a < 4; ++a)
#pragma unroll
        for (int c = 0; c < 12; ++c) { acck[a][c] = 0.f; accv[a][c] = 0.f; }
    for (int st = 0; st < 4; ++st) {
        __syncthreads();
        for (int i = tid; i < 32*64; i += 512) {
            int row = i >> 6, c4 = (i & 63) << 2;
            *reinterpret_cast<float4*>(&El[row*256 + c4]) =
                ld4(&E[(j0 + st*32 + row)*256 + c4]);
        }
        for (int i = tid; i < 768; i += 512) {
            int row = i / 24, c4 = (i % 24) << 2;
            int grow = b*LL_ + j0 + st*32 + row;
            *reinterpret_cast<float4*>(&Xk[row*96 + c4]) = ld4(&qkv[(long)grow*288 + 96 + c4]);
            *reinterpret_cast<float4*>(&Xv[row*96 + c4]) = ld4(&vf[(long)grow*96 + c4]);
        }
        __syncthreads();
#pragma unroll 2
        for (int j = 0; j < 32; ++j) {
            float4 e4 = ld4(&El[j*256 + kk0]);
            float ev[4] = {e4.x, e4.y, e4.z, e4.w};
            float xk[12], xv[12];
            *reinterpret_cast<float4*>(&xk[0]) = ld4(&Xk[j*96 + c0]);
            *reinterpret_cast<float4*>(&xk[4]) = ld4(&Xk[j*96 + c0 + 4]);
            *reinterpret_cast<float4*>(&xk[8]) = ld4(&Xk[j*96 + c0 + 8]);
            *reinterpret_cast<float4*>(&xv[0]) = ld4(&Xv[j*96 + c0]);
            *reinterpret_cast<float4*>(&xv[4]) = ld4(&Xv[j*96 + c0 + 4]);
            *reinterpret_cast<float4*>(&xv[8]) = ld4(&Xv[j*96 + c0 + 8]);
#pragma unroll
            for (int a = 0; a < 4; ++a) {
                float e = ev[a];
#pragma unroll
                for (int c = 0; c < 12; ++c) {
                    acck[a][c] = fmaf(e, xk[c], acck[a][c]);
                    accv[a][c] = fmaf(e, xv[c], accv[a][c]);
                }
            }
        }
    }
    // part16[b][jc][m][kk][c] bf16
#pragma unroll
    for (int a = 0; a < 4; ++a) {
        long rk = ((long)((b*128 + jc)*2 + 0)*256 + kk0 + a)*96 + c0;
        unsigned int* dk = (unsigned int*)(part16 + rk);
        dk[0] = pk2(acck[a][0], acck[a][1]);
        dk[1] = pk2(acck[a][2], acck[a][3]);
        dk[2] = pk2(acck[a][4], acck[a][5]);
        dk[3] = pk2(acck[a][6], acck[a][7]);
        dk[4] = pk2(acck[a][8], acck[a][9]);
        dk[5] = pk2(acck[a][10], acck[a][11]);
        long rv = ((long)((b*128 + jc)*2 + 1)*256 + kk0 + a)*96 + c0;
        unsigned int* dv = (unsigned int*)(part16 + rv);
        dv[0] = pk2(accv[a][0], accv[a][1]);
        dv[1] = pk2(accv[a][2], accv[a][3]);
        dv[2] = pk2(accv[a][4], accv[a][5]);
        dv[3] = pk2(accv[a][6], accv[a][7]);
        dv[4] = pk2(accv[a][8], accv[a][9]);
        dv[5] = pk2(accv[a][10], accv[a][11]);
    }
}

// ------- K3b: reduce partials -> bf16 kp16[b][h][kk][16] (pads 12..15 = 0),
//                                  bf16 vp16[b][h][16][256] (rows 12..15 unused) -------
__global__ __launch_bounds__(256) void k_ered_fin(const ushortT* __restrict__ part16,
        ushortT* __restrict__ kp16, ushortT* __restrict__ vp16) {
    const int idx = blockIdx.x*256 + threadIdx.x;  // 2*2*256*96 = 98304
    const int c  = idx % 96;
    const int kk = (idx / 96) % 256;
    const int m  = (idx / (96*256)) % 2;
    const int b  = idx / (96*256*2);
    float s = 0.f;
    int off = ((b*256 + m)*256 + kk)*96 + c;
    for (int jc = 0; jc < 128; ++jc) {
        s += ubf(part16[off]);
        off += 49152;
    }
    const int h = c / DHD, d = c % DHD;
    ushortT v = bf1(s);
    if (m == 0) {
        kp16[((b*NH + h)*256 + kk)*16 + d] = v;
        if (d < 4) kp16[((b*NH + h)*256 + kk)*16 + 12 + d] = 0;
    } else {
        vp16[((b*NH + h)*16 + d)*256 + kk] = v;
    }
}

// ------- K4: attention core. A/B fragments from global bf16 (L2-hot);
// per head: [stage q] B [QK->exp->P LDS] B [PV + rinv] B [reduce -> obuf bf16] -------
__global__ __launch_bounds__(256) void k_attn(const float* __restrict__ qkv,
        const ushortT* __restrict__ kp16, const ushortT* __restrict__ vp16,
        ushortT* __restrict__ obuf) {
    // shorts: P[32][264] @0 | q[32][40] @8448 | opart f32[4][32][16] @9728
    // | rinv f32[32] @13824 | ws f32[128] @13888 ; total 14144 shorts = 28288B
    __shared__ short lds[14144];
    const int P_s = 0;
    const int q_s = 8448;
    const int op_s = 9728;
    const int ri_s = 13824;
    const int ws_s = 13888;
    const int tid = threadIdx.x;
    const int lane = tid & 63, wv = tid >> 6;
    const int l15 = lane & 15, l4 = lane >> 4;
    const int r0 = blockIdx.x * 32;
    const int b = r0 >> 14;
    const float scale = 0.28867513459481287f;  // 1/sqrt(12)
    unsigned int* qu = (unsigned int*)(lds + q_s);
    // zero q pad slots 12..39 once (per-head staging writes only 0..11)
    for (int i = tid; i < 448; i += 256) {
        int r = i / 14, sz = i % 14;
        qu[r*20 + 6 + sz] = 0u;
    }
    for (int h = 0; h < NH; ++h) {
        if (tid < 192) {
            int r = tid / 6, dp = tid % 6;
            const float* sq = qkv + (long)(r0 + r)*288 + h*12 + dp*2;
            qu[r*20 + dp] = pk2(sq[0], sq[1]);
        }
        __syncthreads();
        // ---- QK: S^T = K' . Q^T ; exp ; pack P bf16 to LDS ; row sums ----
        {
            short8v bq0 = *(const short8v*)(lds + q_s + l15*40 + l4*8);
            short8v bq1 = *(const short8v*)(lds + q_s + (l15 + 16)*40 + l4*8);
            const ushortT* kpb = kp16 + ((long)(b*NH + h)*256)*16 + l15*16 + l4*8;
            unsigned int* Pw = (unsigned int*)(lds + P_s);
            float ps0 = 0.f, ps1 = 0.f;
            f32x4 z = {0.f, 0.f, 0.f, 0.f};
#pragma unroll
            for (int mi = 0; mi < 4; ++mi) {
                int mt = wv*4 + mi;
                short8v a = *(const short8v*)(kpb + mt*256);
                f32x4 s0 = __builtin_amdgcn_mfma_f32_16x16x32_bf16(a, bq0, z, 0, 0, 0);
                f32x4 s1 = __builtin_amdgcn_mfma_f32_16x16x32_bf16(a, bq1, z, 0, 0, 0);
                float p0[4], p1[4];
#pragma unroll
                for (int r = 0; r < 4; ++r) {
                    p0[r] = __expf(s0[r] * scale);
                    p1[r] = __expf(s1[r] * scale);
                }
                ps0 += p0[0] + p0[1] + p0[2] + p0[3];
                ps1 += p1[0] + p1[1] + p1[2] + p1[3];
                int kkb = mt*16 + l4*4;
                unsigned int u0 = (l15*264 + kkb) >> 1;
                unsigned int u1 = ((l15 + 16)*264 + kkb) >> 1;
                Pw[u0]     = pk2(p0[0], p0[1]);
                Pw[u0 + 1] = pk2(p0[2], p0[3]);
                Pw[u1]     = pk2(p1[0], p1[1]);
                Pw[u1 + 1] = pk2(p1[2], p1[3]);
            }
            ps0 += __shfl_xor(ps0, 16, 64); ps0 += __shfl_xor(ps0, 32, 64);
            ps1 += __shfl_xor(ps1, 16, 64); ps1 += __shfl_xor(ps1, 32, 64);
            float* wsf = (float*)(lds + ws_s);
            if (lane < 16) { wsf[wv*32 + lane] = ps0; wsf[wv*32 + 16 + lane] = ps1; }
        }
        __syncthreads();
        // ---- PV (B-frags from global vp16) + rinv ----
        {
            float* wsf = (float*)(lds + ws_s);
            float* rin = (float*)(lds + ri_s);
            if (tid < 32)
                rin[tid] = 1.0f / (wsf[tid] + wsf[32 + tid] + wsf[64 + tid] + wsf[96 + tid]);
            f32x4 o0 = {0.f, 0.f, 0.f, 0.f}, o1 = {0.f, 0.f, 0.f, 0.f};
            const ushortT* vb = vp16 + ((long)(b*NH + h)*16 + l15)*256 + l4*8;
#pragma unroll
            for (int kq = 0; kq < 2; ++kq) {
                int ks = wv*2 + kq;
                short8v bvf = *(const short8v*)(vb + ks*32);
                short8v a0 = *(const short8v*)(lds + P_s + l15*264 + ks*32 + l4*8);
                short8v a1 = *(const short8v*)(lds + P_s + (16 + l15)*264 + ks*32 + l4*8);
                o0 = __builtin_amdgcn_mfma_f32_16x16x32_bf16(a0, bvf, o0, 0, 0, 0);
                o1 = __builtin_amdgcn_mfma_f32_16x16x32_bf16(a1, bvf, o1, 0, 0, 0);
            }
            float* op = (float*)(lds + op_s);
            int rowb = l4*4;
#pragma unroll
            for (int r = 0; r < 4; ++r) {
                op[wv*512 + (rowb + r)*16 + l15] = o0[r];
                op[wv*512 + (16 + rowb + r)*16 + l15] = o1[r];
            }
        }
        __syncthreads();
        // ---- reduce across waves, normalize, store obuf bf16 ----
        if (tid < 192) {
            float* op = (float*)(lds + op_s);
            float* rin = (float*)(lds + ri_s);
            int i = tid / 6, dp = tid % 6;
            float ri = rin[i];
            int o = i*16 + dp*2;
            float s0 = (op[o] + op[512 + o] + op[1024 + o] + op[1536 + o]) * ri;
            float s1 = (op[o+1] + op[512 + o+1] + op[1024 + o+1] + op[1536 + o+1]) * ri;
            ((unsigned int*)obuf)[(r0 + i)*48 + h*6 + dp] = pk2(s0, s1);
        }
    }
}

// ------- K5: out = o @ W0 via MFMA (64-row blocks) -------
__global__ __launch_bounds__(256) void k_out(const ushortT* __restrict__ obuf,
        const float* __restrict__ W0, float* __restrict__ out) {
    __shared__ ushortT ol[64*104];     // 13312B, padded stride
    __shared__ ushortT w0t[96*104];    // 19968B, W0 transposed [n][k]
    const int tid = threadIdx.x;
    const int r0 = blockIdx.x * 64;
    for (int i = tid; i < 768; i += 256) {
        int r = i / 12, sg = i % 12;
        *reinterpret_cast<uint4*>(&ol[r*104 + sg*8]) =
            *reinterpret_cast<const uint4*>(&obuf[(long)(r0 + r)*96 + sg*8]);
    }
    for (int i = tid; i < 9216; i += 256) {
        int k = i / 96, n = i % 96;
        w0t[n*104 + k] = bf1(W0[i]);
    }
    __syncthreads();
    const int lane = tid & 63, wv = tid >> 6;
    const int l15 = lane & 15, l4 = lane >> 4;
#pragma unroll
    for (int nt = 0; nt < 6; ++nt) {
        f32x4 acc = {0.f, 0.f, 0.f, 0.f};
#pragma unroll
        for (int kt = 0; kt < 3; ++kt) {
            short8v a = *(const short8v*)((const short*)ol + (wv*16 + l15)*104 + kt*32 + l4*8);
            short8v bw = *(const short8v*)((const short*)w0t + (nt*16 + l15)*104 + kt*32 + l4*8);
            acc = __builtin_amdgcn_mfma_f32_16x16x32_bf16(a, bw, acc, 0, 0, 0);
        }
#pragma unroll
        for (int r = 0; r < 4; ++r)
            out[(long)(r0 + wv*16 + l4*4 + r)*96 + nt*16 + l15] = acc[r];
    }
}

extern "C" void kernel_launch(void* const* d_in, const int* in_sizes, int n_in,
                              void* d_out, int out_size, void* d_ws, size_t ws_size,
                              hipStream_t stream) {
    (void)in_sizes; (void)n_in; (void)out_size; (void)ws_size;
    const float* x    = (const float*)d_in[0];
    const float* Wqkv = (const float*)d_in[1];
    const float* W0   = (const float*)d_in[2];
    const float* E    = (const float*)d_in[3];
    const float* c0w  = (const float*)d_in[4];
    const float* c0b  = (const float*)d_in[5];
    const float* cspw = (const float*)d_in[6];
    const float* cspb = (const float*)d_in[7];
    const float* c1w  = (const float*)d_in[8];
    const float* c1b  = (const float*)d_in[9];
    float* out = (float*)d_out;
    float* ws  = (float*)d_ws;

    // ws layout (float offsets):
    // qkv 0..9437184 | vf @9437184 | a1 @12582912 | a2 @15728640
    // part16 (25MB bf16) overlays a1+a2 @12582912 (dead when k_ered runs)
    // obuf bf16 overlays part16 region @12582912 (part dead after fin)
    // kp16 @25165824 (32768 f) | vp16 @25198592 (32768 f)
    float* qkv  = ws;
    float* vf   = ws + 9437184;
    float* a1   = ws + 12582912;
    float* a2   = ws + 15728640;
    ushortT* part16 = (ushortT*)(ws + 12582912);
    ushortT* obuf   = (ushortT*)(ws + 12582912);
    ushortT* kp16   = (ushortT*)(ws + 25165824);
    ushortT* vp16   = (ushortT*)(ws + 25198592);

    k_qkv<<<dim3(NROW/32), dim3(256), 0, stream>>>(x, Wqkv, qkv);
    k_dw5<<<dim3(NROW/32), dim3(256), 0, stream>>>(x, c0w, c0b, a1);
    k_dw7<<<dim3(NROW/32), dim3(256), 0, stream>>>(a1, cspw, cspb, a2);
    k_pw_gate<<<dim3(NROW/32), dim3(256), 0, stream>>>(a2, c1w, c1b, x, qkv, vf);
    k_ered<<<dim3(256), dim3(512), 0, stream>>>(E, qkv, vf, part16);
    k_ered_fin<<<dim3(384), dim3(256), 0, stream>>>(part16, kp16, vp16);
    k_attn<<<dim3(NROW/32), dim3(256), 0, stream>>>(qkv, kp16, vp16, obuf);
    k_out<<<dim3(NROW/64), dim3(256), 0, stream>>>(obuf, W0, out);
}

// Round 6
// 194.997 us; speedup vs baseline: 2.2704x; 1.0552x over previous
//
#include <hip/hip_runtime.h>

#define HH_ 128
#define WW_ 128
#define LL_ (HH_*WW_)     // 16384
#define NH 8
#define DHD 12
#define KD 256
#define BB_ 2
#define NROW (BB_*LL_)    // 32768

typedef __attribute__((ext_vector_type(8))) short short8v;
typedef __attribute__((ext_vector_type(4))) float f32x4;
typedef unsigned short ushortT;

__device__ __forceinline__ float4 ld4(const float* p) {
    return *reinterpret_cast<const float4*>(p);
}
__device__ __forceinline__ unsigned int pk2(float a, float b) {
    unsigned int ua = __float_as_uint(a);
    unsigned int ub = __float_as_uint(b);
    ua = (ua + 0x7FFFu + ((ua >> 16) & 1u)) >> 16;
    ub = (ub + 0x7FFFu + ((ub >> 16) & 1u)) >> 16;
    return ua | (ub << 16);
}
__device__ __forceinline__ ushortT bf1(float a) {
    unsigned int u = __float_as_uint(a);
    return (ushortT)((u + 0x7FFFu + ((u >> 16) & 1u)) >> 16);
}
__device__ __forceinline__ float ubf(ushortT v) {
    return __uint_as_float(((unsigned int)v) << 16);
}

// ------- K0: pre-transpose weights to bf16 [n][k] for MFMA B/A-frags -------
__global__ __launch_bounds__(256) void k_prep(const float* __restrict__ Wq,
        const float* __restrict__ W0, ushortT* __restrict__ wqT,
        ushortT* __restrict__ w0T) {
    int i = blockIdx.x*256 + threadIdx.x;
    if (i < 288*96) {
        int n = i / 96, k = i % 96;
        wqT[n*96 + k] = bf1(Wq[k*288 + n]);
    } else if (i < 288*96 + 96*96) {
        int j = i - 288*96;
        int n = j / 96, k = j % 96;
        w0T[n*96 + k] = bf1(W0[k*96 + n]);
    }
}

// ------- K1: qkv16 = bf16(x @ Wqkv) via MFMA. 64 rows/block, A=Wq^T global -------
__global__ __launch_bounds__(256) void k_qkv(const float* __restrict__ x,
        const ushortT* __restrict__ wqT, ushortT* __restrict__ qkv16) {
    __shared__ ushortT xb[64*104];
    const int tid = threadIdx.x;
    const int r0w = blockIdx.x * 64;
    for (int i = tid; i < 64*48; i += 256) {
        int r = i / 48, cp = i % 48;
        const float* sp = x + (long)(r0w + r)*96 + cp*2;
        ((unsigned int*)xb)[r*52 + cp] = pk2(sp[0], sp[1]);
    }
    __syncthreads();
    const int lane = tid & 63, wv = tid >> 6;
    const int l15 = lane & 15, l4 = lane >> 4;
    short8v bx[3];
#pragma unroll
    for (int kt = 0; kt < 3; ++kt)
        bx[kt] = *(const short8v*)((const short*)xb + (wv*16 + l15)*104 + kt*32 + l4*8);
#pragma unroll 2
    for (int mt = 0; mt < 18; ++mt) {
        f32x4 acc = {0.f, 0.f, 0.f, 0.f};
#pragma unroll
        for (int kt = 0; kt < 3; ++kt) {
            short8v a = *(const short8v*)((const short*)wqT + (mt*16 + l15)*96 + kt*32 + l4*8);
            acc = __builtin_amdgcn_mfma_f32_16x16x32_bf16(a, bx[kt], acc, 0, 0, 0);
        }
        // D: n(col)=l15 -> x-row; m(row)=l4*4+r -> weight col (consecutive -> pack)
        unsigned int* q32 = (unsigned int*)(qkv16 + (long)(r0w + wv*16 + l15)*288 + mt*16 + l4*4);
        q32[0] = pk2(acc[0], acc[1]);
        q32[1] = pk2(acc[2], acc[3]);
    }
}

// ---------------- K2a: depthwise 5x5, pad 2 (channels-last) ----------------
__global__ __launch_bounds__(256) void k_dw5(const float* __restrict__ xin,
                                             const float* __restrict__ w,
                                             const float* __restrict__ bias,
                                             float* __restrict__ out) {
    __shared__ float wl[25][96];
    const int tid = threadIdx.x;
    for (int i = tid; i < 25*96; i += 256) {
        int c = i / 25, t = i % 25;
        wl[t][c] = w[i];
    }
    __syncthreads();
    const int c4 = (tid & 7)*4;
    const int px = tid >> 3;
    const int pix0 = blockIdx.x * 32;
    const int b = pix0 >> 14;
    const int y = (pix0 & 16383) >> 7;
    const int xx = (pix0 & 127) + px;
    float4 acc[3];
#pragma unroll
    for (int ch = 0; ch < 3; ++ch) { acc[ch].x=0.f; acc[ch].y=0.f; acc[ch].z=0.f; acc[ch].w=0.f; }
#pragma unroll
    for (int iy = 0; iy < 5; ++iy) {
        int y2 = y + iy - 2;
        if (y2 < 0 || y2 >= HH_) continue;
#pragma unroll
        for (int ix = 0; ix < 5; ++ix) {
            int x2 = xx + ix - 2;
            if (x2 < 0 || x2 >= WW_) continue;
            const float* src = xin + ((b << 14) + y2*WW_ + x2)*96;
            const float* wt = &wl[iy*5 + ix][0];
#pragma unroll
            for (int ch = 0; ch < 3; ++ch) {
                float4 xv = ld4(src + ch*32 + c4);
                float4 wv = ld4(wt + ch*32 + c4);
                acc[ch].x = fmaf(xv.x, wv.x, acc[ch].x);
                acc[ch].y = fmaf(xv.y, wv.y, acc[ch].y);
                acc[ch].z = fmaf(xv.z, wv.z, acc[ch].z);
                acc[ch].w = fmaf(xv.w, wv.w, acc[ch].w);
            }
        }
    }
    float* dst = out + (long)(pix0 + px)*96;
#pragma unroll
    for (int ch = 0; ch < 3; ++ch) {
        float4 bv = ld4(bias + ch*32 + c4);
        float4 r;
        r.x = acc[ch].x + bv.x; r.y = acc[ch].y + bv.y;
        r.z = acc[ch].z + bv.z; r.w = acc[ch].w + bv.w;
        *reinterpret_cast<float4*>(dst + ch*32 + c4) = r;
    }
}

// ---------------- K2b: depthwise 7x7, dilation 3, pad 9 ----------------
__global__ __launch_bounds__(256) void k_dw7(const float* __restrict__ xin,
                                             const float* __restrict__ w,
                                             const float* __restrict__ bias,
                                             float* __restrict__ out) {
    __shared__ float wl[49][96];
    const int tid = threadIdx.x;
    for (int i = tid; i < 49*96; i += 256) {
        int c = i / 49, t = i % 49;
        wl[t][c] = w[i];
    }
    __syncthreads();
    const int c4 = (tid & 7)*4;
    const int px = tid >> 3;
    const int pix0 = blockIdx.x * 32;
    const int b = pix0 >> 14;
    const int y = (pix0 & 16383) >> 7;
    const int xx = (pix0 & 127) + px;
    float4 acc[3];
#pragma unroll
    for (int ch = 0; ch < 3; ++ch) { acc[ch].x=0.f; acc[ch].y=0.f; acc[ch].z=0.f; acc[ch].w=0.f; }
#pragma unroll
    for (int iy = 0; iy < 7; ++iy) {
        int y2 = y + iy*3 - 9;
        if (y2 < 0 || y2 >= HH_) continue;
#pragma unroll
        for (int ix = 0; ix < 7; ++ix) {
            int x2 = xx + ix*3 - 9;
            if (x2 < 0 || x2 >= WW_) continue;
            const float* src = xin + ((b << 14) + y2*WW_ + x2)*96;
            const float* wt = &wl[iy*7 + ix][0];
#pragma unroll
            for (int ch = 0; ch < 3; ++ch) {
                float4 xv = ld4(src + ch*32 + c4);
                float4 wv = ld4(wt + ch*32 + c4);
                acc[ch].x = fmaf(xv.x, wv.x, acc[ch].x);
                acc[ch].y = fmaf(xv.y, wv.y, acc[ch].y);
                acc[ch].z = fmaf(xv.z, wv.z, acc[ch].z);
                acc[ch].w = fmaf(xv.w, wv.w, acc[ch].w);
            }
        }
    }
    float* dst = out + (long)(pix0 + px)*96;
#pragma unroll
    for (int ch = 0; ch < 3; ++ch) {
        float4 bv = ld4(bias + ch*32 + c4);
        float4 r;
        r.x = acc[ch].x + bv.x; r.y = acc[ch].y + bv.y;
        r.z = acc[ch].z + bv.z; r.w = acc[ch].w + bv.w;
        *reinterpret_cast<float4*>(dst + ch*32 + c4) = r;
    }
}

// ------- K2c: a3 = a2 @ w1^T + b1 ; vf = x * a3 * v (v from bf16 qkv16) -------
__global__ __launch_bounds__(256) void k_pw_gate(const float* __restrict__ a2,
        const float* __restrict__ w1, const float* __restrict__ b1,
        const float* __restrict__ xin, const ushortT* __restrict__ qkv16,
        float* __restrict__ vf) {
    __shared__ float aT[96][36];
    __shared__ float wT[96][100];
    const int tid = threadIdx.x;
    const int r0 = blockIdx.x * 32;
    for (int i = tid; i < 32*96; i += 256) {
        int r = i / 96, c = i % 96;
        aT[c][r] = a2[(r0 + r)*96 + c];
    }
    for (int i = tid; i < 96*96; i += 256) {
        int o = i / 96, ci = i % 96;
        wT[ci][o] = w1[i];
    }
    __syncthreads();
    const int cg = tid & 31, rg = tid >> 5;
    const int c0 = cg*3, rr = rg*4;
    float acc[4][3];
#pragma unroll
    for (int r = 0; r < 4; ++r)
#pragma unroll
        for (int j = 0; j < 3; ++j) acc[r][j] = 0.f;
#pragma unroll 4
    for (int k = 0; k < 96; ++k) {
        float4 a4 = ld4(&aT[k][rr]);
        float av[4] = {a4.x, a4.y, a4.z, a4.w};
#pragma unroll
        for (int j = 0; j < 3; ++j) {
            float w = wT[k][c0 + j];
#pragma unroll
            for (int r = 0; r < 4; ++r) acc[r][j] = fmaf(av[r], w, acc[r][j]);
        }
    }
#pragma unroll
    for (int r = 0; r < 4; ++r) {
        int row = r0 + rr + r;
#pragma unroll
        for (int j = 0; j < 3; ++j) {
            int c = c0 + j;
            float g = acc[r][j] + b1[c];
            float v = ubf(qkv16[(long)row*288 + 192 + c]);
            vf[row*96 + c] = xin[row*96 + c] * v * g;
        }
    }
}

// ------- K3a: E-reduction, 64-row j-chunks (grid 512 -> 2 blocks/CU) -------
__global__ __launch_bounds__(512) void k_ered(const float* __restrict__ E,
        const ushortT* __restrict__ qkv16, const float* __restrict__ vf,
        ushortT* __restrict__ part16) {
    __shared__ float El[32*256];
    __shared__ float Xk[32*96];
    __shared__ float Xv[32*96];
    const int tid = threadIdx.x;
    const int b  = blockIdx.x >> 8;
    const int jc = blockIdx.x & 255;
    const int j0 = jc * 64;
    const int cg = tid & 7, kkg = tid >> 3;
    const int kk0 = kkg*4, c0 = cg*12;
    float acck[4][12];
    float accv[4][12];
#pragma unroll
    for (int a = 0; a < 4; ++a)
#pragma unroll
        for (int c = 0; c < 12; ++c) { acck[a][c] = 0.f; accv[a][c] = 0.f; }
    for (int st = 0; st < 2; ++st) {
        __syncthreads();
        for (int i = tid; i < 32*64; i += 512) {
            int row = i >> 6, c4 = (i & 63) << 2;
            *reinterpret_cast<float4*>(&El[row*256 + c4]) =
                ld4(&E[(j0 + st*32 + row)*256 + c4]);
        }
        for (int i = tid; i < 768; i += 512) {
            int row = i / 24, cq = i % 24;
            int grow = b*LL_ + j0 + st*32 + row;
            uint2 kk2 = *reinterpret_cast<const uint2*>(qkv16 + (long)grow*288 + 96 + cq*4);
            float4 kf;
            kf.x = ubf((ushortT)(kk2.x & 0xFFFF));
            kf.y = ubf((ushortT)(kk2.x >> 16));
            kf.z = ubf((ushortT)(kk2.y & 0xFFFF));
            kf.w = ubf((ushortT)(kk2.y >> 16));
            *reinterpret_cast<float4*>(&Xk[row*96 + cq*4]) = kf;
            *reinterpret_cast<float4*>(&Xv[row*96 + cq*4]) = ld4(&vf[(long)grow*96 + cq*4]);
        }
        __syncthreads();
#pragma unroll 2
        for (int j = 0; j < 32; ++j) {
            float4 e4 = ld4(&El[j*256 + kk0]);
            float ev[4] = {e4.x, e4.y, e4.z, e4.w};
            float xk[12], xv[12];
            *reinterpret_cast<float4*>(&xk[0]) = ld4(&Xk[j*96 + c0]);
            *reinterpret_cast<float4*>(&xk[4]) = ld4(&Xk[j*96 + c0 + 4]);
            *reinterpret_cast<float4*>(&xk[8]) = ld4(&Xk[j*96 + c0 + 8]);
            *reinterpret_cast<float4*>(&xv[0]) = ld4(&Xv[j*96 + c0]);
            *reinterpret_cast<float4*>(&xv[4]) = ld4(&Xv[j*96 + c0 + 4]);
            *reinterpret_cast<float4*>(&xv[8]) = ld4(&Xv[j*96 + c0 + 8]);
#pragma unroll
            for (int a = 0; a < 4; ++a) {
                float e = ev[a];
#pragma unroll
                for (int c = 0; c < 12; ++c) {
                    acck[a][c] = fmaf(e, xk[c], acck[a][c]);
                    accv[a][c] = fmaf(e, xv[c], accv[a][c]);
                }
            }
        }
    }
    // part16[b][jc(256)][m][kk][c] bf16
#pragma unroll
    for (int a = 0; a < 4; ++a) {
        long rk = ((long)((b*256 + jc)*2 + 0)*256 + kk0 + a)*96 + c0;
        unsigned int* dk = (unsigned int*)(part16 + rk);
        dk[0] = pk2(acck[a][0], acck[a][1]);
        dk[1] = pk2(acck[a][2], acck[a][3]);
        dk[2] = pk2(acck[a][4], acck[a][5]);
        dk[3] = pk2(acck[a][6], acck[a][7]);
        dk[4] = pk2(acck[a][8], acck[a][9]);
        dk[5] = pk2(acck[a][10], acck[a][11]);
        long rv = ((long)((b*256 + jc)*2 + 1)*256 + kk0 + a)*96 + c0;
        unsigned int* dv = (unsigned int*)(part16 + rv);
        dv[0] = pk2(accv[a][0], accv[a][1]);
        dv[1] = pk2(accv[a][2], accv[a][3]);
        dv[2] = pk2(accv[a][4], accv[a][5]);
        dv[3] = pk2(accv[a][6], accv[a][7]);
        dv[4] = pk2(accv[a][8], accv[a][9]);
        dv[5] = pk2(accv[a][10], accv[a][11]);
    }
}

// ------- K3b: reduce partials -> bf16 kp16[b][h][kk][16], vp16[b][h][16][256] -------
__global__ __launch_bounds__(256) void k_ered_fin(const ushortT* __restrict__ part16,
        ushortT* __restrict__ kp16, ushortT* __restrict__ vp16) {
    const int idx = blockIdx.x*256 + threadIdx.x;  // 2*2*256*96 = 98304
    const int c  = idx % 96;
    const int kk = (idx / 96) % 256;
    const int m  = (idx / (96*256)) % 2;
    const int b  = idx / (96*256*2);
    float s = 0.f;
    long off = ((long)(b*512 + m)*256 + kk)*96 + c;
    for (int jc = 0; jc < 256; ++jc) {
        s += ubf(part16[off]);
        off += 49152;
    }
    const int h = c / DHD, d = c % DHD;
    ushortT v = bf1(s);
    if (m == 0) {
        kp16[((b*NH + h)*256 + kk)*16 + d] = v;
        if (d < 4) kp16[((b*NH + h)*256 + kk)*16 + 12 + d] = 0;
    } else {
        vp16[((b*NH + h)*16 + d)*256 + kk] = v;
    }
}

// ------- K4: attention core (A/B frags from global bf16, L2-hot) -------
__global__ __launch_bounds__(256) void k_attn(const ushortT* __restrict__ qkv16,
        const ushortT* __restrict__ kp16, const ushortT* __restrict__ vp16,
        ushortT* __restrict__ obuf) {
    // shorts: P[32][264] @0 | q[32][40] @8448 | opart f32[4][32][16] @9728
    // | rinv f32[32] @13824 | ws f32[128] @13888 ; total 14144 shorts = 28288B
    __shared__ short lds[14144];
    const int P_s = 0;
    const int q_s = 8448;
    const int op_s = 9728;
    const int ri_s = 13824;
    const int ws_s = 13888;
    const int tid = threadIdx.x;
    const int lane = tid & 63, wv = tid >> 6;
    const int l15 = lane & 15, l4 = lane >> 4;
    const int r0 = blockIdx.x * 32;
    const int b = r0 >> 14;
    const float scale = 0.28867513459481287f;  // 1/sqrt(12)
    unsigned int* qu = (unsigned int*)(lds + q_s);
    for (int i = tid; i < 448; i += 256) {
        int r = i / 14, sz = i % 14;
        qu[r*20 + 6 + sz] = 0u;
    }
    for (int h = 0; h < NH; ++h) {
        if (tid < 192) {
            int r = tid / 6, dp = tid % 6;
            qu[r*20 + dp] = *reinterpret_cast<const unsigned int*>(
                qkv16 + (long)(r0 + r)*288 + h*12 + dp*2);
        }
        __syncthreads();
        // ---- QK: S^T = K' . Q^T ; exp ; pack P bf16 to LDS ; row sums ----
        {
            short8v bq0 = *(const short8v*)(lds + q_s + l15*40 + l4*8);
            short8v bq1 = *(const short8v*)(lds + q_s + (l15 + 16)*40 + l4*8);
            const ushortT* kpb = kp16 + ((long)(b*NH + h)*256)*16 + l15*16 + l4*8;
            unsigned int* Pw = (unsigned int*)(lds + P_s);
            float ps0 = 0.f, ps1 = 0.f;
            f32x4 z = {0.f, 0.f, 0.f, 0.f};
#pragma unroll
            for (int mi = 0; mi < 4; ++mi) {
                int mt = wv*4 + mi;
                short8v a = *(const short8v*)(kpb + mt*256);
                f32x4 s0 = __builtin_amdgcn_mfma_f32_16x16x32_bf16(a, bq0, z, 0, 0, 0);
                f32x4 s1 = __builtin_amdgcn_mfma_f32_16x16x32_bf16(a, bq1, z, 0, 0, 0);
                float p0[4], p1[4];
#pragma unroll
                for (int r = 0; r < 4; ++r) {
                    p0[r] = __expf(s0[r] * scale);
                    p1[r] = __expf(s1[r] * scale);
                }
                ps0 += p0[0] + p0[1] + p0[2] + p0[3];
                ps1 += p1[0] + p1[1] + p1[2] + p1[3];
                int kkb = mt*16 + l4*4;
                unsigned int u0 = (l15*264 + kkb) >> 1;
                unsigned int u1 = ((l15 + 16)*264 + kkb) >> 1;
                Pw[u0]     = pk2(p0[0], p0[1]);
                Pw[u0 + 1] = pk2(p0[2], p0[3]);
                Pw[u1]     = pk2(p1[0], p1[1]);
                Pw[u1 + 1] = pk2(p1[2], p1[3]);
            }
            ps0 += __shfl_xor(ps0, 16, 64); ps0 += __shfl_xor(ps0, 32, 64);
            ps1 += __shfl_xor(ps1, 16, 64); ps1 += __shfl_xor(ps1, 32, 64);
            float* wsf = (float*)(lds + ws_s);
            if (lane < 16) { wsf[wv*32 + lane] = ps0; wsf[wv*32 + 16 + lane] = ps1; }
        }
        __syncthreads();
        // ---- PV (B-frags from global vp16) + rinv ----
        {
            float* wsf = (float*)(lds + ws_s);
            float* rin = (float*)(lds + ri_s);
            if (tid < 32)
                rin[tid] = 1.0f / (wsf[tid] + wsf[32 + tid] + wsf[64 + tid] + wsf[96 + tid]);
            f32x4 o0 = {0.f, 0.f, 0.f, 0.f}, o1 = {0.f, 0.f, 0.f, 0.f};
            const ushortT* vb = vp16 + ((long)(b*NH + h)*16 + l15)*256 + l4*8;
#pragma unroll
            for (int kq = 0; kq < 2; ++kq) {
                int ks = wv*2 + kq;
                short8v bvf = *(const short8v*)(vb + ks*32);
                short8v a0 = *(const short8v*)(lds + P_s + l15*264 + ks*32 + l4*8);
                short8v a1 = *(const short8v*)(lds + P_s + (16 + l15)*264 + ks*32 + l4*8);
                o0 = __builtin_amdgcn_mfma_f32_16x16x32_bf16(a0, bvf, o0, 0, 0, 0);
                o1 = __builtin_amdgcn_mfma_f32_16x16x32_bf16(a1, bvf, o1, 0, 0, 0);
            }
            float* op = (float*)(lds + op_s);
            int rowb = l4*4;
#pragma unroll
            for (int r = 0; r < 4; ++r) {
                op[wv*512 + (rowb + r)*16 + l15] = o0[r];
                op[wv*512 + (16 + rowb + r)*16 + l15] = o1[r];
            }
        }
        __syncthreads();
        // ---- reduce across waves, normalize, store obuf bf16 ----
        if (tid < 192) {
            float* op = (float*)(lds + op_s);
            float* rin = (float*)(lds + ri_s);
            int i = tid / 6, dp = tid % 6;
            float ri = rin[i];
            int o = i*16 + dp*2;
            float s0 = (op[o] + op[512 + o] + op[1024 + o] + op[1536 + o]) * ri;
            float s1 = (op[o+1] + op[512 + o+1] + op[1024 + o+1] + op[1536 + o+1]) * ri;
            ((unsigned int*)obuf)[(r0 + i)*48 + h*6 + dp] = pk2(s0, s1);
        }
        __syncthreads();
    }
}

// ------- K5: out = o @ W0 via MFMA (W0^T bf16 frags from global) -------
__global__ __launch_bounds__(256) void k_out(const ushortT* __restrict__ obuf,
        const ushortT* __restrict__ w0T, float* __restrict__ out) {
    __shared__ ushortT ol[64*104];
    const int tid = threadIdx.x;
    const int r0 = blockIdx.x * 64;
    for (int i = tid; i < 768; i += 256) {
        int r = i / 12, sg = i % 12;
        *reinterpret_cast<uint4*>(&ol[r*104 + sg*8]) =
            *reinterpret_cast<const uint4*>(&obuf[(long)(r0 + r)*96 + sg*8]);
    }
    __syncthreads();
    const int lane = tid & 63, wv = tid >> 6;
    const int l15 = lane & 15, l4 = lane >> 4;
    short8v a[3];
#pragma unroll
    for (int kt = 0; kt < 3; ++kt)
        a[kt] = *(const short8v*)((const short*)ol + (wv*16 + l15)*104 + kt*32 + l4*8);
#pragma unroll
    for (int nt = 0; nt < 6; ++nt) {
        f32x4 acc = {0.f, 0.f, 0.f, 0.f};
#pragma unroll
        for (int kt = 0; kt < 3; ++kt) {
            short8v bw = *(const short8v*)((const short*)w0T + (nt*16 + l15)*96 + kt*32 + l4*8);
            acc = __builtin_amdgcn_mfma_f32_16x16x32_bf16(a[kt], bw, acc, 0, 0, 0);
        }
#pragma unroll
        for (int r = 0; r < 4; ++r)
            out[(long)(r0 + wv*16 + l4*4 + r)*96 + nt*16 + l15] = acc[r];
    }
}

extern "C" void kernel_launch(void* const* d_in, const int* in_sizes, int n_in,
                              void* d_out, int out_size, void* d_ws, size_t ws_size,
                              hipStream_t stream) {
    (void)in_sizes; (void)n_in; (void)out_size; (void)ws_size;
    const float* x    = (const float*)d_in[0];
    const float* Wqkv = (const float*)d_in[1];
    const float* W0   = (const float*)d_in[2];
    const float* E    = (const float*)d_in[3];
    const float* c0w  = (const float*)d_in[4];
    const float* c0b  = (const float*)d_in[5];
    const float* cspw = (const float*)d_in[6];
    const float* cspb = (const float*)d_in[7];
    const float* c1w  = (const float*)d_in[8];
    const float* c1b  = (const float*)d_in[9];
    float* out = (float*)d_out;
    float* ws  = (float*)d_ws;

    // ws layout (float offsets):
    // qkv16 (ush) @0 (4.72M f) | wqT16 @4800000 | w0T16 @4820000
    // vf @9437184 | a1 @12582912 | a2 @15728640
    // part16 (ush, 12.58M f) overlays 12582912..25165824 (a1/a2 dead by k_ered)
    // obuf (ush) overlays @12582912 after fin
    // kp16 @25165824 | vp16 @25198592
    ushortT* qkv16  = (ushortT*)ws;
    ushortT* wqT16  = (ushortT*)(ws + 4800000);
    ushortT* w0T16  = (ushortT*)(ws + 4820000);
    float* vf   = ws + 9437184;
    float* a1   = ws + 12582912;
    float* a2   = ws + 15728640;
    ushortT* part16 = (ushortT*)(ws + 12582912);
    ushortT* obuf   = (ushortT*)(ws + 12582912);
    ushortT* kp16   = (ushortT*)(ws + 25165824);
    ushortT* vp16   = (ushortT*)(ws + 25198592);

    k_prep<<<dim3(144), dim3(256), 0, stream>>>(Wqkv, W0, wqT16, w0T16);
    k_qkv<<<dim3(NROW/64), dim3(256), 0, stream>>>(x, wqT16, qkv16);
    k_dw5<<<dim3(NROW/32), dim3(256), 0, stream>>>(x, c0w, c0b, a1);
    k_dw7<<<dim3(NROW/32), dim3(256), 0, stream>>>(a1, cspw, cspb, a2);
    k_pw_gate<<<dim3(NROW/32), dim3(256), 0, stream>>>(a2, c1w, c1b, x, qkv16, vf);
    k_ered<<<dim3(512), dim3(512), 0, stream>>>(E, qkv16, vf, part16);
    k_ered_fin<<<dim3(384), dim3(256), 0, stream>>>(part16, kp16, vp16);
    k_attn<<<dim3(NROW/32), dim3(256), 0, stream>>>(qkv16, kp16, vp16, obuf);
    k_out<<<dim3(NROW/64), dim3(256), 0, stream>>>(obuf, w0T16, out);
}

// Round 7
// 170.717 us; speedup vs baseline: 2.5934x; 1.1422x over previous
//
#include <hip/hip_runtime.h>

#define HH_ 128
#define WW_ 128
#define LL_ (HH_*WW_)     // 16384
#define NH 8
#define DHD 12
#define KD 256
#define BB_ 2
#define NROW (BB_*LL_)    // 32768

typedef __attribute__((ext_vector_type(8))) short short8v;
typedef __attribute__((ext_vector_type(4))) float f32x4;
typedef unsigned short ushortT;

__device__ __forceinline__ float4 ld4(const float* p) {
    return *reinterpret_cast<const float4*>(p);
}
__device__ __forceinline__ unsigned int pk2(float a, float b) {
    unsigned int ua = __float_as_uint(a);
    unsigned int ub = __float_as_uint(b);
    ua = (ua + 0x7FFFu + ((ua >> 16) & 1u)) >> 16;
    ub = (ub + 0x7FFFu + ((ub >> 16) & 1u)) >> 16;
    return ua | (ub << 16);
}
__device__ __forceinline__ ushortT bf1(float a) {
    unsigned int u = __float_as_uint(a);
    return (ushortT)((u + 0x7FFFu + ((u >> 16) & 1u)) >> 16);
}
__device__ __forceinline__ float ubf(ushortT v) {
    return __uint_as_float(((unsigned int)v) << 16);
}

// ------- K0a: weights -> bf16 [n][k] -------
__global__ __launch_bounds__(256) void k_prep(const float* __restrict__ Wq,
        const float* __restrict__ W0, ushortT* __restrict__ wqT,
        ushortT* __restrict__ w0T) {
    int i = blockIdx.x*256 + threadIdx.x;
    if (i < 288*96) {
        int n = i / 96, k = i % 96;
        wqT[n*96 + k] = bf1(Wq[k*288 + n]);
    } else if (i < 288*96 + 96*96) {
        int j = i - 288*96;
        int n = j / 96, k = j % 96;
        w0T[n*96 + k] = bf1(W0[k*96 + n]);
    }
}

// ------- K0b: E -> bf16 transposed ET16[kk 256][j 16384] -------
__global__ __launch_bounds__(256) void k_prepE(const float* __restrict__ E,
        ushortT* __restrict__ ET) {
    __shared__ ushortT Tz[64*66];
    const int tid = threadIdx.x;
    const int jt = blockIdx.x >> 2, kt = blockIdx.x & 3;
    const int j0 = jt * 64, kk0 = kt * 64;
    for (int i = tid; i < 64*16; i += 256) {
        int row = i >> 4, s4 = (i & 15) << 2;
        float4 e4 = ld4(&E[(long)(j0 + row)*256 + kk0 + s4]);
        Tz[(s4 + 0)*66 + row] = bf1(e4.x);
        Tz[(s4 + 1)*66 + row] = bf1(e4.y);
        Tz[(s4 + 2)*66 + row] = bf1(e4.z);
        Tz[(s4 + 3)*66 + row] = bf1(e4.w);
    }
    __syncthreads();
    unsigned int* Tu = (unsigned int*)Tz;
    for (int i = tid; i < 64*32; i += 256) {
        int kk = i >> 5, s = i & 31;
        ((unsigned int*)ET)[(((long)(kk0 + kk) << 14) + j0 >> 1) + s] = Tu[kk*33 + s];
    }
}

// ------- K1: qkv16 = bf16(x @ Wqkv) via MFMA -------
__global__ __launch_bounds__(256) void k_qkv(const float* __restrict__ x,
        const ushortT* __restrict__ wqT, ushortT* __restrict__ qkv16) {
    __shared__ ushortT xb[64*104];
    const int tid = threadIdx.x;
    const int r0w = blockIdx.x * 64;
    for (int i = tid; i < 64*48; i += 256) {
        int r = i / 48, cp = i % 48;
        const float* sp = x + (long)(r0w + r)*96 + cp*2;
        ((unsigned int*)xb)[r*52 + cp] = pk2(sp[0], sp[1]);
    }
    __syncthreads();
    const int lane = tid & 63, wv = tid >> 6;
    const int l15 = lane & 15, l4 = lane >> 4;
    short8v bx[3];
#pragma unroll
    for (int kt = 0; kt < 3; ++kt)
        bx[kt] = *(const short8v*)((const short*)xb + (wv*16 + l15)*104 + kt*32 + l4*8);
#pragma unroll 2
    for (int mt = 0; mt < 18; ++mt) {
        f32x4 acc = {0.f, 0.f, 0.f, 0.f};
#pragma unroll
        for (int kt = 0; kt < 3; ++kt) {
            short8v a = *(const short8v*)((const short*)wqT + (mt*16 + l15)*96 + kt*32 + l4*8);
            acc = __builtin_amdgcn_mfma_f32_16x16x32_bf16(a, bx[kt], acc, 0, 0, 0);
        }
        unsigned int* q32 = (unsigned int*)(qkv16 + (long)(r0w + wv*16 + l15)*288 + mt*16 + l4*4);
        q32[0] = pk2(acc[0], acc[1]);
        q32[1] = pk2(acc[2], acc[3]);
    }
}

// ---------------- K2a: depthwise 5x5, pad 2 (channels-last) ----------------
__global__ __launch_bounds__(256) void k_dw5(const float* __restrict__ xin,
                                             const float* __restrict__ w,
                                             const float* __restrict__ bias,
                                             float* __restrict__ out) {
    __shared__ float wl[25][96];
    const int tid = threadIdx.x;
    for (int i = tid; i < 25*96; i += 256) {
        int c = i / 25, t = i % 25;
        wl[t][c] = w[i];
    }
    __syncthreads();
    const int c4 = (tid & 7)*4;
    const int px = tid >> 3;
    const int pix0 = blockIdx.x * 32;
    const int b = pix0 >> 14;
    const int y = (pix0 & 16383) >> 7;
    const int xx = (pix0 & 127) + px;
    float4 acc[3];
#pragma unroll
    for (int ch = 0; ch < 3; ++ch) { acc[ch].x=0.f; acc[ch].y=0.f; acc[ch].z=0.f; acc[ch].w=0.f; }
#pragma unroll
    for (int iy = 0; iy < 5; ++iy) {
        int y2 = y + iy - 2;
        if (y2 < 0 || y2 >= HH_) continue;
#pragma unroll
        for (int ix = 0; ix < 5; ++ix) {
            int x2 = xx + ix - 2;
            if (x2 < 0 || x2 >= WW_) continue;
            const float* src = xin + ((b << 14) + y2*WW_ + x2)*96;
            const float* wt = &wl[iy*5 + ix][0];
#pragma unroll
            for (int ch = 0; ch < 3; ++ch) {
                float4 xv = ld4(src + ch*32 + c4);
                float4 wv = ld4(wt + ch*32 + c4);
                acc[ch].x = fmaf(xv.x, wv.x, acc[ch].x);
                acc[ch].y = fmaf(xv.y, wv.y, acc[ch].y);
                acc[ch].z = fmaf(xv.z, wv.z, acc[ch].z);
                acc[ch].w = fmaf(xv.w, wv.w, acc[ch].w);
            }
        }
    }
    float* dst = out + (long)(pix0 + px)*96;
#pragma unroll
    for (int ch = 0; ch < 3; ++ch) {
        float4 bv = ld4(bias + ch*32 + c4);
        float4 r;
        r.x = acc[ch].x + bv.x; r.y = acc[ch].y + bv.y;
        r.z = acc[ch].z + bv.z; r.w = acc[ch].w + bv.w;
        *reinterpret_cast<float4*>(dst + ch*32 + c4) = r;
    }
}

// ---------------- K2b: depthwise 7x7, dilation 3, pad 9 ----------------
__global__ __launch_bounds__(256) void k_dw7(const float* __restrict__ xin,
                                             const float* __restrict__ w,
                                             const float* __restrict__ bias,
                                             float* __restrict__ out) {
    __shared__ float wl[49][96];
    const int tid = threadIdx.x;
    for (int i = tid; i < 49*96; i += 256) {
        int c = i / 49, t = i % 49;
        wl[t][c] = w[i];
    }
    __syncthreads();
    const int c4 = (tid & 7)*4;
    const int px = tid >> 3;
    const int pix0 = blockIdx.x * 32;
    const int b = pix0 >> 14;
    const int y = (pix0 & 16383) >> 7;
    const int xx = (pix0 & 127) + px;
    float4 acc[3];
#pragma unroll
    for (int ch = 0; ch < 3; ++ch) { acc[ch].x=0.f; acc[ch].y=0.f; acc[ch].z=0.f; acc[ch].w=0.f; }
#pragma unroll
    for (int iy = 0; iy < 7; ++iy) {
        int y2 = y + iy*3 - 9;
        if (y2 < 0 || y2 >= HH_) continue;
#pragma unroll
        for (int ix = 0; ix < 7; ++ix) {
            int x2 = xx + ix*3 - 9;
            if (x2 < 0 || x2 >= WW_) continue;
            const float* src = xin + ((b << 14) + y2*WW_ + x2)*96;
            const float* wt = &wl[iy*7 + ix][0];
#pragma unroll
            for (int ch = 0; ch < 3; ++ch) {
                float4 xv = ld4(src + ch*32 + c4);
                float4 wv = ld4(wt + ch*32 + c4);
                acc[ch].x = fmaf(xv.x, wv.x, acc[ch].x);
                acc[ch].y = fmaf(xv.y, wv.y, acc[ch].y);
                acc[ch].z = fmaf(xv.z, wv.z, acc[ch].z);
                acc[ch].w = fmaf(xv.w, wv.w, acc[ch].w);
            }
        }
    }
    float* dst = out + (long)(pix0 + px)*96;
#pragma unroll
    for (int ch = 0; ch < 3; ++ch) {
        float4 bv = ld4(bias + ch*32 + c4);
        float4 r;
        r.x = acc[ch].x + bv.x; r.y = acc[ch].y + bv.y;
        r.z = acc[ch].z + bv.z; r.w = acc[ch].w + bv.w;
        *reinterpret_cast<float4*>(dst + ch*32 + c4) = r;
    }
}

// ------- K2c: a3 = a2 @ w1^T + b1 ; vf = x * a3 * v (v from bf16 qkv16) -------
__global__ __launch_bounds__(256) void k_pw_gate(const float* __restrict__ a2,
        const float* __restrict__ w1, const float* __restrict__ b1,
        const float* __restrict__ xin, const ushortT* __restrict__ qkv16,
        float* __restrict__ vf) {
    __shared__ float aT[96][36];
    __shared__ float wT[96][100];
    const int tid = threadIdx.x;
    const int r0 = blockIdx.x * 32;
    for (int i = tid; i < 32*96; i += 256) {
        int r = i / 96, c = i % 96;
        aT[c][r] = a2[(r0 + r)*96 + c];
    }
    for (int i = tid; i < 96*96; i += 256) {
        int o = i / 96, ci = i % 96;
        wT[ci][o] = w1[i];
    }
    __syncthreads();
    const int cg = tid & 31, rg = tid >> 5;
    const int c0 = cg*3, rr = rg*4;
    float acc[4][3];
#pragma unroll
    for (int r = 0; r < 4; ++r)
#pragma unroll
        for (int j = 0; j < 3; ++j) acc[r][j] = 0.f;
#pragma unroll 4
    for (int k = 0; k < 96; ++k) {
        float4 a4 = ld4(&aT[k][rr]);
        float av[4] = {a4.x, a4.y, a4.z, a4.w};
#pragma unroll
        for (int j = 0; j < 3; ++j) {
            float w = wT[k][c0 + j];
#pragma unroll
            for (int r = 0; r < 4; ++r) acc[r][j] = fmaf(av[r], w, acc[r][j]);
        }
    }
#pragma unroll
    for (int r = 0; r < 4; ++r) {
        int row = r0 + rr + r;
#pragma unroll
        for (int j = 0; j < 3; ++j) {
            int c = c0 + j;
            float g = acc[r][j] + b1[c];
            float v = ubf(qkv16[(long)row*288 + 192 + c]);
            vf[row*96 + c] = xin[row*96 + c] * v * g;
        }
    }
}

// ------- K2d: transpose k-slice + vf -> XT16[b][cc 192][j 16384] bf16 -------
__global__ __launch_bounds__(256) void k_tr(const ushortT* __restrict__ qkv16,
        const float* __restrict__ vf, ushortT* __restrict__ XT) {
    __shared__ ushortT T[192*66];
    const int tid = threadIdx.x;
    const int b = blockIdx.x >> 8;
    const int jc = blockIdx.x & 255;
    const int j0 = jc * 64;
    const unsigned int* q32 = (const unsigned int*)qkv16;
    for (int i = tid; i < 64*48; i += 256) {
        int row = i / 48, cp = i % 48;
        long grow = (long)b*LL_ + j0 + row;
        unsigned int kk2 = q32[grow*144 + 48 + cp];
        T[(2*cp + 0)*66 + row] = (ushortT)(kk2 & 0xFFFF);
        T[(2*cp + 1)*66 + row] = (ushortT)(kk2 >> 16);
    }
    for (int i = tid; i < 64*24; i += 256) {
        int row = i / 24, cq = (i % 24) << 2;
        long grow = (long)b*LL_ + j0 + row;
        float4 v4 = ld4(&vf[grow*96 + cq]);
        T[(96 + cq + 0)*66 + row] = bf1(v4.x);
        T[(96 + cq + 1)*66 + row] = bf1(v4.y);
        T[(96 + cq + 2)*66 + row] = bf1(v4.z);
        T[(96 + cq + 3)*66 + row] = bf1(v4.w);
    }
    __syncthreads();
    unsigned int* Tu = (unsigned int*)T;
    for (int i = tid; i < 192*32; i += 256) {
        int cc = i >> 5, s = i & 31;
        ((unsigned int*)XT)[((((long)b*192 + cc) << 14) + j0 >> 1) + s] = Tu[cc*33 + s];
    }
}

// ------- K3a: E-reduction as MFMA split-K GEMM. grid = 2b x 128 jc (128 j),
// 512 thr: wave = (mtg = wv&3 -> 4 mt, nth = wv>>2 -> 6 nt). No LDS. -------
__global__ __launch_bounds__(512) void k_ered(const ushortT* __restrict__ ET,
        const ushortT* __restrict__ XT, ushortT* __restrict__ part16) {
    const int tid = threadIdx.x;
    const int lane = tid & 63, wv = tid >> 6;
    const int l15 = lane & 15, l4 = lane >> 4;
    const int mtg = wv & 3, nth = wv >> 2;
    const int b  = blockIdx.x >> 7;
    const int jc = blockIdx.x & 127;
    const int j0 = jc * 128;
    f32x4 acc[4][6];
#pragma unroll
    for (int mi = 0; mi < 4; ++mi)
#pragma unroll
        for (int ni = 0; ni < 6; ++ni)
            acc[mi][ni] = (f32x4){0.f, 0.f, 0.f, 0.f};
    const ushortT* Ab = ET + ((long)(mtg*64 + l15) << 14) + j0 + l4*8;
    const ushortT* Bb = XT + (((long)b*192 + nth*96 + l15) << 14) + j0 + l4*8;
#pragma unroll
    for (int ks = 0; ks < 4; ++ks) {
        short8v a[4], bx[6];
#pragma unroll
        for (int mi = 0; mi < 4; ++mi)
            a[mi] = *(const short8v*)(Ab + ((long)mi << 18) + ks*32);
#pragma unroll
        for (int ni = 0; ni < 6; ++ni)
            bx[ni] = *(const short8v*)(Bb + ((long)ni << 18) + ks*32);
#pragma unroll
        for (int mi = 0; mi < 4; ++mi)
#pragma unroll
            for (int ni = 0; ni < 6; ++ni)
                acc[mi][ni] = __builtin_amdgcn_mfma_f32_16x16x32_bf16(a[mi], bx[ni], acc[mi][ni], 0, 0, 0);
    }
    const long base = (long)(b*128 + jc)*49152;
#pragma unroll
    for (int mi = 0; mi < 4; ++mi) {
        int kkb = (mtg*4 + mi)*16 + l4*4;
#pragma unroll
        for (int ni = 0; ni < 6; ++ni) {
            int cc = (nth*6 + ni)*16 + l15;
#pragma unroll
            for (int r = 0; r < 4; ++r)
                part16[base + (long)(kkb + r)*192 + cc] = bf1(acc[mi][ni][r]);
        }
    }
}

// ------- K3b: reduce partials -> bf16 kp16[b][h][kk][16], vp16[b][h][16][256] -------
__global__ __launch_bounds__(256) void k_ered_fin(const ushortT* __restrict__ part16,
        ushortT* __restrict__ kp16, ushortT* __restrict__ vp16) {
    const int idx = blockIdx.x*256 + threadIdx.x;  // 2*2*256*96 = 98304
    const int c  = idx % 96;
    const int kk = (idx / 96) % 256;
    const int m  = (idx / (96*256)) % 2;
    const int b  = idx / (96*256*2);
    float s = 0.f;
    long off = ((long)(b*128)*256 + kk)*192 + m*96 + c;
    for (int jc = 0; jc < 128; ++jc) {
        s += ubf(part16[off]);
        off += 49152;
    }
    const int h = c / DHD, d = c % DHD;
    ushortT v = bf1(s);
    if (m == 0) {
        kp16[((b*NH + h)*256 + kk)*16 + d] = v;
        if (d < 4) kp16[((b*NH + h)*256 + kk)*16 + 12 + d] = 0;
    } else {
        vp16[((b*NH + h)*16 + d)*256 + kk] = v;
    }
}

// ------- K4: attention core (A/B frags from global bf16, L2-hot) -------
__global__ __launch_bounds__(256) void k_attn(const ushortT* __restrict__ qkv16,
        const ushortT* __restrict__ kp16, const ushortT* __restrict__ vp16,
        ushortT* __restrict__ obuf) {
    __shared__ short lds[14144];
    const int P_s = 0;
    const int q_s = 8448;
    const int op_s = 9728;
    const int ri_s = 13824;
    const int ws_s = 13888;
    const int tid = threadIdx.x;
    const int lane = tid & 63, wv = tid >> 6;
    const int l15 = lane & 15, l4 = lane >> 4;
    const int r0 = blockIdx.x * 32;
    const int b = r0 >> 14;
    const float scale = 0.28867513459481287f;  // 1/sqrt(12)
    unsigned int* qu = (unsigned int*)(lds + q_s);
    for (int i = tid; i < 448; i += 256) {
        int r = i / 14, sz = i % 14;
        qu[r*20 + 6 + sz] = 0u;
    }
    for (int h = 0; h < NH; ++h) {
        if (tid < 192) {
            int r = tid / 6, dp = tid % 6;
            qu[r*20 + dp] = *reinterpret_cast<const unsigned int*>(
                qkv16 + (long)(r0 + r)*288 + h*12 + dp*2);
        }
        __syncthreads();
        {
            short8v bq0 = *(const short8v*)(lds + q_s + l15*40 + l4*8);
            short8v bq1 = *(const short8v*)(lds + q_s + (l15 + 16)*40 + l4*8);
            const ushortT* kpb = kp16 + ((long)(b*NH + h)*256)*16 + l15*16 + l4*8;
            unsigned int* Pw = (unsigned int*)(lds + P_s);
            float ps0 = 0.f, ps1 = 0.f;
            f32x4 z = {0.f, 0.f, 0.f, 0.f};
#pragma unroll
            for (int mi = 0; mi < 4; ++mi) {
                int mt = wv*4 + mi;
                short8v a = *(const short8v*)(kpb + mt*256);
                f32x4 s0 = __builtin_amdgcn_mfma_f32_16x16x32_bf16(a, bq0, z, 0, 0, 0);
                f32x4 s1 = __builtin_amdgcn_mfma_f32_16x16x32_bf16(a, bq1, z, 0, 0, 0);
                float p0[4], p1[4];
#pragma unroll
                for (int r = 0; r < 4; ++r) {
                    p0[r] = __expf(s0[r] * scale);
                    p1[r] = __expf(s1[r] * scale);
                }
                ps0 += p0[0] + p0[1] + p0[2] + p0[3];
                ps1 += p1[0] + p1[1] + p1[2] + p1[3];
                int kkb = mt*16 + l4*4;
                unsigned int u0 = (l15*264 + kkb) >> 1;
                unsigned int u1 = ((l15 + 16)*264 + kkb) >> 1;
                Pw[u0]     = pk2(p0[0], p0[1]);
                Pw[u0 + 1] = pk2(p0[2], p0[3]);
                Pw[u1]     = pk2(p1[0], p1[1]);
                Pw[u1 + 1] = pk2(p1[2], p1[3]);
            }
            ps0 += __shfl_xor(ps0, 16, 64); ps0 += __shfl_xor(ps0, 32, 64);
            ps1 += __shfl_xor(ps1, 16, 64); ps1 += __shfl_xor(ps1, 32, 64);
            float* wsf = (float*)(lds + ws_s);
            if (lane < 16) { wsf[wv*32 + lane] = ps0; wsf[wv*32 + 16 + lane] = ps1; }
        }
        __syncthreads();
        {
            float* wsf = (float*)(lds + ws_s);
            float* rin = (float*)(lds + ri_s);
            if (tid < 32)
                rin[tid] = 1.0f / (wsf[tid] + wsf[32 + tid] + wsf[64 + tid] + wsf[96 + tid]);
            f32x4 o0 = {0.f, 0.f, 0.f, 0.f}, o1 = {0.f, 0.f, 0.f, 0.f};
            const ushortT* vb = vp16 + ((long)(b*NH + h)*16 + l15)*256 + l4*8;
#pragma unroll
            for (int kq = 0; kq < 2; ++kq) {
                int ks = wv*2 + kq;
                short8v bvf = *(const short8v*)(vb + ks*32);
                short8v a0 = *(const short8v*)(lds + P_s + l15*264 + ks*32 + l4*8);
                short8v a1 = *(const short8v*)(lds + P_s + (16 + l15)*264 + ks*32 + l4*8);
                o0 = __builtin_amdgcn_mfma_f32_16x16x32_bf16(a0, bvf, o0, 0, 0, 0);
                o1 = __builtin_amdgcn_mfma_f32_16x16x32_bf16(a1, bvf, o1, 0, 0, 0);
            }
            float* op = (float*)(lds + op_s);
            int rowb = l4*4;
#pragma unroll
            for (int r = 0; r < 4; ++r) {
                op[wv*512 + (rowb + r)*16 + l15] = o0[r];
                op[wv*512 + (16 + rowb + r)*16 + l15] = o1[r];
            }
        }
        __syncthreads();
        if (tid < 192) {
            float* op = (float*)(lds + op_s);
            float* rin = (float*)(lds + ri_s);
            int i = tid / 6, dp = tid % 6;
            float ri = rin[i];
            int o = i*16 + dp*2;
            float s0 = (op[o] + op[512 + o] + op[1024 + o] + op[1536 + o]) * ri;
            float s1 = (op[o+1] + op[512 + o+1] + op[1024 + o+1] + op[1536 + o+1]) * ri;
            ((unsigned int*)obuf)[(r0 + i)*48 + h*6 + dp] = pk2(s0, s1);
        }
        __syncthreads();
    }
}

// ------- K5: out = o @ W0 via MFMA (W0^T bf16 frags from global) -------
__global__ __launch_bounds__(256) void k_out(const ushortT* __restrict__ obuf,
        const ushortT* __restrict__ w0T, float* __restrict__ out) {
    __shared__ ushortT ol[64*104];
    const int tid = threadIdx.x;
    const int r0 = blockIdx.x * 64;
    for (int i = tid; i < 768; i += 256) {
        int r = i / 12, sg = i % 12;
        *reinterpret_cast<uint4*>(&ol[r*104 + sg*8]) =
            *reinterpret_cast<const uint4*>(&obuf[(long)(r0 + r)*96 + sg*8]);
    }
    __syncthreads();
    const int lane = tid & 63, wv = tid >> 6;
    const int l15 = lane & 15, l4 = lane >> 4;
    short8v a[3];
#pragma unroll
    for (int kt = 0; kt < 3; ++kt)
        a[kt] = *(const short8v*)((const short*)ol + (wv*16 + l15)*104 + kt*32 + l4*8);
#pragma unroll
    for (int nt = 0; nt < 6; ++nt) {
        f32x4 acc = {0.f, 0.f, 0.f, 0.f};
#pragma unroll
        for (int kt = 0; kt < 3; ++kt) {
            short8v bw = *(const short8v*)((const short*)w0T + (nt*16 + l15)*96 + kt*32 + l4*8);
            acc = __builtin_amdgcn_mfma_f32_16x16x32_bf16(a[kt], bw, acc, 0, 0, 0);
        }
#pragma unroll
        for (int r = 0; r < 4; ++r)
            out[(long)(r0 + wv*16 + l4*4 + r)*96 + nt*16 + l15] = acc[r];
    }
}

extern "C" void kernel_launch(void* const* d_in, const int* in_sizes, int n_in,
                              void* d_out, int out_size, void* d_ws, size_t ws_size,
                              hipStream_t stream) {
    (void)in_sizes; (void)n_in; (void)out_size; (void)ws_size;
    const float* x    = (const float*)d_in[0];
    const float* Wqkv = (const float*)d_in[1];
    const float* W0   = (const float*)d_in[2];
    const float* E    = (const float*)d_in[3];
    const float* c0w  = (const float*)d_in[4];
    const float* c0b  = (const float*)d_in[5];
    const float* cspw = (const float*)d_in[6];
    const float* cspb = (const float*)d_in[7];
    const float* c1w  = (const float*)d_in[8];
    const float* c1b  = (const float*)d_in[9];
    float* out = (float*)d_out;
    float* ws  = (float*)d_ws;

    // ws layout (float offsets):
    // qkv16 @0 (4718592) | wqT16 @4718592 | w0T16 @4732416 | ET16 @4737024 (2097152)
    // XT16 @6834176 (3145728) | vf @9979904 (3145728) | a1 @13125632 | a2 @16271360
    // part16 (6291456 f) overlays a1+a2 @13125632 (dead by k_ered); obuf same region
    // kp16 @19417088 (32768) | vp16 @19449856 (32768) ; total ~78 MB
    ushortT* qkv16  = (ushortT*)ws;
    ushortT* wqT16  = (ushortT*)(ws + 4718592);
    ushortT* w0T16  = (ushortT*)(ws + 4732416);
    ushortT* ET16   = (ushortT*)(ws + 4737024);
    ushortT* XT16   = (ushortT*)(ws + 6834176);
    float* vf   = ws + 9979904;
    float* a1   = ws + 13125632;
    float* a2   = ws + 16271360;
    ushortT* part16 = (ushortT*)(ws + 13125632);
    ushortT* obuf   = (ushortT*)(ws + 13125632);
    ushortT* kp16   = (ushortT*)(ws + 19417088);
    ushortT* vp16   = (ushortT*)(ws + 19449856);

    k_prep<<<dim3(144), dim3(256), 0, stream>>>(Wqkv, W0, wqT16, w0T16);
    k_prepE<<<dim3(1024), dim3(256), 0, stream>>>(E, ET16);
    k_qkv<<<dim3(NROW/64), dim3(256), 0, stream>>>(x, wqT16, qkv16);
    k_dw5<<<dim3(NROW/32), dim3(256), 0, stream>>>(x, c0w, c0b, a1);
    k_dw7<<<dim3(NROW/32), dim3(256), 0, stream>>>(a1, cspw, cspb, a2);
    k_pw_gate<<<dim3(NROW/32), dim3(256), 0, stream>>>(a2, c1w, c1b, x, qkv16, vf);
    k_tr<<<dim3(512), dim3(256), 0, stream>>>(qkv16, vf, XT16);
    k_ered<<<dim3(256), dim3(512), 0, stream>>>(ET16, XT16, part16);
    k_ered_fin<<<dim3(384), dim3(256), 0, stream>>>(part16, kp16, vp16);
    k_attn<<<dim3(NROW/32), dim3(256), 0, stream>>>(qkv16, kp16, vp16, obuf);
    k_out<<<dim3(NROW/64), dim3(256), 0, stream>>>(obuf, w0T16, out);
}

// Round 9
// 151.712 us; speedup vs baseline: 2.9182x; 1.1253x over previous
//
#include <hip/hip_runtime.h>

#define HH_ 128
#define WW_ 128
#define LL_ (HH_*WW_)     // 16384
#define NH 8
#define DHD 12
#define KD 256
#define BB_ 2
#define NROW (BB_*LL_)    // 32768

typedef __attribute__((ext_vector_type(8))) short short8v;
typedef __attribute__((ext_vector_type(4))) float f32x4;
typedef unsigned short ushortT;

__device__ __forceinline__ float4 ld4(const float* p) {
    return *reinterpret_cast<const float4*>(p);
}
__device__ __forceinline__ unsigned int pk2(float a, float b) {
    unsigned int ua = __float_as_uint(a);
    unsigned int ub = __float_as_uint(b);
    ua = (ua + 0x7FFFu + ((ua >> 16) & 1u)) >> 16;
    ub = (ub + 0x7FFFu + ((ub >> 16) & 1u)) >> 16;
    return ua | (ub << 16);
}
__device__ __forceinline__ ushortT bf1(float a) {
    unsigned int u = __float_as_uint(a);
    return (ushortT)((u + 0x7FFFu + ((u >> 16) & 1u)) >> 16);
}
__device__ __forceinline__ float ubf(ushortT v) {
    return __uint_as_float(((unsigned int)v) << 16);
}

// ------- K0: merged prep. blocks <1024: E -> ET16[kk][j] bf16 transposed;
//             blocks >=1024: Wqkv/W0 -> bf16 [n][k], w1 -> bf16 cast -------
__global__ __launch_bounds__(256) void k_prep(const float* __restrict__ E,
        const float* __restrict__ Wq, const float* __restrict__ W0,
        const float* __restrict__ w1, ushortT* __restrict__ ET,
        ushortT* __restrict__ wqT, ushortT* __restrict__ w0T,
        ushortT* __restrict__ w1c) {
    __shared__ ushortT Tz[64*66];
    const int tid = threadIdx.x;
    if (blockIdx.x < 1024) {
        const int jt = blockIdx.x >> 2, kt = blockIdx.x & 3;
        const int j0 = jt * 64, kk0 = kt * 64;
        for (int i = tid; i < 64*16; i += 256) {
            int row = i >> 4, s4 = (i & 15) << 2;
            float4 e4 = ld4(&E[(long)(j0 + row)*256 + kk0 + s4]);
            Tz[(s4 + 0)*66 + row] = bf1(e4.x);
            Tz[(s4 + 1)*66 + row] = bf1(e4.y);
            Tz[(s4 + 2)*66 + row] = bf1(e4.z);
            Tz[(s4 + 3)*66 + row] = bf1(e4.w);
        }
        __syncthreads();
        unsigned int* Tu = (unsigned int*)Tz;
        for (int i = tid; i < 64*32; i += 256) {
            int kk = i >> 5, s = i & 31;
            ((unsigned int*)ET)[(((long)(kk0 + kk) << 14) + j0 >> 1) + s] = Tu[kk*33 + s];
        }
    } else {
        int i = (blockIdx.x - 1024)*256 + tid;
        if (i < 27648) {
            int n = i / 96, k = i % 96;
            wqT[n*96 + k] = bf1(Wq[k*288 + n]);
        } else if (i < 36864) {
            int j = i - 27648;
            int n = j / 96, k = j % 96;
            w0T[n*96 + k] = bf1(W0[k*96 + n]);
        } else if (i < 46080) {
            int j = i - 36864;
            w1c[j] = bf1(w1[j]);
        }
    }
}

// ------- K1: qkv16 = bf16(x @ Wqkv) via MFMA -------
__global__ __launch_bounds__(256) void k_qkv(const float* __restrict__ x,
        const ushortT* __restrict__ wqT, ushortT* __restrict__ qkv16) {
    __shared__ ushortT xb[64*104];
    const int tid = threadIdx.x;
    const int r0w = blockIdx.x * 64;
    for (int i = tid; i < 64*48; i += 256) {
        int r = i / 48, cp = i % 48;
        const float* sp = x + (long)(r0w + r)*96 + cp*2;
        ((unsigned int*)xb)[r*52 + cp] = pk2(sp[0], sp[1]);
    }
    __syncthreads();
    const int lane = tid & 63, wv = tid >> 6;
    const int l15 = lane & 15, l4 = lane >> 4;
    short8v bx[3];
#pragma unroll
    for (int kt = 0; kt < 3; ++kt)
        bx[kt] = *(const short8v*)((const short*)xb + (wv*16 + l15)*104 + kt*32 + l4*8);
#pragma unroll 2
    for (int mt = 0; mt < 18; ++mt) {
        f32x4 acc = {0.f, 0.f, 0.f, 0.f};
#pragma unroll
        for (int kt = 0; kt < 3; ++kt) {
            short8v a = *(const short8v*)((const short*)wqT + (mt*16 + l15)*96 + kt*32 + l4*8);
            acc = __builtin_amdgcn_mfma_f32_16x16x32_bf16(a, bx[kt], acc, 0, 0, 0);
        }
        unsigned int* q32 = (unsigned int*)(qkv16 + (long)(r0w + wv*16 + l15)*288 + mt*16 + l4*4);
        q32[0] = pk2(acc[0], acc[1]);
        q32[1] = pk2(acc[2], acc[3]);
    }
}

// ---------------- K2a: depthwise 5x5, pad 2 (channels-last) ----------------
__global__ __launch_bounds__(256) void k_dw5(const float* __restrict__ xin,
                                             const float* __restrict__ w,
                                             const float* __restrict__ bias,
                                             float* __restrict__ out) {
    __shared__ float wl[25][96];
    const int tid = threadIdx.x;
    for (int i = tid; i < 25*96; i += 256) {
        int c = i / 25, t = i % 25;
        wl[t][c] = w[i];
    }
    __syncthreads();
    const int c4 = (tid & 7)*4;
    const int px = tid >> 3;
    const int pix0 = blockIdx.x * 32;
    const int b = pix0 >> 14;
    const int y = (pix0 & 16383) >> 7;
    const int xx = (pix0 & 127) + px;
    float4 acc[3];
#pragma unroll
    for (int ch = 0; ch < 3; ++ch) { acc[ch].x=0.f; acc[ch].y=0.f; acc[ch].z=0.f; acc[ch].w=0.f; }
#pragma unroll
    for (int iy = 0; iy < 5; ++iy) {
        int y2 = y + iy - 2;
        if (y2 < 0 || y2 >= HH_) continue;
#pragma unroll
        for (int ix = 0; ix < 5; ++ix) {
            int x2 = xx + ix - 2;
            if (x2 < 0 || x2 >= WW_) continue;
            const float* src = xin + ((b << 14) + y2*WW_ + x2)*96;
            const float* wt = &wl[iy*5 + ix][0];
#pragma unroll
            for (int ch = 0; ch < 3; ++ch) {
                float4 xv = ld4(src + ch*32 + c4);
                float4 wv = ld4(wt + ch*32 + c4);
                acc[ch].x = fmaf(xv.x, wv.x, acc[ch].x);
                acc[ch].y = fmaf(xv.y, wv.y, acc[ch].y);
                acc[ch].z = fmaf(xv.z, wv.z, acc[ch].z);
                acc[ch].w = fmaf(xv.w, wv.w, acc[ch].w);
            }
        }
    }
    float* dst = out + (long)(pix0 + px)*96;
#pragma unroll
    for (int ch = 0; ch < 3; ++ch) {
        float4 bv = ld4(bias + ch*32 + c4);
        float4 r;
        r.x = acc[ch].x + bv.x; r.y = acc[ch].y + bv.y;
        r.z = acc[ch].z + bv.z; r.w = acc[ch].w + bv.w;
        *reinterpret_cast<float4*>(dst + ch*32 + c4) = r;
    }
}

// ---------------- K2b: depthwise 7x7, dilation 3, pad 9 ----------------
__global__ __launch_bounds__(256) void k_dw7(const float* __restrict__ xin,
                                             const float* __restrict__ w,
                                             const float* __restrict__ bias,
                                             float* __restrict__ out) {
    __shared__ float wl[49][96];
    const int tid = threadIdx.x;
    for (int i = tid; i < 49*96; i += 256) {
        int c = i / 49, t = i % 49;
        wl[t][c] = w[i];
    }
    __syncthreads();
    const int c4 = (tid & 7)*4;
    const int px = tid >> 3;
    const int pix0 = blockIdx.x * 32;
    const int b = pix0 >> 14;
    const int y = (pix0 & 16383) >> 7;
    const int xx = (pix0 & 127) + px;
    float4 acc[3];
#pragma unroll
    for (int ch = 0; ch < 3; ++ch) { acc[ch].x=0.f; acc[ch].y=0.f; acc[ch].z=0.f; acc[ch].w=0.f; }
#pragma unroll
    for (int iy = 0; iy < 7; ++iy) {
        int y2 = y + iy*3 - 9;
        if (y2 < 0 || y2 >= HH_) continue;
#pragma unroll
        for (int ix = 0; ix < 7; ++ix) {
            int x2 = xx + ix*3 - 9;
            if (x2 < 0 || x2 >= WW_) continue;
            const float* src = xin + ((b << 14) + y2*WW_ + x2)*96;
            const float* wt = &wl[iy*7 + ix][0];
#pragma unroll
            for (int ch = 0; ch < 3; ++ch) {
                float4 xv = ld4(src + ch*32 + c4);
                float4 wv = ld4(wt + ch*32 + c4);
                acc[ch].x = fmaf(xv.x, wv.x, acc[ch].x);
                acc[ch].y = fmaf(xv.y, wv.y, acc[ch].y);
                acc[ch].z = fmaf(xv.z, wv.z, acc[ch].z);
                acc[ch].w = fmaf(xv.w, wv.w, acc[ch].w);
            }
        }
    }
    float* dst = out + (long)(pix0 + px)*96;
#pragma unroll
    for (int ch = 0; ch < 3; ++ch) {
        float4 bv = ld4(bias + ch*32 + c4);
        float4 r;
        r.x = acc[ch].x + bv.x; r.y = acc[ch].y + bv.y;
        r.z = acc[ch].z + bv.z; r.w = acc[ch].w + bv.w;
        *reinterpret_cast<float4*>(dst + ch*32 + c4) = r;
    }
}

// ------- K2c: fused a3 = a2@w1^T + b1 (MFMA); vf = x*a3*v; writes BOTH halves
// of XT[b][cc 192][j] (cc<96 = k transposed, cc>=96 = vf transposed). 64 rows/blk -------
__global__ __launch_bounds__(256) void k_pw_gate(const float* __restrict__ a2,
        const ushortT* __restrict__ w1c, const float* __restrict__ b1,
        const float* __restrict__ xin, const ushortT* __restrict__ qkv16,
        ushortT* __restrict__ XT) {
    __shared__ ushortT ab[64*104];     // 13312B
    __shared__ ushortT ktile[96*66];   // 12672B
    __shared__ ushortT vtile[96*66];   // 12672B
    const int tid = threadIdx.x;
    const int r0 = blockIdx.x * 64;
    const int b = r0 >> 14, j0 = r0 & 16383;
    for (int i = tid; i < 64*48; i += 256) {
        int r = i / 48, cp = i % 48;
        const float* sp = a2 + (long)(r0 + r)*96 + cp*2;
        ((unsigned int*)ab)[r*52 + cp] = pk2(sp[0], sp[1]);
    }
    const unsigned int* q32 = (const unsigned int*)qkv16;
    for (int i = tid; i < 64*48; i += 256) {
        int row = i / 48, cp = i % 48;
        unsigned int kk2 = q32[(long)(r0 + row)*144 + 48 + cp];
        ktile[(2*cp + 0)*66 + row] = (ushortT)(kk2 & 0xFFFF);
        ktile[(2*cp + 1)*66 + row] = (ushortT)(kk2 >> 16);
    }
    __syncthreads();
    const int lane = tid & 63, wv = tid >> 6;
    const int l15 = lane & 15, l4 = lane >> 4;
    const int row = r0 + wv*16 + l15;
    const int jloc = wv*16 + l15;
    short8v bx[3];
#pragma unroll
    for (int kt = 0; kt < 3; ++kt)
        bx[kt] = *(const short8v*)((const short*)ab + (wv*16 + l15)*104 + kt*32 + l4*8);
#pragma unroll
    for (int mt = 0; mt < 6; ++mt) {
        f32x4 acc = {0.f, 0.f, 0.f, 0.f};
#pragma unroll
        for (int kt = 0; kt < 3; ++kt) {
            short8v a = *(const short8v*)((const short*)w1c + (mt*16 + l15)*96 + kt*32 + l4*8);
            acc = __builtin_amdgcn_mfma_f32_16x16x32_bf16(a, bx[kt], acc, 0, 0, 0);
        }
        const int c0 = mt*16 + l4*4;
        float4 b4 = ld4(&b1[c0]);
        float4 x4 = ld4(&xin[(long)row*96 + c0]);
        uint2 vv = *reinterpret_cast<const uint2*>(qkv16 + (long)row*288 + 192 + c0);
        float v0 = ubf((ushortT)(vv.x & 0xFFFF)), v1 = ubf((ushortT)(vv.x >> 16));
        float v2 = ubf((ushortT)(vv.y & 0xFFFF)), v3 = ubf((ushortT)(vv.y >> 16));
        vtile[(c0 + 0)*66 + jloc] = bf1(x4.x * v0 * (acc[0] + b4.x));
        vtile[(c0 + 1)*66 + jloc] = bf1(x4.y * v1 * (acc[1] + b4.y));
        vtile[(c0 + 2)*66 + jloc] = bf1(x4.z * v2 * (acc[2] + b4.z));
        vtile[(c0 + 3)*66 + jloc] = bf1(x4.w * v3 * (acc[3] + b4.w));
    }
    __syncthreads();
    unsigned int* XTu = (unsigned int*)XT;
    unsigned int* ku = (unsigned int*)ktile;
    unsigned int* vu = (unsigned int*)vtile;
    for (int i = tid; i < 96*32; i += 256) {
        int cc = i >> 5, s = i & 31;
        XTu[((((long)b*192 + cc) << 14) + j0 >> 1) + s] = ku[cc*33 + s];
    }
    for (int i = tid; i < 96*32; i += 256) {
        int cc = i >> 5, s = i & 31;
        XTu[((((long)b*192 + 96 + cc) << 14) + j0 >> 1) + s] = vu[cc*33 + s];
    }
}

// ------- K3a: E-reduction as MFMA split-K GEMM (no LDS) -------
__global__ __launch_bounds__(512) void k_ered(const ushortT* __restrict__ ET,
        const ushortT* __restrict__ XT, ushortT* __restrict__ part16) {
    const int tid = threadIdx.x;
    const int lane = tid & 63, wv = tid >> 6;
    const int l15 = lane & 15, l4 = lane >> 4;
    const int mtg = wv & 3, nth = wv >> 2;
    const int b  = blockIdx.x >> 7;
    const int jc = blockIdx.x & 127;
    const int j0 = jc * 128;
    f32x4 acc[4][6];
#pragma unroll
    for (int mi = 0; mi < 4; ++mi)
#pragma unroll
        for (int ni = 0; ni < 6; ++ni)
            acc[mi][ni] = (f32x4){0.f, 0.f, 0.f, 0.f};
    const ushortT* Ab = ET + ((long)(mtg*64 + l15) << 14) + j0 + l4*8;
    const ushortT* Bb = XT + (((long)b*192 + nth*96 + l15) << 14) + j0 + l4*8;
#pragma unroll
    for (int ks = 0; ks < 4; ++ks) {
        short8v a[4], bx[6];
#pragma unroll
        for (int mi = 0; mi < 4; ++mi)
            a[mi] = *(const short8v*)(Ab + ((long)mi << 18) + ks*32);
#pragma unroll
        for (int ni = 0; ni < 6; ++ni)
            bx[ni] = *(const short8v*)(Bb + ((long)ni << 18) + ks*32);
#pragma unroll
        for (int mi = 0; mi < 4; ++mi)
#pragma unroll
            for (int ni = 0; ni < 6; ++ni)
                acc[mi][ni] = __builtin_amdgcn_mfma_f32_16x16x32_bf16(a[mi], bx[ni], acc[mi][ni], 0, 0, 0);
    }
    const long base = (long)(b*128 + jc)*49152;
#pragma unroll
    for (int mi = 0; mi < 4; ++mi) {
        int kkb = (mtg*4 + mi)*16 + l4*4;
#pragma unroll
        for (int ni = 0; ni < 6; ++ni) {
            int cc = (nth*6 + ni)*16 + l15;
#pragma unroll
            for (int r = 0; r < 4; ++r)
                part16[base + (long)(kkb + r)*192 + cc] = bf1(acc[mi][ni][r]);
        }
    }
}

// ------- K3b: reduce partials -> bf16 kp16[b][h][kk][16], vp16[b][h][16][256] -------
__global__ __launch_bounds__(256) void k_ered_fin(const ushortT* __restrict__ part16,
        ushortT* __restrict__ kp16, ushortT* __restrict__ vp16) {
    const int idx = blockIdx.x*256 + threadIdx.x;  // 2*2*256*96 = 98304
    const int c  = idx % 96;
    const int kk = (idx / 96) % 256;
    const int m  = (idx / (96*256)) % 2;
    const int b  = idx / (96*256*2);
    float s = 0.f;
    long off = ((long)(b*128)*256 + kk)*192 + m*96 + c;
    for (int jc = 0; jc < 128; ++jc) {
        s += ubf(part16[off]);
        off += 49152;
    }
    const int h = c / DHD, d = c % DHD;
    ushortT v = bf1(s);
    if (m == 0) {
        kp16[((b*NH + h)*256 + kk)*16 + d] = v;
        if (d < 4) kp16[((b*NH + h)*256 + kk)*16 + 12 + d] = 0;
    } else {
        vp16[((b*NH + h)*16 + d)*256 + kk] = v;
    }
}

// ------- K4: barrier-free attention. Each wave owns 2 heads end-to-end;
// P in wave-private LDS laid out in PV B-frag order [ks][chunk][row][8].
// (R8 bug fixed: P-write offsets now in u32 units; max index 2047 u32/wave.) -------
__global__ __launch_bounds__(256) void k_attn(const ushortT* __restrict__ qkv16,
        const ushortT* __restrict__ kp16, const ushortT* __restrict__ vp16,
        ushortT* __restrict__ obuf) {
    __shared__ ushortT Pl[4][4096];    // 8KB per wave, 32KB total
    const int tid = threadIdx.x;
    const int lane = tid & 63, wv = tid >> 6;
    const int l15 = lane & 15, l4 = lane >> 4;
    const int r0 = blockIdx.x * 32;
    const int b = r0 >> 14;
    const float scale = 0.28867513459481287f;  // 1/sqrt(12)
    ushortT* Pw = &Pl[wv][0];
    unsigned int* Pu = (unsigned int*)Pw;
    // u32 units: [ks](256) [chunk=(mt&1)*2+(l4>>1)](64) [row=l15](4) [(l4&1)*2 + r/2]
    const int wbase = (l4 >> 1)*64 + l15*4 + (l4 & 1)*2;
    const f32x4 z = {0.f, 0.f, 0.f, 0.f};
#pragma unroll
    for (int hh = 0; hh < 2; ++hh) {
        const int h = wv + hh*4;
        const ushortT* kpb = kp16 + ((long)(b*NH + h) << 12) + l15*16 + l4*8;
        const ushortT* vb  = vp16 + (((long)(b*NH + h)*16 + l15) << 8) + l4*8;
#pragma unroll
        for (int nt = 0; nt < 2; ++nt) {
            // B-frag q: rows r0+nt*16+l15, k=d=l4*8..+7 (zero d>=12)
            short8v bq = {0, 0, 0, 0, 0, 0, 0, 0};
            {
                unsigned int* bq32 = (unsigned int*)&bq;
                const ushortT* qp = qkv16 + (long)(r0 + nt*16 + l15)*288 + h*12;
                if (l4 == 0) {
                    uint2 t0 = *reinterpret_cast<const uint2*>(qp);
                    uint2 t1 = *reinterpret_cast<const uint2*>(qp + 4);
                    bq32[0] = t0.x; bq32[1] = t0.y; bq32[2] = t1.x; bq32[3] = t1.y;
                } else if (l4 == 1) {
                    uint2 t0 = *reinterpret_cast<const uint2*>(qp + 8);
                    bq32[0] = t0.x; bq32[1] = t0.y;
                }
            }
            float psum = 0.f;
#pragma unroll
            for (int mt = 0; mt < 16; ++mt) {
                short8v a = *(const short8v*)(kpb + mt*256);
                f32x4 s = __builtin_amdgcn_mfma_f32_16x16x32_bf16(a, bq, z, 0, 0, 0);
                float p0 = __expf(s[0] * scale);
                float p1 = __expf(s[1] * scale);
                float p2 = __expf(s[2] * scale);
                float p3 = __expf(s[3] * scale);
                psum += (p0 + p1) + (p2 + p3);
                unsigned int* dst = Pu + (mt >> 1)*256 + (mt & 1)*128 + wbase;
                dst[0] = pk2(p0, p1);
                dst[1] = pk2(p2, p3);
            }
            psum += __shfl_xor(psum, 16, 64);
            psum += __shfl_xor(psum, 32, 64);
            float rinv = 1.0f / psum;
            f32x4 o = {0.f, 0.f, 0.f, 0.f};
#pragma unroll
            for (int ks = 0; ks < 8; ++ks) {
                short8v bp = *(const short8v*)(Pw + ks*512 + l4*128 + l15*8);
                short8v av = *(const short8v*)(vb + ks*32);
                o = __builtin_amdgcn_mfma_f32_16x16x32_bf16(av, bp, o, 0, 0, 0);
            }
            if (l4 < 3) {
                unsigned int* od = (unsigned int*)(obuf + (long)(r0 + nt*16 + l15)*96 + h*12 + l4*4);
                od[0] = pk2(o[0]*rinv, o[1]*rinv);
                od[1] = pk2(o[2]*rinv, o[3]*rinv);
            }
        }
    }
}

// ------- K5: out = o @ W0 via MFMA (W0^T bf16 frags from global) -------
__global__ __launch_bounds__(256) void k_out(const ushortT* __restrict__ obuf,
        const ushortT* __restrict__ w0T, float* __restrict__ out) {
    __shared__ ushortT ol[64*104];
    const int tid = threadIdx.x;
    const int r0 = blockIdx.x * 64;
    for (int i = tid; i < 768; i += 256) {
        int r = i / 12, sg = i % 12;
        *reinterpret_cast<uint4*>(&ol[r*104 + sg*8]) =
            *reinterpret_cast<const uint4*>(&obuf[(long)(r0 + r)*96 + sg*8]);
    }
    __syncthreads();
    const int lane = tid & 63, wv = tid >> 6;
    const int l15 = lane & 15, l4 = lane >> 4;
    short8v a[3];
#pragma unroll
    for (int kt = 0; kt < 3; ++kt)
        a[kt] = *(const short8v*)((const short*)ol + (wv*16 + l15)*104 + kt*32 + l4*8);
#pragma unroll
    for (int nt = 0; nt < 6; ++nt) {
        f32x4 acc = {0.f, 0.f, 0.f, 0.f};
#pragma unroll
        for (int kt = 0; kt < 3; ++kt) {
            short8v bw = *(const short8v*)((const short*)w0T + (nt*16 + l15)*96 + kt*32 + l4*8);
            acc = __builtin_amdgcn_mfma_f32_16x16x32_bf16(a[kt], bw, acc, 0, 0, 0);
        }
#pragma unroll
        for (int r = 0; r < 4; ++r)
            out[(long)(r0 + wv*16 + l4*4 + r)*96 + nt*16 + l15] = acc[r];
    }
}

extern "C" void kernel_launch(void* const* d_in, const int* in_sizes, int n_in,
                              void* d_out, int out_size, void* d_ws, size_t ws_size,
                              hipStream_t stream) {
    (void)in_sizes; (void)n_in; (void)out_size; (void)ws_size;
    const float* x    = (const float*)d_in[0];
    const float* Wqkv = (const float*)d_in[1];
    const float* W0   = (const float*)d_in[2];
    const float* E    = (const float*)d_in[3];
    const float* c0w  = (const float*)d_in[4];
    const float* c0b  = (const float*)d_in[5];
    const float* cspw = (const float*)d_in[6];
    const float* cspb = (const float*)d_in[7];
    const float* c1w  = (const float*)d_in[8];
    const float* c1b  = (const float*)d_in[9];
    float* out = (float*)d_out;
    float* ws  = (float*)d_ws;

    // ws layout (float offsets):
    // qkv16 @0 (4718592) | wqT16 @4718592 (13824) | w0T16 @4732416 (4608)
    // w1c16 @4737024 (4608) | ET16 @4741632 (2097152) | XT16 @6838784 (3145728)
    // a1 @9984512 (3145728) | a2 @13130240 (3145728)
    // part16 (6291456 f) overlays a1+a2 @9984512 (dead by k_ered); obuf same region
    // kp16 @16275968 (32768) | vp16 @16308736 (32768)  -> total ~65 MB
    ushortT* qkv16  = (ushortT*)ws;
    ushortT* wqT16  = (ushortT*)(ws + 4718592);
    ushortT* w0T16  = (ushortT*)(ws + 4732416);
    ushortT* w1c16  = (ushortT*)(ws + 4737024);
    ushortT* ET16   = (ushortT*)(ws + 4741632);
    ushortT* XT16   = (ushortT*)(ws + 6838784);
    float* a1   = ws + 9984512;
    float* a2   = ws + 13130240;
    ushortT* part16 = (ushortT*)(ws + 9984512);
    ushortT* obuf   = (ushortT*)(ws + 9984512);
    ushortT* kp16   = (ushortT*)(ws + 16275968);
    ushortT* vp16   = (ushortT*)(ws + 16308736);

    k_prep<<<dim3(1204), dim3(256), 0, stream>>>(E, Wqkv, W0, c1w, ET16, wqT16, w0T16, w1c16);
    k_qkv<<<dim3(NROW/64), dim3(256), 0, stream>>>(x, wqT16, qkv16);
    k_dw5<<<dim3(NROW/32), dim3(256), 0, stream>>>(x, c0w, c0b, a1);
    k_dw7<<<dim3(NROW/32), dim3(256), 0, stream>>>(a1, cspw, cspb, a2);
    k_pw_gate<<<dim3(NROW/64), dim3(256), 0, stream>>>(a2, w1c16, c1b, x, qkv16, XT16);
    k_ered<<<dim3(256), dim3(512), 0, stream>>>(ET16, XT16, part16);
    k_ered_fin<<<dim3(384), dim3(256), 0, stream>>>(part16, kp16, vp16);
    k_attn<<<dim3(NROW/32), dim3(256), 0, stream>>>(qkv16, kp16, vp16, obuf);
    k_out<<<dim3(NROW/64), dim3(256), 0, stream>>>(obuf, w0T16, out);
}

// Round 10
// 149.372 us; speedup vs baseline: 2.9639x; 1.0157x over previous
//
#include <hip/hip_runtime.h>

#define HH_ 128
#define WW_ 128
#define LL_ (HH_*WW_)     // 16384
#define NH 8
#define DHD 12
#define KD 256
#define BB_ 2
#define NROW (BB_*LL_)    // 32768

typedef __attribute__((ext_vector_type(8))) short short8v;
typedef __attribute__((ext_vector_type(4))) float f32x4;
typedef unsigned short ushortT;

__device__ __forceinline__ float4 ld4(const float* p) {
    return *reinterpret_cast<const float4*>(p);
}
__device__ __forceinline__ unsigned int pk2(float a, float b) {
    unsigned int ua = __float_as_uint(a);
    unsigned int ub = __float_as_uint(b);
    ua = (ua + 0x7FFFu + ((ua >> 16) & 1u)) >> 16;
    ub = (ub + 0x7FFFu + ((ub >> 16) & 1u)) >> 16;
    return ua | (ub << 16);
}
__device__ __forceinline__ ushortT bf1(float a) {
    unsigned int u = __float_as_uint(a);
    return (ushortT)((u + 0x7FFFu + ((u >> 16) & 1u)) >> 16);
}
__device__ __forceinline__ float ubf(ushortT v) {
    return __uint_as_float(((unsigned int)v) << 16);
}
// single-instruction packed f32->bf16 (RNE), gfx950
__device__ __forceinline__ unsigned int cvtpk(float a, float b) {
    unsigned int r;
    asm("v_cvt_pk_bf16_f32 %0, %1, %2" : "=v"(r) : "v"(a), "v"(b));
    return r;
}

// ------- K0: merged prep. blocks <1024: E -> ET16[kk][j] bf16 transposed;
//             blocks >=1024: Wqkv/W0 -> bf16 [n][k], w1 -> bf16 cast -------
__global__ __launch_bounds__(256) void k_prep(const float* __restrict__ E,
        const float* __restrict__ Wq, const float* __restrict__ W0,
        const float* __restrict__ w1, ushortT* __restrict__ ET,
        ushortT* __restrict__ wqT, ushortT* __restrict__ w0T,
        ushortT* __restrict__ w1c) {
    __shared__ ushortT Tz[64*66];
    const int tid = threadIdx.x;
    if (blockIdx.x < 1024) {
        const int jt = blockIdx.x >> 2, kt = blockIdx.x & 3;
        const int j0 = jt * 64, kk0 = kt * 64;
        for (int i = tid; i < 64*16; i += 256) {
            int row = i >> 4, s4 = (i & 15) << 2;
            float4 e4 = ld4(&E[(long)(j0 + row)*256 + kk0 + s4]);
            Tz[(s4 + 0)*66 + row] = bf1(e4.x);
            Tz[(s4 + 1)*66 + row] = bf1(e4.y);
            Tz[(s4 + 2)*66 + row] = bf1(e4.z);
            Tz[(s4 + 3)*66 + row] = bf1(e4.w);
        }
        __syncthreads();
        unsigned int* Tu = (unsigned int*)Tz;
        for (int i = tid; i < 64*32; i += 256) {
            int kk = i >> 5, s = i & 31;
            ((unsigned int*)ET)[(((long)(kk0 + kk) << 14) + j0 >> 1) + s] = Tu[kk*33 + s];
        }
    } else {
        int i = (blockIdx.x - 1024)*256 + tid;
        if (i < 27648) {
            int n = i / 96, k = i % 96;
            wqT[n*96 + k] = bf1(Wq[k*288 + n]);
        } else if (i < 36864) {
            int j = i - 27648;
            int n = j / 96, k = j % 96;
            w0T[n*96 + k] = bf1(W0[k*96 + n]);
        } else if (i < 46080) {
            int j = i - 36864;
            w1c[j] = bf1(w1[j]);
        }
    }
}

// ------- K1: qkv16 = bf16(x @ Wqkv) via MFMA -------
__global__ __launch_bounds__(256) void k_qkv(const float* __restrict__ x,
        const ushortT* __restrict__ wqT, ushortT* __restrict__ qkv16) {
    __shared__ ushortT xb[64*104];
    const int tid = threadIdx.x;
    const int r0w = blockIdx.x * 64;
    for (int i = tid; i < 64*48; i += 256) {
        int r = i / 48, cp = i % 48;
        const float* sp = x + (long)(r0w + r)*96 + cp*2;
        ((unsigned int*)xb)[r*52 + cp] = pk2(sp[0], sp[1]);
    }
    __syncthreads();
    const int lane = tid & 63, wv = tid >> 6;
    const int l15 = lane & 15, l4 = lane >> 4;
    short8v bx[3];
#pragma unroll
    for (int kt = 0; kt < 3; ++kt)
        bx[kt] = *(const short8v*)((const short*)xb + (wv*16 + l15)*104 + kt*32 + l4*8);
#pragma unroll 2
    for (int mt = 0; mt < 18; ++mt) {
        f32x4 acc = {0.f, 0.f, 0.f, 0.f};
#pragma unroll
        for (int kt = 0; kt < 3; ++kt) {
            short8v a = *(const short8v*)((const short*)wqT + (mt*16 + l15)*96 + kt*32 + l4*8);
            acc = __builtin_amdgcn_mfma_f32_16x16x32_bf16(a, bx[kt], acc, 0, 0, 0);
        }
        unsigned int* q32 = (unsigned int*)(qkv16 + (long)(r0w + wv*16 + l15)*288 + mt*16 + l4*4);
        q32[0] = pk2(acc[0], acc[1]);
        q32[1] = pk2(acc[2], acc[3]);
    }
}

// ---------------- K2a: depthwise 5x5, pad 2 (channels-last) ----------------
__global__ __launch_bounds__(256) void k_dw5(const float* __restrict__ xin,
                                             const float* __restrict__ w,
                                             const float* __restrict__ bias,
                                             float* __restrict__ out) {
    __shared__ float wl[25][96];
    const int tid = threadIdx.x;
    for (int i = tid; i < 25*96; i += 256) {
        int c = i / 25, t = i % 25;
        wl[t][c] = w[i];
    }
    __syncthreads();
    const int c4 = (tid & 7)*4;
    const int px = tid >> 3;
    const int pix0 = blockIdx.x * 32;
    const int b = pix0 >> 14;
    const int y = (pix0 & 16383) >> 7;
    const int xx = (pix0 & 127) + px;
    float4 acc[3];
#pragma unroll
    for (int ch = 0; ch < 3; ++ch) { acc[ch].x=0.f; acc[ch].y=0.f; acc[ch].z=0.f; acc[ch].w=0.f; }
#pragma unroll
    for (int iy = 0; iy < 5; ++iy) {
        int y2 = y + iy - 2;
        if (y2 < 0 || y2 >= HH_) continue;
#pragma unroll
        for (int ix = 0; ix < 5; ++ix) {
            int x2 = xx + ix - 2;
            if (x2 < 0 || x2 >= WW_) continue;
            const float* src = xin + ((b << 14) + y2*WW_ + x2)*96;
            const float* wt = &wl[iy*5 + ix][0];
#pragma unroll
            for (int ch = 0; ch < 3; ++ch) {
                float4 xv = ld4(src + ch*32 + c4);
                float4 wv = ld4(wt + ch*32 + c4);
                acc[ch].x = fmaf(xv.x, wv.x, acc[ch].x);
                acc[ch].y = fmaf(xv.y, wv.y, acc[ch].y);
                acc[ch].z = fmaf(xv.z, wv.z, acc[ch].z);
                acc[ch].w = fmaf(xv.w, wv.w, acc[ch].w);
            }
        }
    }
    float* dst = out + (long)(pix0 + px)*96;
#pragma unroll
    for (int ch = 0; ch < 3; ++ch) {
        float4 bv = ld4(bias + ch*32 + c4);
        float4 r;
        r.x = acc[ch].x + bv.x; r.y = acc[ch].y + bv.y;
        r.z = acc[ch].z + bv.z; r.w = acc[ch].w + bv.w;
        *reinterpret_cast<float4*>(dst + ch*32 + c4) = r;
    }
}

// ---------------- K2b: depthwise 7x7, dilation 3, pad 9 ----------------
__global__ __launch_bounds__(256) void k_dw7(const float* __restrict__ xin,
                                             const float* __restrict__ w,
                                             const float* __restrict__ bias,
                                             float* __restrict__ out) {
    __shared__ float wl[49][96];
    const int tid = threadIdx.x;
    for (int i = tid; i < 49*96; i += 256) {
        int c = i / 49, t = i % 49;
        wl[t][c] = w[i];
    }
    __syncthreads();
    const int c4 = (tid & 7)*4;
    const int px = tid >> 3;
    const int pix0 = blockIdx.x * 32;
    const int b = pix0 >> 14;
    const int y = (pix0 & 16383) >> 7;
    const int xx = (pix0 & 127) + px;
    float4 acc[3];
#pragma unroll
    for (int ch = 0; ch < 3; ++ch) { acc[ch].x=0.f; acc[ch].y=0.f; acc[ch].z=0.f; acc[ch].w=0.f; }
#pragma unroll
    for (int iy = 0; iy < 7; ++iy) {
        int y2 = y + iy*3 - 9;
        if (y2 < 0 || y2 >= HH_) continue;
#pragma unroll
        for (int ix = 0; ix < 7; ++ix) {
            int x2 = xx + ix*3 - 9;
            if (x2 < 0 || x2 >= WW_) continue;
            const float* src = xin + ((b << 14) + y2*WW_ + x2)*96;
            const float* wt = &wl[iy*7 + ix][0];
#pragma unroll
            for (int ch = 0; ch < 3; ++ch) {
                float4 xv = ld4(src + ch*32 + c4);
                float4 wv = ld4(wt + ch*32 + c4);
                acc[ch].x = fmaf(xv.x, wv.x, acc[ch].x);
                acc[ch].y = fmaf(xv.y, wv.y, acc[ch].y);
                acc[ch].z = fmaf(xv.z, wv.z, acc[ch].z);
                acc[ch].w = fmaf(xv.w, wv.w, acc[ch].w);
            }
        }
    }
    float* dst = out + (long)(pix0 + px)*96;
#pragma unroll
    for (int ch = 0; ch < 3; ++ch) {
        float4 bv = ld4(bias + ch*32 + c4);
        float4 r;
        r.x = acc[ch].x + bv.x; r.y = acc[ch].y + bv.y;
        r.z = acc[ch].z + bv.z; r.w = acc[ch].w + bv.w;
        *reinterpret_cast<float4*>(dst + ch*32 + c4) = r;
    }
}

// ------- K2c: fused a3 = a2@w1^T + b1 (MFMA); vf = x*a3*v; writes BOTH halves
// of XT[b][cc 192][j] (cc<96 = k transposed, cc>=96 = vf transposed). 64 rows/blk -------
__global__ __launch_bounds__(256) void k_pw_gate(const float* __restrict__ a2,
        const ushortT* __restrict__ w1c, const float* __restrict__ b1,
        const float* __restrict__ xin, const ushortT* __restrict__ qkv16,
        ushortT* __restrict__ XT) {
    __shared__ ushortT ab[64*104];     // 13312B
    __shared__ ushortT ktile[96*66];   // 12672B
    __shared__ ushortT vtile[96*66];   // 12672B
    const int tid = threadIdx.x;
    const int r0 = blockIdx.x * 64;
    const int b = r0 >> 14, j0 = r0 & 16383;
    for (int i = tid; i < 64*48; i += 256) {
        int r = i / 48, cp = i % 48;
        const float* sp = a2 + (long)(r0 + r)*96 + cp*2;
        ((unsigned int*)ab)[r*52 + cp] = pk2(sp[0], sp[1]);
    }
    const unsigned int* q32 = (const unsigned int*)qkv16;
    for (int i = tid; i < 64*48; i += 256) {
        int row = i / 48, cp = i % 48;
        unsigned int kk2 = q32[(long)(r0 + row)*144 + 48 + cp];
        ktile[(2*cp + 0)*66 + row] = (ushortT)(kk2 & 0xFFFF);
        ktile[(2*cp + 1)*66 + row] = (ushortT)(kk2 >> 16);
    }
    __syncthreads();
    const int lane = tid & 63, wv = tid >> 6;
    const int l15 = lane & 15, l4 = lane >> 4;
    const int row = r0 + wv*16 + l15;
    const int jloc = wv*16 + l15;
    short8v bx[3];
#pragma unroll
    for (int kt = 0; kt < 3; ++kt)
        bx[kt] = *(const short8v*)((const short*)ab + (wv*16 + l15)*104 + kt*32 + l4*8);
#pragma unroll
    for (int mt = 0; mt < 6; ++mt) {
        f32x4 acc = {0.f, 0.f, 0.f, 0.f};
#pragma unroll
        for (int kt = 0; kt < 3; ++kt) {
            short8v a = *(const short8v*)((const short*)w1c + (mt*16 + l15)*96 + kt*32 + l4*8);
            acc = __builtin_amdgcn_mfma_f32_16x16x32_bf16(a, bx[kt], acc, 0, 0, 0);
        }
        const int c0 = mt*16 + l4*4;
        float4 b4 = ld4(&b1[c0]);
        float4 x4 = ld4(&xin[(long)row*96 + c0]);
        uint2 vv = *reinterpret_cast<const uint2*>(qkv16 + (long)row*288 + 192 + c0);
        float v0 = ubf((ushortT)(vv.x & 0xFFFF)), v1 = ubf((ushortT)(vv.x >> 16));
        float v2 = ubf((ushortT)(vv.y & 0xFFFF)), v3 = ubf((ushortT)(vv.y >> 16));
        vtile[(c0 + 0)*66 + jloc] = bf1(x4.x * v0 * (acc[0] + b4.x));
        vtile[(c0 + 1)*66 + jloc] = bf1(x4.y * v1 * (acc[1] + b4.y));
        vtile[(c0 + 2)*66 + jloc] = bf1(x4.z * v2 * (acc[2] + b4.z));
        vtile[(c0 + 3)*66 + jloc] = bf1(x4.w * v3 * (acc[3] + b4.w));
    }
    __syncthreads();
    unsigned int* XTu = (unsigned int*)XT;
    unsigned int* ku = (unsigned int*)ktile;
    unsigned int* vu = (unsigned int*)vtile;
    for (int i = tid; i < 96*32; i += 256) {
        int cc = i >> 5, s = i & 31;
        XTu[((((long)b*192 + cc) << 14) + j0 >> 1) + s] = ku[cc*33 + s];
    }
    for (int i = tid; i < 96*32; i += 256) {
        int cc = i >> 5, s = i & 31;
        XTu[((((long)b*192 + 96 + cc) << 14) + j0 >> 1) + s] = vu[cc*33 + s];
    }
}

// ------- K3a: E-reduction as MFMA split-K GEMM (no LDS) -------
__global__ __launch_bounds__(512) void k_ered(const ushortT* __restrict__ ET,
        const ushortT* __restrict__ XT, ushortT* __restrict__ part16) {
    const int tid = threadIdx.x;
    const int lane = tid & 63, wv = tid >> 6;
    const int l15 = lane & 15, l4 = lane >> 4;
    const int mtg = wv & 3, nth = wv >> 2;
    const int b  = blockIdx.x >> 7;
    const int jc = blockIdx.x & 127;
    const int j0 = jc * 128;
    f32x4 acc[4][6];
#pragma unroll
    for (int mi = 0; mi < 4; ++mi)
#pragma unroll
        for (int ni = 0; ni < 6; ++ni)
            acc[mi][ni] = (f32x4){0.f, 0.f, 0.f, 0.f};
    const ushortT* Ab = ET + ((long)(mtg*64 + l15) << 14) + j0 + l4*8;
    const ushortT* Bb = XT + (((long)b*192 + nth*96 + l15) << 14) + j0 + l4*8;
#pragma unroll
    for (int ks = 0; ks < 4; ++ks) {
        short8v a[4], bx[6];
#pragma unroll
        for (int mi = 0; mi < 4; ++mi)
            a[mi] = *(const short8v*)(Ab + ((long)mi << 18) + ks*32);
#pragma unroll
        for (int ni = 0; ni < 6; ++ni)
            bx[ni] = *(const short8v*)(Bb + ((long)ni << 18) + ks*32);
#pragma unroll
        for (int mi = 0; mi < 4; ++mi)
#pragma unroll
            for (int ni = 0; ni < 6; ++ni)
                acc[mi][ni] = __builtin_amdgcn_mfma_f32_16x16x32_bf16(a[mi], bx[ni], acc[mi][ni], 0, 0, 0);
    }
    const long base = (long)(b*128 + jc)*49152;
#pragma unroll
    for (int mi = 0; mi < 4; ++mi) {
        int kkb = (mtg*4 + mi)*16 + l4*4;
#pragma unroll
        for (int ni = 0; ni < 6; ++ni) {
            int cc = (nth*6 + ni)*16 + l15;
#pragma unroll
            for (int r = 0; r < 4; ++r)
                part16[base + (long)(kkb + r)*192 + cc] = bf1(acc[mi][ni][r]);
        }
    }
}

// ------- K3b: reduce partials -> bf16 kp16[b][h][kk][16] (scaled by 1/sqrt(12)*log2e,
// pads 0), vp16[b][h][16][256] (row 12 = ONES for MFMA row-sum, 13..15 = 0) -------
__global__ __launch_bounds__(256) void k_ered_fin(const ushortT* __restrict__ part16,
        ushortT* __restrict__ kp16, ushortT* __restrict__ vp16) {
    const int idx = blockIdx.x*256 + threadIdx.x;  // 2*2*256*96 = 98304
    const int c  = idx % 96;
    const int kk = (idx / 96) % 256;
    const int m  = (idx / (96*256)) % 2;
    const int b  = idx / (96*256*2);
    float s = 0.f;
    long off = ((long)(b*128)*256 + kk)*192 + m*96 + c;
    for (int jc = 0; jc < 128; ++jc) {
        s += ubf(part16[off]);
        off += 49152;
    }
    const int h = c / DHD, d = c % DHD;
    if (m == 0) {
        // fold softmax scale * log2(e) into k' so QK output feeds exp2 directly
        kp16[((b*NH + h)*256 + kk)*16 + d] = bf1(s * 0.4164701998f);
        if (d < 4) kp16[((b*NH + h)*256 + kk)*16 + 12 + d] = 0;
    } else {
        vp16[((b*NH + h)*16 + d)*256 + kk] = bf1(s);
        if (d < 4)
            vp16[((b*NH + h)*16 + 12 + d)*256 + kk] = (d == 0) ? (ushortT)0x3F80 : (ushortT)0;
    }
}

// ------- K4: barrier-free attention. Wave owns 2 heads end-to-end.
// kp A-frags hoisted to 16 regs (reused across both nt); softmax denom via
// PV row d=12 (= ones) -> free MFMA row-sum; exp2 + v_cvt_pk_bf16_f32 -------
__global__ __launch_bounds__(256) void k_attn(const ushortT* __restrict__ qkv16,
        const ushortT* __restrict__ kp16, const ushortT* __restrict__ vp16,
        ushortT* __restrict__ obuf) {
    __shared__ ushortT Pl[4][4096];    // 8KB per wave, 32KB total
    const int tid = threadIdx.x;
    const int lane = tid & 63, wv = tid >> 6;
    const int l15 = lane & 15, l4 = lane >> 4;
    const int r0 = blockIdx.x * 32;
    const int b = r0 >> 14;
    ushortT* Pw = &Pl[wv][0];
    unsigned int* Pu = (unsigned int*)Pw;
    // u32 units: [ks](256) [chunk=(mt&1)*2+(l4>>1)](64) [row=l15](4) [(l4&1)*2 + r/2]
    const int wbase = (l4 >> 1)*64 + l15*4 + (l4 & 1)*2;
    const f32x4 z = {0.f, 0.f, 0.f, 0.f};
#pragma unroll
    for (int hh = 0; hh < 2; ++hh) {
        const int h = wv + hh*4;
        const ushortT* kpb = kp16 + ((long)(b*NH + h) << 12) + l15*16 + l4*8;
        const ushortT* vb  = vp16 + (((long)(b*NH + h)*16 + l15) << 8) + l4*8;
        short8v a[16];
#pragma unroll
        for (int mt = 0; mt < 16; ++mt)
            a[mt] = *(const short8v*)(kpb + mt*256);
#pragma unroll
        for (int nt = 0; nt < 2; ++nt) {
            short8v bq = {0, 0, 0, 0, 0, 0, 0, 0};
            {
                unsigned int* bq32 = (unsigned int*)&bq;
                const ushortT* qp = qkv16 + (long)(r0 + nt*16 + l15)*288 + h*12;
                if (l4 == 0) {
                    uint2 t0 = *reinterpret_cast<const uint2*>(qp);
                    uint2 t1 = *reinterpret_cast<const uint2*>(qp + 4);
                    bq32[0] = t0.x; bq32[1] = t0.y; bq32[2] = t1.x; bq32[3] = t1.y;
                } else if (l4 == 1) {
                    uint2 t0 = *reinterpret_cast<const uint2*>(qp + 8);
                    bq32[0] = t0.x; bq32[1] = t0.y;
                }
            }
#pragma unroll
            for (int mt = 0; mt < 16; ++mt) {
                f32x4 s = __builtin_amdgcn_mfma_f32_16x16x32_bf16(a[mt], bq, z, 0, 0, 0);
                unsigned int* dst = Pu + (mt >> 1)*256 + (mt & 1)*128 + wbase;
                dst[0] = cvtpk(exp2f(s[0]), exp2f(s[1]));
                dst[1] = cvtpk(exp2f(s[2]), exp2f(s[3]));
            }
            f32x4 o = z;
#pragma unroll
            for (int ks = 0; ks < 8; ++ks) {
                short8v bp = *(const short8v*)(Pw + ks*512 + l4*128 + l15*8);
                short8v av = *(const short8v*)(vb + ks*32);
                o = __builtin_amdgcn_mfma_f32_16x16x32_bf16(av, bp, o, 0, 0, 0);
            }
            // row-sum sits in output row m=12 (V pad row of ones): lane 48+l15, reg 0
            float rinv = 1.0f / __shfl(o[0], 48 + l15, 64);
            if (l4 < 3) {
                unsigned int* od = (unsigned int*)(obuf + (long)(r0 + nt*16 + l15)*96 + h*12 + l4*4);
                od[0] = cvtpk(o[0]*rinv, o[1]*rinv);
                od[1] = cvtpk(o[2]*rinv, o[3]*rinv);
            }
        }
    }
}

// ------- K5: out = o @ W0 via MFMA (W0^T bf16 frags from global) -------
__global__ __launch_bounds__(256) void k_out(const ushortT* __restrict__ obuf,
        const ushortT* __restrict__ w0T, float* __restrict__ out) {
    __shared__ ushortT ol[64*104];
    const int tid = threadIdx.x;
    const int r0 = blockIdx.x * 64;
    for (int i = tid; i < 768; i += 256) {
        int r = i / 12, sg = i % 12;
        *reinterpret_cast<uint4*>(&ol[r*104 + sg*8]) =
            *reinterpret_cast<const uint4*>(&obuf[(long)(r0 + r)*96 + sg*8]);
    }
    __syncthreads();
    const int lane = tid & 63, wv = tid >> 6;
    const int l15 = lane & 15, l4 = lane >> 4;
    short8v a[3];
#pragma unroll
    for (int kt = 0; kt < 3; ++kt)
        a[kt] = *(const short8v*)((const short*)ol + (wv*16 + l15)*104 + kt*32 + l4*8);
#pragma unroll
    for (int nt = 0; nt < 6; ++nt) {
        f32x4 acc = {0.f, 0.f, 0.f, 0.f};
#pragma unroll
        for (int kt = 0; kt < 3; ++kt) {
            short8v bw = *(const short8v*)((const short*)w0T + (nt*16 + l15)*96 + kt*32 + l4*8);
            acc = __builtin_amdgcn_mfma_f32_16x16x32_bf16(a[kt], bw, acc, 0, 0, 0);
        }
#pragma unroll
        for (int r = 0; r < 4; ++r)
            out[(long)(r0 + wv*16 + l4*4 + r)*96 + nt*16 + l15] = acc[r];
    }
}

extern "C" void kernel_launch(void* const* d_in, const int* in_sizes, int n_in,
                              void* d_out, int out_size, void* d_ws, size_t ws_size,
                              hipStream_t stream) {
    (void)in_sizes; (void)n_in; (void)out_size; (void)ws_size;
    const float* x    = (const float*)d_in[0];
    const float* Wqkv = (const float*)d_in[1];
    const float* W0   = (const float*)d_in[2];
    const float* E    = (const float*)d_in[3];
    const float* c0w  = (const float*)d_in[4];
    const float* c0b  = (const float*)d_in[5];
    const float* cspw = (const float*)d_in[6];
    const float* cspb = (const float*)d_in[7];
    const float* c1w  = (const float*)d_in[8];
    const float* c1b  = (const float*)d_in[9];
    float* out = (float*)d_out;
    float* ws  = (float*)d_ws;

    ushortT* qkv16  = (ushortT*)ws;
    ushortT* wqT16  = (ushortT*)(ws + 4718592);
    ushortT* w0T16  = (ushortT*)(ws + 4732416);
    ushortT* w1c16  = (ushortT*)(ws + 4737024);
    ushortT* ET16   = (ushortT*)(ws + 4741632);
    ushortT* XT16   = (ushortT*)(ws + 6838784);
    float* a1   = ws + 9984512;
    float* a2   = ws + 13130240;
    ushortT* part16 = (ushortT*)(ws + 9984512);
    ushortT* obuf   = (ushortT*)(ws + 9984512);
    ushortT* kp16   = (ushortT*)(ws + 16275968);
    ushortT* vp16   = (ushortT*)(ws + 16308736);

    k_prep<<<dim3(1204), dim3(256), 0, stream>>>(E, Wqkv, W0, c1w, ET16, wqT16, w0T16, w1c16);
    k_qkv<<<dim3(NROW/64), dim3(256), 0, stream>>>(x, wqT16, qkv16);
    k_dw5<<<dim3(NROW/32), dim3(256), 0, stream>>>(x, c0w, c0b, a1);
    k_dw7<<<dim3(NROW/32), dim3(256), 0, stream>>>(a1, cspw, cspb, a2);
    k_pw_gate<<<dim3(NROW/64), dim3(256), 0, stream>>>(a2, w1c16, c1b, x, qkv16, XT16);
    k_ered<<<dim3(256), dim3(512), 0, stream>>>(ET16, XT16, part16);
    k_ered_fin<<<dim3(384), dim3(256), 0, stream>>>(part16, kp16, vp16);
    k_attn<<<dim3(NROW/32), dim3(256), 0, stream>>>(qkv16, kp16, vp16, obuf);
    k_out<<<dim3(NROW/64), dim3(256), 0, stream>>>(obuf, w0T16, out);
}

// Round 11
// 148.048 us; speedup vs baseline: 2.9904x; 1.0089x over previous
//
#include <hip/hip_runtime.h>

#define HH_ 128
#define WW_ 128
#define LL_ (HH_*WW_)     // 16384
#define NH 8
#define DHD 12
#define KD 256
#define BB_ 2
#define NROW (BB_*LL_)    // 32768

typedef __attribute__((ext_vector_type(8))) short short8v;
typedef __attribute__((ext_vector_type(4))) float f32x4;
typedef unsigned short ushortT;

__device__ __forceinline__ float4 ld4(const float* p) {
    return *reinterpret_cast<const float4*>(p);
}
__device__ __forceinline__ unsigned int pk2(float a, float b) {
    unsigned int ua = __float_as_uint(a);
    unsigned int ub = __float_as_uint(b);
    ua = (ua + 0x7FFFu + ((ua >> 16) & 1u)) >> 16;
    ub = (ub + 0x7FFFu + ((ub >> 16) & 1u)) >> 16;
    return ua | (ub << 16);
}
__device__ __forceinline__ ushortT bf1(float a) {
    unsigned int u = __float_as_uint(a);
    return (ushortT)((u + 0x7FFFu + ((u >> 16) & 1u)) >> 16);
}
__device__ __forceinline__ float ubf(ushortT v) {
    return __uint_as_float(((unsigned int)v) << 16);
}
// single-instruction packed f32->bf16 (RNE), gfx950
__device__ __forceinline__ unsigned int cvtpk(float a, float b) {
    unsigned int r;
    asm("v_cvt_pk_bf16_f32 %0, %1, %2" : "=v"(r) : "v"(a), "v"(b));
    return r;
}

// ------- K0: merged prep. blocks <1024: E -> ET16[kk][j] bf16 transposed;
//             blocks >=1024: Wqkv/W0 -> bf16 [n][k], w1 -> bf16 cast -------
__global__ __launch_bounds__(256) void k_prep(const float* __restrict__ E,
        const float* __restrict__ Wq, const float* __restrict__ W0,
        const float* __restrict__ w1, ushortT* __restrict__ ET,
        ushortT* __restrict__ wqT, ushortT* __restrict__ w0T,
        ushortT* __restrict__ w1c) {
    __shared__ ushortT Tz[64*66];
    const int tid = threadIdx.x;
    if (blockIdx.x < 1024) {
        const int jt = blockIdx.x >> 2, kt = blockIdx.x & 3;
        const int j0 = jt * 64, kk0 = kt * 64;
        for (int i = tid; i < 64*16; i += 256) {
            int row = i >> 4, s4 = (i & 15) << 2;
            float4 e4 = ld4(&E[(long)(j0 + row)*256 + kk0 + s4]);
            Tz[(s4 + 0)*66 + row] = bf1(e4.x);
            Tz[(s4 + 1)*66 + row] = bf1(e4.y);
            Tz[(s4 + 2)*66 + row] = bf1(e4.z);
            Tz[(s4 + 3)*66 + row] = bf1(e4.w);
        }
        __syncthreads();
        unsigned int* Tu = (unsigned int*)Tz;
        for (int i = tid; i < 64*32; i += 256) {
            int kk = i >> 5, s = i & 31;
            ((unsigned int*)ET)[(((long)(kk0 + kk) << 14) + j0 >> 1) + s] = Tu[kk*33 + s];
        }
    } else {
        int i = (blockIdx.x - 1024)*256 + tid;
        if (i < 27648) {
            int n = i / 96, k = i % 96;
            wqT[n*96 + k] = bf1(Wq[k*288 + n]);
        } else if (i < 36864) {
            int j = i - 27648;
            int n = j / 96, k = j % 96;
            w0T[n*96 + k] = bf1(W0[k*96 + n]);
        } else if (i < 46080) {
            int j = i - 36864;
            w1c[j] = bf1(w1[j]);
        }
    }
}

// ------- K1: qkv16 = bf16(x @ Wqkv) via MFMA -------
__global__ __launch_bounds__(256) void k_qkv(const float* __restrict__ x,
        const ushortT* __restrict__ wqT, ushortT* __restrict__ qkv16) {
    __shared__ ushortT xb[64*104];
    const int tid = threadIdx.x;
    const int r0w = blockIdx.x * 64;
    for (int i = tid; i < 64*48; i += 256) {
        int r = i / 48, cp = i % 48;
        const float* sp = x + (long)(r0w + r)*96 + cp*2;
        ((unsigned int*)xb)[r*52 + cp] = pk2(sp[0], sp[1]);
    }
    __syncthreads();
    const int lane = tid & 63, wv = tid >> 6;
    const int l15 = lane & 15, l4 = lane >> 4;
    short8v bx[3];
#pragma unroll
    for (int kt = 0; kt < 3; ++kt)
        bx[kt] = *(const short8v*)((const short*)xb + (wv*16 + l15)*104 + kt*32 + l4*8);
#pragma unroll 2
    for (int mt = 0; mt < 18; ++mt) {
        f32x4 acc = {0.f, 0.f, 0.f, 0.f};
#pragma unroll
        for (int kt = 0; kt < 3; ++kt) {
            short8v a = *(const short8v*)((const short*)wqT + (mt*16 + l15)*96 + kt*32 + l4*8);
            acc = __builtin_amdgcn_mfma_f32_16x16x32_bf16(a, bx[kt], acc, 0, 0, 0);
        }
        unsigned int* q32 = (unsigned int*)(qkv16 + (long)(r0w + wv*16 + l15)*288 + mt*16 + l4*4);
        q32[0] = pk2(acc[0], acc[1]);
        q32[1] = pk2(acc[2], acc[3]);
    }
}

// ---------------- K2a: depthwise 5x5, pad 2 (channels-last) ----------------
__global__ __launch_bounds__(256) void k_dw5(const float* __restrict__ xin,
                                             const float* __restrict__ w,
                                             const float* __restrict__ bias,
                                             float* __restrict__ out) {
    __shared__ float wl[25][96];
    const int tid = threadIdx.x;
    for (int i = tid; i < 25*96; i += 256) {
        int c = i / 25, t = i % 25;
        wl[t][c] = w[i];
    }
    __syncthreads();
    const int c4 = (tid & 7)*4;
    const int px = tid >> 3;
    const int pix0 = blockIdx.x * 32;
    const int b = pix0 >> 14;
    const int y = (pix0 & 16383) >> 7;
    const int xx = (pix0 & 127) + px;
    float4 acc[3];
#pragma unroll
    for (int ch = 0; ch < 3; ++ch) { acc[ch].x=0.f; acc[ch].y=0.f; acc[ch].z=0.f; acc[ch].w=0.f; }
#pragma unroll
    for (int iy = 0; iy < 5; ++iy) {
        int y2 = y + iy - 2;
        if (y2 < 0 || y2 >= HH_) continue;
#pragma unroll
        for (int ix = 0; ix < 5; ++ix) {
            int x2 = xx + ix - 2;
            if (x2 < 0 || x2 >= WW_) continue;
            const float* src = xin + ((b << 14) + y2*WW_ + x2)*96;
            const float* wt = &wl[iy*5 + ix][0];
#pragma unroll
            for (int ch = 0; ch < 3; ++ch) {
                float4 xv = ld4(src + ch*32 + c4);
                float4 wv = ld4(wt + ch*32 + c4);
                acc[ch].x = fmaf(xv.x, wv.x, acc[ch].x);
                acc[ch].y = fmaf(xv.y, wv.y, acc[ch].y);
                acc[ch].z = fmaf(xv.z, wv.z, acc[ch].z);
                acc[ch].w = fmaf(xv.w, wv.w, acc[ch].w);
            }
        }
    }
    float* dst = out + (long)(pix0 + px)*96;
#pragma unroll
    for (int ch = 0; ch < 3; ++ch) {
        float4 bv = ld4(bias + ch*32 + c4);
        float4 r;
        r.x = acc[ch].x + bv.x; r.y = acc[ch].y + bv.y;
        r.z = acc[ch].z + bv.z; r.w = acc[ch].w + bv.w;
        *reinterpret_cast<float4*>(dst + ch*32 + c4) = r;
    }
}

// ---------------- K2b: depthwise 7x7, dilation 3, pad 9 ----------------
__global__ __launch_bounds__(256) void k_dw7(const float* __restrict__ xin,
                                             const float* __restrict__ w,
                                             const float* __restrict__ bias,
                                             float* __restrict__ out) {
    __shared__ float wl[49][96];
    const int tid = threadIdx.x;
    for (int i = tid; i < 49*96; i += 256) {
        int c = i / 49, t = i % 49;
        wl[t][c] = w[i];
    }
    __syncthreads();
    const int c4 = (tid & 7)*4;
    const int px = tid >> 3;
    const int pix0 = blockIdx.x * 32;
    const int b = pix0 >> 14;
    const int y = (pix0 & 16383) >> 7;
    const int xx = (pix0 & 127) + px;
    float4 acc[3];
#pragma unroll
    for (int ch = 0; ch < 3; ++ch) { acc[ch].x=0.f; acc[ch].y=0.f; acc[ch].z=0.f; acc[ch].w=0.f; }
#pragma unroll
    for (int iy = 0; iy < 7; ++iy) {
        int y2 = y + iy*3 - 9;
        if (y2 < 0 || y2 >= HH_) continue;
#pragma unroll
        for (int ix = 0; ix < 7; ++ix) {
            int x2 = xx + ix*3 - 9;
            if (x2 < 0 || x2 >= WW_) continue;
            const float* src = xin + ((b << 14) + y2*WW_ + x2)*96;
            const float* wt = &wl[iy*7 + ix][0];
#pragma unroll
            for (int ch = 0; ch < 3; ++ch) {
                float4 xv = ld4(src + ch*32 + c4);
                float4 wv = ld4(wt + ch*32 + c4);
                acc[ch].x = fmaf(xv.x, wv.x, acc[ch].x);
                acc[ch].y = fmaf(xv.y, wv.y, acc[ch].y);
                acc[ch].z = fmaf(xv.z, wv.z, acc[ch].z);
                acc[ch].w = fmaf(xv.w, wv.w, acc[ch].w);
            }
        }
    }
    float* dst = out + (long)(pix0 + px)*96;
#pragma unroll
    for (int ch = 0; ch < 3; ++ch) {
        float4 bv = ld4(bias + ch*32 + c4);
        float4 r;
        r.x = acc[ch].x + bv.x; r.y = acc[ch].y + bv.y;
        r.z = acc[ch].z + bv.z; r.w = acc[ch].w + bv.w;
        *reinterpret_cast<float4*>(dst + ch*32 + c4) = r;
    }
}

// ------- K2c: fused a3 = a2@w1^T + b1 (MFMA); vf = x*a3*v; writes BOTH halves
// of XT[b][cc 192][j] (cc<96 = k transposed, cc>=96 = vf transposed). 64 rows/blk -------
__global__ __launch_bounds__(256) void k_pw_gate(const float* __restrict__ a2,
        const ushortT* __restrict__ w1c, const float* __restrict__ b1,
        const float* __restrict__ xin, const ushortT* __restrict__ qkv16,
        ushortT* __restrict__ XT) {
    __shared__ ushortT ab[64*104];     // 13312B
    __shared__ ushortT ktile[96*66];   // 12672B
    __shared__ ushortT vtile[96*66];   // 12672B
    const int tid = threadIdx.x;
    const int r0 = blockIdx.x * 64;
    const int b = r0 >> 14, j0 = r0 & 16383;
    for (int i = tid; i < 64*48; i += 256) {
        int r = i / 48, cp = i % 48;
        const float* sp = a2 + (long)(r0 + r)*96 + cp*2;
        ((unsigned int*)ab)[r*52 + cp] = pk2(sp[0], sp[1]);
    }
    const unsigned int* q32 = (const unsigned int*)qkv16;
    for (int i = tid; i < 64*48; i += 256) {
        int row = i / 48, cp = i % 48;
        unsigned int kk2 = q32[(long)(r0 + row)*144 + 48 + cp];
        ktile[(2*cp + 0)*66 + row] = (ushortT)(kk2 & 0xFFFF);
        ktile[(2*cp + 1)*66 + row] = (ushortT)(kk2 >> 16);
    }
    __syncthreads();
    const int lane = tid & 63, wv = tid >> 6;
    const int l15 = lane & 15, l4 = lane >> 4;
    const int row = r0 + wv*16 + l15;
    const int jloc = wv*16 + l15;
    short8v bx[3];
#pragma unroll
    for (int kt = 0; kt < 3; ++kt)
        bx[kt] = *(const short8v*)((const short*)ab + (wv*16 + l15)*104 + kt*32 + l4*8);
#pragma unroll
    for (int mt = 0; mt < 6; ++mt) {
        f32x4 acc = {0.f, 0.f, 0.f, 0.f};
#pragma unroll
        for (int kt = 0; kt < 3; ++kt) {
            short8v a = *(const short8v*)((const short*)w1c + (mt*16 + l15)*96 + kt*32 + l4*8);
            acc = __builtin_amdgcn_mfma_f32_16x16x32_bf16(a, bx[kt], acc, 0, 0, 0);
        }
        const int c0 = mt*16 + l4*4;
        float4 b4 = ld4(&b1[c0]);
        float4 x4 = ld4(&xin[(long)row*96 + c0]);
        uint2 vv = *reinterpret_cast<const uint2*>(qkv16 + (long)row*288 + 192 + c0);
        float v0 = ubf((ushortT)(vv.x & 0xFFFF)), v1 = ubf((ushortT)(vv.x >> 16));
        float v2 = ubf((ushortT)(vv.y & 0xFFFF)), v3 = ubf((ushortT)(vv.y >> 16));
        vtile[(c0 + 0)*66 + jloc] = bf1(x4.x * v0 * (acc[0] + b4.x));
        vtile[(c0 + 1)*66 + jloc] = bf1(x4.y * v1 * (acc[1] + b4.y));
        vtile[(c0 + 2)*66 + jloc] = bf1(x4.z * v2 * (acc[2] + b4.z));
        vtile[(c0 + 3)*66 + jloc] = bf1(x4.w * v3 * (acc[3] + b4.w));
    }
    __syncthreads();
    unsigned int* XTu = (unsigned int*)XT;
    unsigned int* ku = (unsigned int*)ktile;
    unsigned int* vu = (unsigned int*)vtile;
    for (int i = tid; i < 96*32; i += 256) {
        int cc = i >> 5, s = i & 31;
        XTu[((((long)b*192 + cc) << 14) + j0 >> 1) + s] = ku[cc*33 + s];
    }
    for (int i = tid; i < 96*32; i += 256) {
        int cc = i >> 5, s = i & 31;
        XTu[((((long)b*192 + 96 + cc) << 14) + j0 >> 1) + s] = vu[cc*33 + s];
    }
}

// ------- K3a: E-reduction as MFMA split-K GEMM (no LDS) -------
__global__ __launch_bounds__(512) void k_ered(const ushortT* __restrict__ ET,
        const ushortT* __restrict__ XT, ushortT* __restrict__ part16) {
    const int tid = threadIdx.x;
    const int lane = tid & 63, wv = tid >> 6;
    const int l15 = lane & 15, l4 = lane >> 4;
    const int mtg = wv & 3, nth = wv >> 2;
    const int b  = blockIdx.x >> 7;
    const int jc = blockIdx.x & 127;
    const int j0 = jc * 128;
    f32x4 acc[4][6];
#pragma unroll
    for (int mi = 0; mi < 4; ++mi)
#pragma unroll
        for (int ni = 0; ni < 6; ++ni)
            acc[mi][ni] = (f32x4){0.f, 0.f, 0.f, 0.f};
    const ushortT* Ab = ET + ((long)(mtg*64 + l15) << 14) + j0 + l4*8;
    const ushortT* Bb = XT + (((long)b*192 + nth*96 + l15) << 14) + j0 + l4*8;
#pragma unroll
    for (int ks = 0; ks < 4; ++ks) {
        short8v a[4], bx[6];
#pragma unroll
        for (int mi = 0; mi < 4; ++mi)
            a[mi] = *(const short8v*)(Ab + ((long)mi << 18) + ks*32);
#pragma unroll
        for (int ni = 0; ni < 6; ++ni)
            bx[ni] = *(const short8v*)(Bb + ((long)ni << 18) + ks*32);
#pragma unroll
        for (int mi = 0; mi < 4; ++mi)
#pragma unroll
            for (int ni = 0; ni < 6; ++ni)
                acc[mi][ni] = __builtin_amdgcn_mfma_f32_16x16x32_bf16(a[mi], bx[ni], acc[mi][ni], 0, 0, 0);
    }
    const long base = (long)(b*128 + jc)*49152;
#pragma unroll
    for (int mi = 0; mi < 4; ++mi) {
        int kkb = (mtg*4 + mi)*16 + l4*4;
#pragma unroll
        for (int ni = 0; ni < 6; ++ni) {
            int cc = (nth*6 + ni)*16 + l15;
#pragma unroll
            for (int r = 0; r < 4; ++r)
                part16[base + (long)(kkb + r)*192 + cc] = bf1(acc[mi][ni][r]);
        }
    }
}

// ------- K3b: reduce partials -> bf16 kp16[b][h][kk][16] (scaled by 1/sqrt(12)*log2e,
// pads 0), vp16[b][h][16][256] (row 12 = ONES for MFMA row-sum, 13..15 = 0) -------
__global__ __launch_bounds__(256) void k_ered_fin(const ushortT* __restrict__ part16,
        ushortT* __restrict__ kp16, ushortT* __restrict__ vp16) {
    const int idx = blockIdx.x*256 + threadIdx.x;  // 2*2*256*96 = 98304
    const int c  = idx % 96;
    const int kk = (idx / 96) % 256;
    const int m  = (idx / (96*256)) % 2;
    const int b  = idx / (96*256*2);
    float s = 0.f;
    long off = ((long)(b*128)*256 + kk)*192 + m*96 + c;
    for (int jc = 0; jc < 128; ++jc) {
        s += ubf(part16[off]);
        off += 49152;
    }
    const int h = c / DHD, d = c % DHD;
    if (m == 0) {
        // fold softmax scale * log2(e) into k' so QK output feeds exp2 directly
        kp16[((b*NH + h)*256 + kk)*16 + d] = bf1(s * 0.4164701998f);
        if (d < 4) kp16[((b*NH + h)*256 + kk)*16 + 12 + d] = 0;
    } else {
        vp16[((b*NH + h)*16 + d)*256 + kk] = bf1(s);
        if (d < 4)
            vp16[((b*NH + h)*16 + 12 + d)*256 + kk] = (d == 0) ? (ushortT)0x3F80 : (ushortT)0;
    }
}

// ------- K4: barrier-free attention, one head per wave (grid = rows x 2 head-groups).
// kp A-frags in regs; softmax denom via V pad-row of ones (MFMA row-sum);
// exp2 (scale folded into k') + v_cvt_pk_bf16_f32 -------
__global__ __launch_bounds__(256) void k_attn(const ushortT* __restrict__ qkv16,
        const ushortT* __restrict__ kp16, const ushortT* __restrict__ vp16,
        ushortT* __restrict__ obuf) {
    __shared__ ushortT Pl[4][4096];    // 8KB per wave, 32KB total
    const int tid = threadIdx.x;
    const int lane = tid & 63, wv = tid >> 6;
    const int l15 = lane & 15, l4 = lane >> 4;
    const int bid = blockIdx.x;
    const int r0 = (bid >> 1) * 32;
    const int hgrp = bid & 1;
    const int b = r0 >> 14;
    ushortT* Pw = &Pl[wv][0];
    unsigned int* Pu = (unsigned int*)Pw;
    // u32 units: [ks](256) [chunk=(mt&1)*2+(l4>>1)](64) [row=l15](4) [(l4&1)*2 + r/2]
    const int wbase = (l4 >> 1)*64 + l15*4 + (l4 & 1)*2;
    const f32x4 z = {0.f, 0.f, 0.f, 0.f};
    const int h = wv + hgrp*4;
    const ushortT* kpb = kp16 + ((long)(b*NH + h) << 12) + l15*16 + l4*8;
    const ushortT* vb  = vp16 + (((long)(b*NH + h)*16 + l15) << 8) + l4*8;
    short8v a[16];
#pragma unroll
    for (int mt = 0; mt < 16; ++mt)
        a[mt] = *(const short8v*)(kpb + mt*256);
#pragma unroll
    for (int nt = 0; nt < 2; ++nt) {
        short8v bq = {0, 0, 0, 0, 0, 0, 0, 0};
        {
            unsigned int* bq32 = (unsigned int*)&bq;
            const ushortT* qp = qkv16 + (long)(r0 + nt*16 + l15)*288 + h*12;
            if (l4 == 0) {
                uint2 t0 = *reinterpret_cast<const uint2*>(qp);
                uint2 t1 = *reinterpret_cast<const uint2*>(qp + 4);
                bq32[0] = t0.x; bq32[1] = t0.y; bq32[2] = t1.x; bq32[3] = t1.y;
            } else if (l4 == 1) {
                uint2 t0 = *reinterpret_cast<const uint2*>(qp + 8);
                bq32[0] = t0.x; bq32[1] = t0.y;
            }
        }
#pragma unroll
        for (int mt = 0; mt < 16; ++mt) {
            f32x4 s = __builtin_amdgcn_mfma_f32_16x16x32_bf16(a[mt], bq, z, 0, 0, 0);
            unsigned int* dst = Pu + (mt >> 1)*256 + (mt & 1)*128 + wbase;
            dst[0] = cvtpk(exp2f(s[0]), exp2f(s[1]));
            dst[1] = cvtpk(exp2f(s[2]), exp2f(s[3]));
        }
        f32x4 o = z;
#pragma unroll
        for (int ks = 0; ks < 8; ++ks) {
            short8v bp = *(const short8v*)(Pw + ks*512 + l4*128 + l15*8);
            short8v av = *(const short8v*)(vb + ks*32);
            o = __builtin_amdgcn_mfma_f32_16x16x32_bf16(av, bp, o, 0, 0, 0);
        }
        // row-sum sits in output row m=12 (V pad row of ones): lane 48+l15, reg 0
        float rinv = 1.0f / __shfl(o[0], 48 + l15, 64);
        if (l4 < 3) {
            unsigned int* od = (unsigned int*)(obuf + (long)(r0 + nt*16 + l15)*96 + h*12 + l4*4);
            od[0] = cvtpk(o[0]*rinv, o[1]*rinv);
            od[1] = cvtpk(o[2]*rinv, o[3]*rinv);
        }
    }
}

// ------- K5: out = o @ W0 via MFMA (W0^T bf16 frags from global) -------
__global__ __launch_bounds__(256) void k_out(const ushortT* __restrict__ obuf,
        const ushortT* __restrict__ w0T, float* __restrict__ out) {
    __shared__ ushortT ol[64*104];
    const int tid = threadIdx.x;
    const int r0 = blockIdx.x * 64;
    for (int i = tid; i < 768; i += 256) {
        int r = i / 12, sg = i % 12;
        *reinterpret_cast<uint4*>(&ol[r*104 + sg*8]) =
            *reinterpret_cast<const uint4*>(&obuf[(long)(r0 + r)*96 + sg*8]);
    }
    __syncthreads();
    const int lane = tid & 63, wv = tid >> 6;
    const int l15 = lane & 15, l4 = lane >> 4;
    short8v a[3];
#pragma unroll
    for (int kt = 0; kt < 3; ++kt)
        a[kt] = *(const short8v*)((const short*)ol + (wv*16 + l15)*104 + kt*32 + l4*8);
#pragma unroll
    for (int nt = 0; nt < 6; ++nt) {
        f32x4 acc = {0.f, 0.f, 0.f, 0.f};
#pragma unroll
        for (int kt = 0; kt < 3; ++kt) {
            short8v bw = *(const short8v*)((const short*)w0T + (nt*16 + l15)*96 + kt*32 + l4*8);
            acc = __builtin_amdgcn_mfma_f32_16x16x32_bf16(a[kt], bw, acc, 0, 0, 0);
        }
#pragma unroll
        for (int r = 0; r < 4; ++r)
            out[(long)(r0 + wv*16 + l4*4 + r)*96 + nt*16 + l15] = acc[r];
    }
}

extern "C" void kernel_launch(void* const* d_in, const int* in_sizes, int n_in,
                              void* d_out, int out_size, void* d_ws, size_t ws_size,
                              hipStream_t stream) {
    (void)in_sizes; (void)n_in; (void)out_size; (void)ws_size;
    const float* x    = (const float*)d_in[0];
    const float* Wqkv = (const float*)d_in[1];
    const float* W0   = (const float*)d_in[2];
    const float* E    = (const float*)d_in[3];
    const float* c0w  = (const float*)d_in[4];
    const float* c0b  = (const float*)d_in[5];
    const float* cspw = (const float*)d_in[6];
    const float* cspb = (const float*)d_in[7];
    const float* c1w  = (const float*)d_in[8];
    const float* c1b  = (const float*)d_in[9];
    float* out = (float*)d_out;
    float* ws  = (float*)d_ws;

    ushortT* qkv16  = (ushortT*)ws;
    ushortT* wqT16  = (ushortT*)(ws + 4718592);
    ushortT* w0T16  = (ushortT*)(ws + 4732416);
    ushortT* w1c16  = (ushortT*)(ws + 4737024);
    ushortT* ET16   = (ushortT*)(ws + 4741632);
    ushortT* XT16   = (ushortT*)(ws + 6838784);
    float* a1   = ws + 9984512;
    float* a2   = ws + 13130240;
    ushortT* part16 = (ushortT*)(ws + 9984512);
    ushortT* obuf   = (ushortT*)(ws + 9984512);
    ushortT* kp16   = (ushortT*)(ws + 16275968);
    ushortT* vp16   = (ushortT*)(ws + 16308736);

    k_prep<<<dim3(1204), dim3(256), 0, stream>>>(E, Wqkv, W0, c1w, ET16, wqT16, w0T16, w1c16);
    k_qkv<<<dim3(NROW/64), dim3(256), 0, stream>>>(x, wqT16, qkv16);
    k_dw5<<<dim3(NROW/32), dim3(256), 0, stream>>>(x, c0w, c0b, a1);
    k_dw7<<<dim3(NROW/32), dim3(256), 0, stream>>>(a1, cspw, cspb, a2);
    k_pw_gate<<<dim3(NROW/64), dim3(256), 0, stream>>>(a2, w1c16, c1b, x, qkv16, XT16);
    k_ered<<<dim3(256), dim3(512), 0, stream>>>(ET16, XT16, part16);
    k_ered_fin<<<dim3(384), dim3(256), 0, stream>>>(part16, kp16, vp16);
    k_attn<<<dim3(NROW/16), dim3(256), 0, stream>>>(qkv16, kp16, vp16, obuf);
    k_out<<<dim3(NROW/64), dim3(256), 0, stream>>>(obuf, w0T16, out);
}

// Round 12
// 147.295 us; speedup vs baseline: 3.0057x; 1.0051x over previous
//
#include <hip/hip_runtime.h>

#define HH_ 128
#define WW_ 128
#define LL_ (HH_*WW_)     // 16384
#define NH 8
#define DHD 12
#define KD 256
#define BB_ 2
#define NROW (BB_*LL_)    // 32768

typedef __attribute__((ext_vector_type(8))) short short8v;
typedef __attribute__((ext_vector_type(4))) float f32x4;
typedef unsigned short ushortT;

__device__ __forceinline__ float4 ld4(const float* p) {
    return *reinterpret_cast<const float4*>(p);
}
__device__ __forceinline__ unsigned int pk2(float a, float b) {
    unsigned int ua = __float_as_uint(a);
    unsigned int ub = __float_as_uint(b);
    ua = (ua + 0x7FFFu + ((ua >> 16) & 1u)) >> 16;
    ub = (ub + 0x7FFFu + ((ub >> 16) & 1u)) >> 16;
    return ua | (ub << 16);
}
__device__ __forceinline__ ushortT bf1(float a) {
    unsigned int u = __float_as_uint(a);
    return (ushortT)((u + 0x7FFFu + ((u >> 16) & 1u)) >> 16);
}
__device__ __forceinline__ float ubf(ushortT v) {
    return __uint_as_float(((unsigned int)v) << 16);
}
// single-instruction packed f32->bf16 (RNE), gfx950
__device__ __forceinline__ unsigned int cvtpk(float a, float b) {
    unsigned int r;
    asm("v_cvt_pk_bf16_f32 %0, %1, %2" : "=v"(r) : "v"(a), "v"(b));
    return r;
}

// ------- K0: merged prep. blocks <1024: E -> ET16[kk][j] bf16 transposed;
//             blocks >=1024: Wqkv/W0 -> bf16 [n][k], w1 -> bf16 cast -------
__global__ __launch_bounds__(256) void k_prep(const float* __restrict__ E,
        const float* __restrict__ Wq, const float* __restrict__ W0,
        const float* __restrict__ w1, ushortT* __restrict__ ET,
        ushortT* __restrict__ wqT, ushortT* __restrict__ w0T,
        ushortT* __restrict__ w1c) {
    __shared__ ushortT Tz[64*66];
    const int tid = threadIdx.x;
    if (blockIdx.x < 1024) {
        const int jt = blockIdx.x >> 2, kt = blockIdx.x & 3;
        const int j0 = jt * 64, kk0 = kt * 64;
        for (int i = tid; i < 64*16; i += 256) {
            int row = i >> 4, s4 = (i & 15) << 2;
            float4 e4 = ld4(&E[(long)(j0 + row)*256 + kk0 + s4]);
            Tz[(s4 + 0)*66 + row] = bf1(e4.x);
            Tz[(s4 + 1)*66 + row] = bf1(e4.y);
            Tz[(s4 + 2)*66 + row] = bf1(e4.z);
            Tz[(s4 + 3)*66 + row] = bf1(e4.w);
        }
        __syncthreads();
        unsigned int* Tu = (unsigned int*)Tz;
        for (int i = tid; i < 64*32; i += 256) {
            int kk = i >> 5, s = i & 31;
            ((unsigned int*)ET)[(((long)(kk0 + kk) << 14) + j0 >> 1) + s] = Tu[kk*33 + s];
        }
    } else {
        int i = (blockIdx.x - 1024)*256 + tid;
        if (i < 27648) {
            int n = i / 96, k = i % 96;
            wqT[n*96 + k] = bf1(Wq[k*288 + n]);
        } else if (i < 36864) {
            int j = i - 27648;
            int n = j / 96, k = j % 96;
            w0T[n*96 + k] = bf1(W0[k*96 + n]);
        } else if (i < 46080) {
            int j = i - 36864;
            w1c[j] = bf1(w1[j]);
        }
    }
}

// ------- K1: qkv16 = bf16(x @ Wqkv) via MFMA -------
__global__ __launch_bounds__(256) void k_qkv(const float* __restrict__ x,
        const ushortT* __restrict__ wqT, ushortT* __restrict__ qkv16) {
    __shared__ ushortT xb[64*104];
    const int tid = threadIdx.x;
    const int r0w = blockIdx.x * 64;
    for (int i = tid; i < 64*48; i += 256) {
        int r = i / 48, cp = i % 48;
        const float* sp = x + (long)(r0w + r)*96 + cp*2;
        ((unsigned int*)xb)[r*52 + cp] = pk2(sp[0], sp[1]);
    }
    __syncthreads();
    const int lane = tid & 63, wv = tid >> 6;
    const int l15 = lane & 15, l4 = lane >> 4;
    short8v bx[3];
#pragma unroll
    for (int kt = 0; kt < 3; ++kt)
        bx[kt] = *(const short8v*)((const short*)xb + (wv*16 + l15)*104 + kt*32 + l4*8);
#pragma unroll 2
    for (int mt = 0; mt < 18; ++mt) {
        f32x4 acc = {0.f, 0.f, 0.f, 0.f};
#pragma unroll
        for (int kt = 0; kt < 3; ++kt) {
            short8v a = *(const short8v*)((const short*)wqT + (mt*16 + l15)*96 + kt*32 + l4*8);
            acc = __builtin_amdgcn_mfma_f32_16x16x32_bf16(a, bx[kt], acc, 0, 0, 0);
        }
        unsigned int* q32 = (unsigned int*)(qkv16 + (long)(r0w + wv*16 + l15)*288 + mt*16 + l4*4);
        q32[0] = pk2(acc[0], acc[1]);
        q32[1] = pk2(acc[2], acc[3]);
    }
}

// ---------------- K2a: depthwise 5x5, pad 2 (channels-last) ----------------
__global__ __launch_bounds__(256) void k_dw5(const float* __restrict__ xin,
                                             const float* __restrict__ w,
                                             const float* __restrict__ bias,
                                             float* __restrict__ out) {
    __shared__ float wl[25][96];
    const int tid = threadIdx.x;
    for (int i = tid; i < 25*96; i += 256) {
        int c = i / 25, t = i % 25;
        wl[t][c] = w[i];
    }
    __syncthreads();
    const int c4 = (tid & 7)*4;
    const int px = tid >> 3;
    const int pix0 = blockIdx.x * 32;
    const int b = pix0 >> 14;
    const int y = (pix0 & 16383) >> 7;
    const int xx = (pix0 & 127) + px;
    float4 acc[3];
#pragma unroll
    for (int ch = 0; ch < 3; ++ch) { acc[ch].x=0.f; acc[ch].y=0.f; acc[ch].z=0.f; acc[ch].w=0.f; }
#pragma unroll
    for (int iy = 0; iy < 5; ++iy) {
        int y2 = y + iy - 2;
        if (y2 < 0 || y2 >= HH_) continue;
#pragma unroll
        for (int ix = 0; ix < 5; ++ix) {
            int x2 = xx + ix - 2;
            if (x2 < 0 || x2 >= WW_) continue;
            const float* src = xin + ((b << 14) + y2*WW_ + x2)*96;
            const float* wt = &wl[iy*5 + ix][0];
#pragma unroll
            for (int ch = 0; ch < 3; ++ch) {
                float4 xv = ld4(src + ch*32 + c4);
                float4 wv = ld4(wt + ch*32 + c4);
                acc[ch].x = fmaf(xv.x, wv.x, acc[ch].x);
                acc[ch].y = fmaf(xv.y, wv.y, acc[ch].y);
                acc[ch].z = fmaf(xv.z, wv.z, acc[ch].z);
                acc[ch].w = fmaf(xv.w, wv.w, acc[ch].w);
            }
        }
    }
    float* dst = out + (long)(pix0 + px)*96;
#pragma unroll
    for (int ch = 0; ch < 3; ++ch) {
        float4 bv = ld4(bias + ch*32 + c4);
        float4 r;
        r.x = acc[ch].x + bv.x; r.y = acc[ch].y + bv.y;
        r.z = acc[ch].z + bv.z; r.w = acc[ch].w + bv.w;
        *reinterpret_cast<float4*>(dst + ch*32 + c4) = r;
    }
}

// ---------------- K2b: depthwise 7x7, dilation 3, pad 9 ----------------
__global__ __launch_bounds__(256) void k_dw7(const float* __restrict__ xin,
                                             const float* __restrict__ w,
                                             const float* __restrict__ bias,
                                             float* __restrict__ out) {
    __shared__ float wl[49][96];
    const int tid = threadIdx.x;
    for (int i = tid; i < 49*96; i += 256) {
        int c = i / 49, t = i % 49;
        wl[t][c] = w[i];
    }
    __syncthreads();
    const int c4 = (tid & 7)*4;
    const int px = tid >> 3;
    const int pix0 = blockIdx.x * 32;
    const int b = pix0 >> 14;
    const int y = (pix0 & 16383) >> 7;
    const int xx = (pix0 & 127) + px;
    float4 acc[3];
#pragma unroll
    for (int ch = 0; ch < 3; ++ch) { acc[ch].x=0.f; acc[ch].y=0.f; acc[ch].z=0.f; acc[ch].w=0.f; }
#pragma unroll
    for (int iy = 0; iy < 7; ++iy) {
        int y2 = y + iy*3 - 9;
        if (y2 < 0 || y2 >= HH_) continue;
#pragma unroll
        for (int ix = 0; ix < 7; ++ix) {
            int x2 = xx + ix*3 - 9;
            if (x2 < 0 || x2 >= WW_) continue;
            const float* src = xin + ((b << 14) + y2*WW_ + x2)*96;
            const float* wt = &wl[iy*7 + ix][0];
#pragma unroll
            for (int ch = 0; ch < 3; ++ch) {
                float4 xv = ld4(src + ch*32 + c4);
                float4 wv = ld4(wt + ch*32 + c4);
                acc[ch].x = fmaf(xv.x, wv.x, acc[ch].x);
                acc[ch].y = fmaf(xv.y, wv.y, acc[ch].y);
                acc[ch].z = fmaf(xv.z, wv.z, acc[ch].z);
                acc[ch].w = fmaf(xv.w, wv.w, acc[ch].w);
            }
        }
    }
    float* dst = out + (long)(pix0 + px)*96;
#pragma unroll
    for (int ch = 0; ch < 3; ++ch) {
        float4 bv = ld4(bias + ch*32 + c4);
        float4 r;
        r.x = acc[ch].x + bv.x; r.y = acc[ch].y + bv.y;
        r.z = acc[ch].z + bv.z; r.w = acc[ch].w + bv.w;
        *reinterpret_cast<float4*>(dst + ch*32 + c4) = r;
    }
}

// ------- K2c: fused a3 = a2@w1^T + b1 (MFMA); vf = x*a3*v; writes BOTH halves
// of XT[b][cc 192][j] (cc<96 = k transposed, cc>=96 = vf transposed). 64 rows/blk -------
__global__ __launch_bounds__(256) void k_pw_gate(const float* __restrict__ a2,
        const ushortT* __restrict__ w1c, const float* __restrict__ b1,
        const float* __restrict__ xin, const ushortT* __restrict__ qkv16,
        ushortT* __restrict__ XT) {
    __shared__ ushortT ab[64*104];     // 13312B
    __shared__ ushortT ktile[96*66];   // 12672B
    __shared__ ushortT vtile[96*66];   // 12672B
    const int tid = threadIdx.x;
    const int r0 = blockIdx.x * 64;
    const int b = r0 >> 14, j0 = r0 & 16383;
    for (int i = tid; i < 64*48; i += 256) {
        int r = i / 48, cp = i % 48;
        const float* sp = a2 + (long)(r0 + r)*96 + cp*2;
        ((unsigned int*)ab)[r*52 + cp] = pk2(sp[0], sp[1]);
    }
    const unsigned int* q32 = (const unsigned int*)qkv16;
    for (int i = tid; i < 64*48; i += 256) {
        int row = i / 48, cp = i % 48;
        unsigned int kk2 = q32[(long)(r0 + row)*144 + 48 + cp];
        ktile[(2*cp + 0)*66 + row] = (ushortT)(kk2 & 0xFFFF);
        ktile[(2*cp + 1)*66 + row] = (ushortT)(kk2 >> 16);
    }
    __syncthreads();
    const int lane = tid & 63, wv = tid >> 6;
    const int l15 = lane & 15, l4 = lane >> 4;
    const int row = r0 + wv*16 + l15;
    const int jloc = wv*16 + l15;
    short8v bx[3];
#pragma unroll
    for (int kt = 0; kt < 3; ++kt)
        bx[kt] = *(const short8v*)((const short*)ab + (wv*16 + l15)*104 + kt*32 + l4*8);
#pragma unroll
    for (int mt = 0; mt < 6; ++mt) {
        f32x4 acc = {0.f, 0.f, 0.f, 0.f};
#pragma unroll
        for (int kt = 0; kt < 3; ++kt) {
            short8v a = *(const short8v*)((const short*)w1c + (mt*16 + l15)*96 + kt*32 + l4*8);
            acc = __builtin_amdgcn_mfma_f32_16x16x32_bf16(a, bx[kt], acc, 0, 0, 0);
        }
        const int c0 = mt*16 + l4*4;
        float4 b4 = ld4(&b1[c0]);
        float4 x4 = ld4(&xin[(long)row*96 + c0]);
        uint2 vv = *reinterpret_cast<const uint2*>(qkv16 + (long)row*288 + 192 + c0);
        float v0 = ubf((ushortT)(vv.x & 0xFFFF)), v1 = ubf((ushortT)(vv.x >> 16));
        float v2 = ubf((ushortT)(vv.y & 0xFFFF)), v3 = ubf((ushortT)(vv.y >> 16));
        vtile[(c0 + 0)*66 + jloc] = bf1(x4.x * v0 * (acc[0] + b4.x));
        vtile[(c0 + 1)*66 + jloc] = bf1(x4.y * v1 * (acc[1] + b4.y));
        vtile[(c0 + 2)*66 + jloc] = bf1(x4.z * v2 * (acc[2] + b4.z));
        vtile[(c0 + 3)*66 + jloc] = bf1(x4.w * v3 * (acc[3] + b4.w));
    }
    __syncthreads();
    unsigned int* XTu = (unsigned int*)XT;
    unsigned int* ku = (unsigned int*)ktile;
    unsigned int* vu = (unsigned int*)vtile;
    for (int i = tid; i < 96*32; i += 256) {
        int cc = i >> 5, s = i & 31;
        XTu[((((long)b*192 + cc) << 14) + j0 >> 1) + s] = ku[cc*33 + s];
    }
    for (int i = tid; i < 96*32; i += 256) {
        int cc = i >> 5, s = i & 31;
        XTu[((((long)b*192 + 96 + cc) << 14) + j0 >> 1) + s] = vu[cc*33 + s];
    }
}

// ------- K3a: E-reduction as MFMA split-K GEMM (no LDS).
// __launch_bounds__(512, 2): VGPR budget 256 so acc[4][6] (96 VGPR) stays in regs -------
__global__ __launch_bounds__(512, 2) void k_ered(const ushortT* __restrict__ ET,
        const ushortT* __restrict__ XT, ushortT* __restrict__ part16) {
    const int tid = threadIdx.x;
    const int lane = tid & 63, wv = tid >> 6;
    const int l15 = lane & 15, l4 = lane >> 4;
    const int mtg = wv & 3, nth = wv >> 2;
    const int b  = blockIdx.x >> 7;
    const int jc = blockIdx.x & 127;
    const int j0 = jc * 128;
    f32x4 acc[4][6];
#pragma unroll
    for (int mi = 0; mi < 4; ++mi)
#pragma unroll
        for (int ni = 0; ni < 6; ++ni)
            acc[mi][ni] = (f32x4){0.f, 0.f, 0.f, 0.f};
    const ushortT* Ab = ET + ((long)(mtg*64 + l15) << 14) + j0 + l4*8;
    const ushortT* Bb = XT + (((long)b*192 + nth*96 + l15) << 14) + j0 + l4*8;
#pragma unroll
    for (int ks = 0; ks < 4; ++ks) {
        short8v a[4], bx[6];
#pragma unroll
        for (int mi = 0; mi < 4; ++mi)
            a[mi] = *(const short8v*)(Ab + ((long)mi << 18) + ks*32);
#pragma unroll
        for (int ni = 0; ni < 6; ++ni)
            bx[ni] = *(const short8v*)(Bb + ((long)ni << 18) + ks*32);
#pragma unroll
        for (int mi = 0; mi < 4; ++mi)
#pragma unroll
            for (int ni = 0; ni < 6; ++ni)
                acc[mi][ni] = __builtin_amdgcn_mfma_f32_16x16x32_bf16(a[mi], bx[ni], acc[mi][ni], 0, 0, 0);
    }
    const long base = (long)(b*128 + jc)*49152;
#pragma unroll
    for (int mi = 0; mi < 4; ++mi) {
        int kkb = (mtg*4 + mi)*16 + l4*4;
#pragma unroll
        for (int ni = 0; ni < 6; ++ni) {
            int cc = (nth*6 + ni)*16 + l15;
#pragma unroll
            for (int r = 0; r < 4; ++r)
                part16[base + (long)(kkb + r)*192 + cc] = bf1(acc[mi][ni][r]);
        }
    }
}

// ------- K3b: reduce partials -> bf16 kp16[b][h][kk][16] (scaled by 1/sqrt(12)*log2e,
// pads 0), vp16[b][h][16][256] (row 12 = ONES for MFMA row-sum, 13..15 = 0) -------
__global__ __launch_bounds__(256) void k_ered_fin(const ushortT* __restrict__ part16,
        ushortT* __restrict__ kp16, ushortT* __restrict__ vp16) {
    const int idx = blockIdx.x*256 + threadIdx.x;  // 2*2*256*96 = 98304
    const int c  = idx % 96;
    const int kk = (idx / 96) % 256;
    const int m  = (idx / (96*256)) % 2;
    const int b  = idx / (96*256*2);
    float s = 0.f;
    long off = ((long)(b*128)*256 + kk)*192 + m*96 + c;
    for (int jc = 0; jc < 128; ++jc) {
        s += ubf(part16[off]);
        off += 49152;
    }
    const int h = c / DHD, d = c % DHD;
    if (m == 0) {
        // fold softmax scale * log2(e) into k' so QK output feeds exp2 directly
        kp16[((b*NH + h)*256 + kk)*16 + d] = bf1(s * 0.4164701998f);
        if (d < 4) kp16[((b*NH + h)*256 + kk)*16 + 12 + d] = 0;
    } else {
        vp16[((b*NH + h)*16 + d)*256 + kk] = bf1(s);
        if (d < 4)
            vp16[((b*NH + h)*16 + 12 + d)*256 + kk] = (d == 0) ? (ushortT)0x3F80 : (ushortT)0;
    }
}

// ------- K4: barrier-free attention, one head per wave.
// __launch_bounds__(256, 4): VGPR budget 128 so a[16] (64 VGPR) actually stays
// resident -> 16-deep load ILP instead of per-mt L2-latency serialization -------
__global__ __launch_bounds__(256, 4) void k_attn(const ushortT* __restrict__ qkv16,
        const ushortT* __restrict__ kp16, const ushortT* __restrict__ vp16,
        ushortT* __restrict__ obuf) {
    __shared__ ushortT Pl[4][4096];    // 8KB per wave, 32KB total
    const int tid = threadIdx.x;
    const int lane = tid & 63, wv = tid >> 6;
    const int l15 = lane & 15, l4 = lane >> 4;
    const int bid = blockIdx.x;
    const int r0 = (bid >> 1) * 32;
    const int hgrp = bid & 1;
    const int b = r0 >> 14;
    ushortT* Pw = &Pl[wv][0];
    unsigned int* Pu = (unsigned int*)Pw;
    // u32 units: [ks](256) [chunk=(mt&1)*2+(l4>>1)](64) [row=l15](4) [(l4&1)*2 + r/2]
    const int wbase = (l4 >> 1)*64 + l15*4 + (l4 & 1)*2;
    const f32x4 z = {0.f, 0.f, 0.f, 0.f};
    const int h = wv + hgrp*4;
    const ushortT* kpb = kp16 + ((long)(b*NH + h) << 12) + l15*16 + l4*8;
    const ushortT* vb  = vp16 + (((long)(b*NH + h)*16 + l15) << 8) + l4*8;
    short8v a[16];
#pragma unroll
    for (int mt = 0; mt < 16; ++mt)
        a[mt] = *(const short8v*)(kpb + mt*256);
#pragma unroll
    for (int nt = 0; nt < 2; ++nt) {
        short8v bq = {0, 0, 0, 0, 0, 0, 0, 0};
        {
            unsigned int* bq32 = (unsigned int*)&bq;
            const ushortT* qp = qkv16 + (long)(r0 + nt*16 + l15)*288 + h*12;
            if (l4 == 0) {
                uint2 t0 = *reinterpret_cast<const uint2*>(qp);
                uint2 t1 = *reinterpret_cast<const uint2*>(qp + 4);
                bq32[0] = t0.x; bq32[1] = t0.y; bq32[2] = t1.x; bq32[3] = t1.y;
            } else if (l4 == 1) {
                uint2 t0 = *reinterpret_cast<const uint2*>(qp + 8);
                bq32[0] = t0.x; bq32[1] = t0.y;
            }
        }
#pragma unroll
        for (int mt = 0; mt < 16; ++mt) {
            f32x4 s = __builtin_amdgcn_mfma_f32_16x16x32_bf16(a[mt], bq, z, 0, 0, 0);
            unsigned int* dst = Pu + (mt >> 1)*256 + (mt & 1)*128 + wbase;
            dst[0] = cvtpk(exp2f(s[0]), exp2f(s[1]));
            dst[1] = cvtpk(exp2f(s[2]), exp2f(s[3]));
        }
        f32x4 o = z;
#pragma unroll
        for (int ks = 0; ks < 8; ++ks) {
            short8v bp = *(const short8v*)(Pw + ks*512 + l4*128 + l15*8);
            short8v av = *(const short8v*)(vb + ks*32);
            o = __builtin_amdgcn_mfma_f32_16x16x32_bf16(av, bp, o, 0, 0, 0);
        }
        // row-sum sits in output row m=12 (V pad row of ones): lane 48+l15, reg 0
        float rinv = 1.0f / __shfl(o[0], 48 + l15, 64);
        if (l4 < 3) {
            unsigned int* od = (unsigned int*)(obuf + (long)(r0 + nt*16 + l15)*96 + h*12 + l4*4);
            od[0] = cvtpk(o[0]*rinv, o[1]*rinv);
            od[1] = cvtpk(o[2]*rinv, o[3]*rinv);
        }
    }
}

// ------- K5: out = o @ W0 via MFMA (W0^T bf16 frags from global) -------
__global__ __launch_bounds__(256) void k_out(const ushortT* __restrict__ obuf,
        const ushortT* __restrict__ w0T, float* __restrict__ out) {
    __shared__ ushortT ol[64*104];
    const int tid = threadIdx.x;
    const int r0 = blockIdx.x * 64;
    for (int i = tid; i < 768; i += 256) {
        int r = i / 12, sg = i % 12;
        *reinterpret_cast<uint4*>(&ol[r*104 + sg*8]) =
            *reinterpret_cast<const uint4*>(&obuf[(long)(r0 + r)*96 + sg*8]);
    }
    __syncthreads();
    const int lane = tid & 63, wv = tid >> 6;
    const int l15 = lane & 15, l4 = lane >> 4;
    short8v a[3];
#pragma unroll
    for (int kt = 0; kt < 3; ++kt)
        a[kt] = *(const short8v*)((const short*)ol + (wv*16 + l15)*104 + kt*32 + l4*8);
#pragma unroll
    for (int nt = 0; nt < 6; ++nt) {
        f32x4 acc = {0.f, 0.f, 0.f, 0.f};
#pragma unroll
        for (int kt = 0; kt < 3; ++kt) {
            short8v bw = *(const short8v*)((const short*)w0T + (nt*16 + l15)*96 + kt*32 + l4*8);
            acc = __builtin_amdgcn_mfma_f32_16x16x32_bf16(a[kt], bw, acc, 0, 0, 0);
        }
#pragma unroll
        for (int r = 0; r < 4; ++r)
            out[(long)(r0 + wv*16 + l4*4 + r)*96 + nt*16 + l15] = acc[r];
    }
}

extern "C" void kernel_launch(void* const* d_in, const int* in_sizes, int n_in,
                              void* d_out, int out_size, void* d_ws, size_t ws_size,
                              hipStream_t stream) {
    (void)in_sizes; (void)n_in; (void)out_size; (void)ws_size;
    const float* x    = (const float*)d_in[0];
    const float* Wqkv = (const float*)d_in[1];
    const float* W0   = (const float*)d_in[2];
    const float* E    = (const float*)d_in[3];
    const float* c0w  = (const float*)d_in[4];
    const float* c0b  = (const float*)d_in[5];
    const float* cspw = (const float*)d_in[6];
    const float* cspb = (const float*)d_in[7];
    const float* c1w  = (const float*)d_in[8];
    const float* c1b  = (const float*)d_in[9];
    float* out = (float*)d_out;
    float* ws  = (float*)d_ws;

    ushortT* qkv16  = (ushortT*)ws;
    ushortT* wqT16  = (ushortT*)(ws + 4718592);
    ushortT* w0T16  = (ushortT*)(ws + 4732416);
    ushortT* w1c16  = (ushortT*)(ws + 4737024);
    ushortT* ET16   = (ushortT*)(ws + 4741632);
    ushortT* XT16   = (ushortT*)(ws + 6838784);
    float* a1   = ws + 9984512;
    float* a2   = ws + 13130240;
    ushortT* part16 = (ushortT*)(ws + 9984512);
    ushortT* obuf   = (ushortT*)(ws + 9984512);
    ushortT* kp16   = (ushortT*)(ws + 16275968);
    ushortT* vp16   = (ushortT*)(ws + 16308736);

    k_prep<<<dim3(1204), dim3(256), 0, stream>>>(E, Wqkv, W0, c1w, ET16, wqT16, w0T16, w1c16);
    k_qkv<<<dim3(NROW/64), dim3(256), 0, stream>>>(x, wqT16, qkv16);
    k_dw5<<<dim3(NROW/32), dim3(256), 0, stream>>>(x, c0w, c0b, a1);
    k_dw7<<<dim3(NROW/32), dim3(256), 0, stream>>>(a1, cspw, cspb, a2);
    k_pw_gate<<<dim3(NROW/64), dim3(256), 0, stream>>>(a2, w1c16, c1b, x, qkv16, XT16);
    k_ered<<<dim3(256), dim3(512), 0, stream>>>(ET16, XT16, part16);
    k_ered_fin<<<dim3(384), dim3(256), 0, stream>>>(part16, kp16, vp16);
    k_attn<<<dim3(NROW/16), dim3(256), 0, stream>>>(qkv16, kp16, vp16, obuf);
    k_out<<<dim3(NROW/64), dim3(256), 0, stream>>>(obuf, w0T16, out);
}

// Round 13
// 145.581 us; speedup vs baseline: 3.0411x; 1.0118x over previous
//
#include <hip/hip_runtime.h>

#define HH_ 128
#define WW_ 128
#define LL_ (HH_*WW_)     // 16384
#define NH 8
#define DHD 12
#define KD 256
#define BB_ 2
#define NROW (BB_*LL_)    // 32768

typedef __attribute__((ext_vector_type(8))) short short8v;
typedef __attribute__((ext_vector_type(4))) float f32x4;
typedef unsigned short ushortT;

__device__ __forceinline__ float4 ld4(const float* p) {
    return *reinterpret_cast<const float4*>(p);
}
__device__ __forceinline__ unsigned int pk2(float a, float b) {
    unsigned int ua = __float_as_uint(a);
    unsigned int ub = __float_as_uint(b);
    ua = (ua + 0x7FFFu + ((ua >> 16) & 1u)) >> 16;
    ub = (ub + 0x7FFFu + ((ub >> 16) & 1u)) >> 16;
    return ua | (ub << 16);
}
__device__ __forceinline__ ushortT bf1(float a) {
    unsigned int u = __float_as_uint(a);
    return (ushortT)((u + 0x7FFFu + ((u >> 16) & 1u)) >> 16);
}
__device__ __forceinline__ float ubf(ushortT v) {
    return __uint_as_float(((unsigned int)v) << 16);
}
// single-instruction packed f32->bf16 (RNE), gfx950
__device__ __forceinline__ unsigned int cvtpk(float a, float b) {
    unsigned int r;
    asm("v_cvt_pk_bf16_f32 %0, %1, %2" : "=v"(r) : "v"(a), "v"(b));
    return r;
}

// ------- K0: merged prep. blocks <1024: E -> ET16[kk][j] bf16 transposed;
//             blocks >=1024: Wqkv/W0 -> bf16 [n][k], w1 -> bf16 cast -------
__global__ __launch_bounds__(256) void k_prep(const float* __restrict__ E,
        const float* __restrict__ Wq, const float* __restrict__ W0,
        const float* __restrict__ w1, ushortT* __restrict__ ET,
        ushortT* __restrict__ wqT, ushortT* __restrict__ w0T,
        ushortT* __restrict__ w1c) {
    __shared__ ushortT Tz[64*66];
    const int tid = threadIdx.x;
    if (blockIdx.x < 1024) {
        const int jt = blockIdx.x >> 2, kt = blockIdx.x & 3;
        const int j0 = jt * 64, kk0 = kt * 64;
        for (int i = tid; i < 64*16; i += 256) {
            int row = i >> 4, s4 = (i & 15) << 2;
            float4 e4 = ld4(&E[(long)(j0 + row)*256 + kk0 + s4]);
            Tz[(s4 + 0)*66 + row] = bf1(e4.x);
            Tz[(s4 + 1)*66 + row] = bf1(e4.y);
            Tz[(s4 + 2)*66 + row] = bf1(e4.z);
            Tz[(s4 + 3)*66 + row] = bf1(e4.w);
        }
        __syncthreads();
        unsigned int* Tu = (unsigned int*)Tz;
        for (int i = tid; i < 64*32; i += 256) {
            int kk = i >> 5, s = i & 31;
            ((unsigned int*)ET)[(((long)(kk0 + kk) << 14) + j0 >> 1) + s] = Tu[kk*33 + s];
        }
    } else {
        int i = (blockIdx.x - 1024)*256 + tid;
        if (i < 27648) {
            int n = i / 96, k = i % 96;
            wqT[n*96 + k] = bf1(Wq[k*288 + n]);
        } else if (i < 36864) {
            int j = i - 27648;
            int n = j / 96, k = j % 96;
            w0T[n*96 + k] = bf1(W0[k*96 + n]);
        } else if (i < 46080) {
            int j = i - 36864;
            w1c[j] = bf1(w1[j]);
        }
    }
}

// ------- K1: qkv16 = bf16(x @ Wqkv) via MFMA -------
__global__ __launch_bounds__(256) void k_qkv(const float* __restrict__ x,
        const ushortT* __restrict__ wqT, ushortT* __restrict__ qkv16) {
    __shared__ ushortT xb[64*104];
    const int tid = threadIdx.x;
    const int r0w = blockIdx.x * 64;
    for (int i = tid; i < 64*48; i += 256) {
        int r = i / 48, cp = i % 48;
        const float* sp = x + (long)(r0w + r)*96 + cp*2;
        ((unsigned int*)xb)[r*52 + cp] = pk2(sp[0], sp[1]);
    }
    __syncthreads();
    const int lane = tid & 63, wv = tid >> 6;
    const int l15 = lane & 15, l4 = lane >> 4;
    short8v bx[3];
#pragma unroll
    for (int kt = 0; kt < 3; ++kt)
        bx[kt] = *(const short8v*)((const short*)xb + (wv*16 + l15)*104 + kt*32 + l4*8);
#pragma unroll 2
    for (int mt = 0; mt < 18; ++mt) {
        f32x4 acc = {0.f, 0.f, 0.f, 0.f};
#pragma unroll
        for (int kt = 0; kt < 3; ++kt) {
            short8v a = *(const short8v*)((const short*)wqT + (mt*16 + l15)*96 + kt*32 + l4*8);
            acc = __builtin_amdgcn_mfma_f32_16x16x32_bf16(a, bx[kt], acc, 0, 0, 0);
        }
        unsigned int* q32 = (unsigned int*)(qkv16 + (long)(r0w + wv*16 + l15)*288 + mt*16 + l4*4);
        q32[0] = pk2(acc[0], acc[1]);
        q32[1] = pk2(acc[2], acc[3]);
    }
}

// ---------------- K2a: depthwise 5x5, pad 2 (channels-last) ----------------
__global__ __launch_bounds__(256) void k_dw5(const float* __restrict__ xin,
                                             const float* __restrict__ w,
                                             const float* __restrict__ bias,
                                             float* __restrict__ out) {
    __shared__ float wl[25][96];
    const int tid = threadIdx.x;
    for (int i = tid; i < 25*96; i += 256) {
        int c = i / 25, t = i % 25;
        wl[t][c] = w[i];
    }
    __syncthreads();
    const int c4 = (tid & 7)*4;
    const int px = tid >> 3;
    const int pix0 = blockIdx.x * 32;
    const int b = pix0 >> 14;
    const int y = (pix0 & 16383) >> 7;
    const int xx = (pix0 & 127) + px;
    float4 acc[3];
#pragma unroll
    for (int ch = 0; ch < 3; ++ch) { acc[ch].x=0.f; acc[ch].y=0.f; acc[ch].z=0.f; acc[ch].w=0.f; }
#pragma unroll
    for (int iy = 0; iy < 5; ++iy) {
        int y2 = y + iy - 2;
        if (y2 < 0 || y2 >= HH_) continue;
#pragma unroll
        for (int ix = 0; ix < 5; ++ix) {
            int x2 = xx + ix - 2;
            if (x2 < 0 || x2 >= WW_) continue;
            const float* src = xin + ((b << 14) + y2*WW_ + x2)*96;
            const float* wt = &wl[iy*5 + ix][0];
#pragma unroll
            for (int ch = 0; ch < 3; ++ch) {
                float4 xv = ld4(src + ch*32 + c4);
                float4 wv = ld4(wt + ch*32 + c4);
                acc[ch].x = fmaf(xv.x, wv.x, acc[ch].x);
                acc[ch].y = fmaf(xv.y, wv.y, acc[ch].y);
                acc[ch].z = fmaf(xv.z, wv.z, acc[ch].z);
                acc[ch].w = fmaf(xv.w, wv.w, acc[ch].w);
            }
        }
    }
    float* dst = out + (long)(pix0 + px)*96;
#pragma unroll
    for (int ch = 0; ch < 3; ++ch) {
        float4 bv = ld4(bias + ch*32 + c4);
        float4 r;
        r.x = acc[ch].x + bv.x; r.y = acc[ch].y + bv.y;
        r.z = acc[ch].z + bv.z; r.w = acc[ch].w + bv.w;
        *reinterpret_cast<float4*>(dst + ch*32 + c4) = r;
    }
}

// ---------------- K2b: depthwise 7x7, dilation 3, pad 9 ----------------
__global__ __launch_bounds__(256) void k_dw7(const float* __restrict__ xin,
                                             const float* __restrict__ w,
                                             const float* __restrict__ bias,
                                             float* __restrict__ out) {
    __shared__ float wl[49][96];
    const int tid = threadIdx.x;
    for (int i = tid; i < 49*96; i += 256) {
        int c = i / 49, t = i % 49;
        wl[t][c] = w[i];
    }
    __syncthreads();
    const int c4 = (tid & 7)*4;
    const int px = tid >> 3;
    const int pix0 = blockIdx.x * 32;
    const int b = pix0 >> 14;
    const int y = (pix0 & 16383) >> 7;
    const int xx = (pix0 & 127) + px;
    float4 acc[3];
#pragma unroll
    for (int ch = 0; ch < 3; ++ch) { acc[ch].x=0.f; acc[ch].y=0.f; acc[ch].z=0.f; acc[ch].w=0.f; }
#pragma unroll
    for (int iy = 0; iy < 7; ++iy) {
        int y2 = y + iy*3 - 9;
        if (y2 < 0 || y2 >= HH_) continue;
#pragma unroll
        for (int ix = 0; ix < 7; ++ix) {
            int x2 = xx + ix*3 - 9;
            if (x2 < 0 || x2 >= WW_) continue;
            const float* src = xin + ((b << 14) + y2*WW_ + x2)*96;
            const float* wt = &wl[iy*7 + ix][0];
#pragma unroll
            for (int ch = 0; ch < 3; ++ch) {
                float4 xv = ld4(src + ch*32 + c4);
                float4 wv = ld4(wt + ch*32 + c4);
                acc[ch].x = fmaf(xv.x, wv.x, acc[ch].x);
                acc[ch].y = fmaf(xv.y, wv.y, acc[ch].y);
                acc[ch].z = fmaf(xv.z, wv.z, acc[ch].z);
                acc[ch].w = fmaf(xv.w, wv.w, acc[ch].w);
            }
        }
    }
    float* dst = out + (long)(pix0 + px)*96;
#pragma unroll
    for (int ch = 0; ch < 3; ++ch) {
        float4 bv = ld4(bias + ch*32 + c4);
        float4 r;
        r.x = acc[ch].x + bv.x; r.y = acc[ch].y + bv.y;
        r.z = acc[ch].z + bv.z; r.w = acc[ch].w + bv.w;
        *reinterpret_cast<float4*>(dst + ch*32 + c4) = r;
    }
}

// ------- K2c: fused a3 = a2@w1^T + b1 (MFMA); vf = x*a3*v; writes BOTH halves
// of XT[b][cc 192][j] (cc<96 = k transposed, cc>=96 = vf transposed). 64 rows/blk -------
__global__ __launch_bounds__(256) void k_pw_gate(const float* __restrict__ a2,
        const ushortT* __restrict__ w1c, const float* __restrict__ b1,
        const float* __restrict__ xin, const ushortT* __restrict__ qkv16,
        ushortT* __restrict__ XT) {
    __shared__ ushortT ab[64*104];     // 13312B
    __shared__ ushortT ktile[96*66];   // 12672B
    __shared__ ushortT vtile[96*66];   // 12672B
    const int tid = threadIdx.x;
    const int r0 = blockIdx.x * 64;
    const int b = r0 >> 14, j0 = r0 & 16383;
    for (int i = tid; i < 64*48; i += 256) {
        int r = i / 48, cp = i % 48;
        const float* sp = a2 + (long)(r0 + r)*96 + cp*2;
        ((unsigned int*)ab)[r*52 + cp] = pk2(sp[0], sp[1]);
    }
    const unsigned int* q32 = (const unsigned int*)qkv16;
    for (int i = tid; i < 64*48; i += 256) {
        int row = i / 48, cp = i % 48;
        unsigned int kk2 = q32[(long)(r0 + row)*144 + 48 + cp];
        ktile[(2*cp + 0)*66 + row] = (ushortT)(kk2 & 0xFFFF);
        ktile[(2*cp + 1)*66 + row] = (ushortT)(kk2 >> 16);
    }
    __syncthreads();
    const int lane = tid & 63, wv = tid >> 6;
    const int l15 = lane & 15, l4 = lane >> 4;
    const int row = r0 + wv*16 + l15;
    const int jloc = wv*16 + l15;
    short8v bx[3];
#pragma unroll
    for (int kt = 0; kt < 3; ++kt)
        bx[kt] = *(const short8v*)((const short*)ab + (wv*16 + l15)*104 + kt*32 + l4*8);
#pragma unroll
    for (int mt = 0; mt < 6; ++mt) {
        f32x4 acc = {0.f, 0.f, 0.f, 0.f};
#pragma unroll
        for (int kt = 0; kt < 3; ++kt) {
            short8v a = *(const short8v*)((const short*)w1c + (mt*16 + l15)*96 + kt*32 + l4*8);
            acc = __builtin_amdgcn_mfma_f32_16x16x32_bf16(a, bx[kt], acc, 0, 0, 0);
        }
        const int c0 = mt*16 + l4*4;
        float4 b4 = ld4(&b1[c0]);
        float4 x4 = ld4(&xin[(long)row*96 + c0]);
        uint2 vv = *reinterpret_cast<const uint2*>(qkv16 + (long)row*288 + 192 + c0);
        float v0 = ubf((ushortT)(vv.x & 0xFFFF)), v1 = ubf((ushortT)(vv.x >> 16));
        float v2 = ubf((ushortT)(vv.y & 0xFFFF)), v3 = ubf((ushortT)(vv.y >> 16));
        vtile[(c0 + 0)*66 + jloc] = bf1(x4.x * v0 * (acc[0] + b4.x));
        vtile[(c0 + 1)*66 + jloc] = bf1(x4.y * v1 * (acc[1] + b4.y));
        vtile[(c0 + 2)*66 + jloc] = bf1(x4.z * v2 * (acc[2] + b4.z));
        vtile[(c0 + 3)*66 + jloc] = bf1(x4.w * v3 * (acc[3] + b4.w));
    }
    __syncthreads();
    unsigned int* XTu = (unsigned int*)XT;
    unsigned int* ku = (unsigned int*)ktile;
    unsigned int* vu = (unsigned int*)vtile;
    for (int i = tid; i < 96*32; i += 256) {
        int cc = i >> 5, s = i & 31;
        XTu[((((long)b*192 + cc) << 14) + j0 >> 1) + s] = ku[cc*33 + s];
    }
    for (int i = tid; i < 96*32; i += 256) {
        int cc = i >> 5, s = i & 31;
        XTu[((((long)b*192 + 96 + cc) << 14) + j0 >> 1) + s] = vu[cc*33 + s];
    }
}

// ------- K3a: E-reduction as MFMA split-K GEMM (no LDS) -------
__global__ __launch_bounds__(512, 2) void k_ered(const ushortT* __restrict__ ET,
        const ushortT* __restrict__ XT, ushortT* __restrict__ part16) {
    const int tid = threadIdx.x;
    const int lane = tid & 63, wv = tid >> 6;
    const int l15 = lane & 15, l4 = lane >> 4;
    const int mtg = wv & 3, nth = wv >> 2;
    const int b  = blockIdx.x >> 7;
    const int jc = blockIdx.x & 127;
    const int j0 = jc * 128;
    f32x4 acc[4][6];
#pragma unroll
    for (int mi = 0; mi < 4; ++mi)
#pragma unroll
        for (int ni = 0; ni < 6; ++ni)
            acc[mi][ni] = (f32x4){0.f, 0.f, 0.f, 0.f};
    const ushortT* Ab = ET + ((long)(mtg*64 + l15) << 14) + j0 + l4*8;
    const ushortT* Bb = XT + (((long)b*192 + nth*96 + l15) << 14) + j0 + l4*8;
#pragma unroll
    for (int ks = 0; ks < 4; ++ks) {
        short8v a[4], bx[6];
#pragma unroll
        for (int mi = 0; mi < 4; ++mi)
            a[mi] = *(const short8v*)(Ab + ((long)mi << 18) + ks*32);
#pragma unroll
        for (int ni = 0; ni < 6; ++ni)
            bx[ni] = *(const short8v*)(Bb + ((long)ni << 18) + ks*32);
#pragma unroll
        for (int mi = 0; mi < 4; ++mi)
#pragma unroll
            for (int ni = 0; ni < 6; ++ni)
                acc[mi][ni] = __builtin_amdgcn_mfma_f32_16x16x32_bf16(a[mi], bx[ni], acc[mi][ni], 0, 0, 0);
    }
    const long base = (long)(b*128 + jc)*49152;
#pragma unroll
    for (int mi = 0; mi < 4; ++mi) {
        int kkb = (mtg*4 + mi)*16 + l4*4;
#pragma unroll
        for (int ni = 0; ni < 6; ++ni) {
            int cc = (nth*6 + ni)*16 + l15;
#pragma unroll
            for (int r = 0; r < 4; ++r)
                part16[base + (long)(kkb + r)*192 + cc] = bf1(acc[mi][ni][r]);
        }
    }
}

// ------- K3b: reduce partials -> bf16 kp16[b][h][kk][16] (scaled by 1/sqrt(12)*log2e,
// pads 0), vp16[b][h][16][256] (row 12 = ONES for MFMA row-sum, 13..15 = 0) -------
__global__ __launch_bounds__(256) void k_ered_fin(const ushortT* __restrict__ part16,
        ushortT* __restrict__ kp16, ushortT* __restrict__ vp16) {
    const int idx = blockIdx.x*256 + threadIdx.x;  // 2*2*256*96 = 98304
    const int c  = idx % 96;
    const int kk = (idx / 96) % 256;
    const int m  = (idx / (96*256)) % 2;
    const int b  = idx / (96*256*2);
    float s = 0.f;
    long off = ((long)(b*128)*256 + kk)*192 + m*96 + c;
    for (int jc = 0; jc < 128; ++jc) {
        s += ubf(part16[off]);
        off += 49152;
    }
    const int h = c / DHD, d = c % DHD;
    if (m == 0) {
        // fold softmax scale * log2(e) into k' so QK output feeds exp2 directly
        kp16[((b*NH + h)*256 + kk)*16 + d] = bf1(s * 0.4164701998f);
        if (d < 4) kp16[((b*NH + h)*256 + kk)*16 + 12 + d] = 0;
    } else {
        vp16[((b*NH + h)*16 + d)*256 + kk] = bf1(s);
        if (d < 4)
            vp16[((b*NH + h)*16 + 12 + d)*256 + kk] = (d == 0) ? (ushortT)0x3F80 : (ushortT)0;
    }
}

// ------- K4 v3: flash-style. Block = 64 rows x ONE head; kp/vp staged in LDS
// cooperatively (1 barrier); all operand reads become LDS-class latency.
// LDS (ushorts): kp[256][16] @0 (4096) | zero-pad @4096 (16) |
//                vp[16][264] @4112 (4224, row-padded vs bank conflicts) |
//                P 4 waves x 4096 @8336. Total 24720 ush = 49440 B -> 3 blk/CU -------
__global__ __launch_bounds__(256, 4) void k_attn(const ushortT* __restrict__ qkv16,
        const ushortT* __restrict__ kp16, const ushortT* __restrict__ vp16,
        ushortT* __restrict__ obuf) {
    __shared__ ushortT lds[24720];
    const int tid = threadIdx.x;
    const int lane = tid & 63, wv = tid >> 6;
    const int l15 = lane & 15, l4 = lane >> 4;
    const int bid = blockIdx.x;
    const int r0 = (bid >> 3) * 64;
    const int h = bid & 7;
    const int b = r0 >> 14;
    // ---- stage kp (512 uint4) + vp (512 uint4, stride 33) + zero pad ----
    {
        const uint4* ksrc = (const uint4*)(kp16 + ((long)(b*NH + h) << 12));
        uint4* kdst = (uint4*)lds;
        kdst[tid] = ksrc[tid];
        kdst[256 + tid] = ksrc[256 + tid];
        const uint4* vsrc = (const uint4*)(vp16 + ((long)(b*NH + h) << 12));
        uint4* vdst = (uint4*)(lds + 4112);
        int r1 = tid >> 5, s1 = tid & 31;
        vdst[r1*33 + s1] = vsrc[tid];
        int j2 = tid + 256;
        int r2 = j2 >> 5, s2 = j2 & 31;
        vdst[r2*33 + s2] = vsrc[j2];
        if (tid < 2) ((uint4*)(lds + 4096))[tid] = (uint4){0u, 0u, 0u, 0u};
    }
    __syncthreads();
    ushortT* Pw = lds + 8336 + wv*4096;
    unsigned int* Pu = (unsigned int*)Pw;
    // u32 units: [ks](256) [chunk=(mt&1)*2+(l4>>1)](64) [row=l15](4) [(l4&1)*2 + r/2]
    const int wbase = (l4 >> 1)*64 + l15*4 + (l4 & 1)*2;
    const f32x4 z = {0.f, 0.f, 0.f, 0.f};
    const int row0 = r0 + wv*16;
    // ---- q B-frag (only global load per wave) ----
    short8v bq = {0, 0, 0, 0, 0, 0, 0, 0};
    {
        unsigned int* bq32 = (unsigned int*)&bq;
        const ushortT* qp = qkv16 + (long)(row0 + l15)*288 + h*12;
        if (l4 == 0) {
            uint2 t0 = *reinterpret_cast<const uint2*>(qp);
            uint2 t1 = *reinterpret_cast<const uint2*>(qp + 4);
            bq32[0] = t0.x; bq32[1] = t0.y; bq32[2] = t1.x; bq32[3] = t1.y;
        } else if (l4 == 1) {
            uint2 t0 = *reinterpret_cast<const uint2*>(qp + 8);
            bq32[0] = t0.x; bq32[1] = t0.y;
        }
    }
    // ---- QK from LDS A-frags; exp2; pack P ----
    const ushortT* kpl = lds + l15*16 + l4*8;
#pragma unroll
    for (int mt = 0; mt < 16; ++mt) {
        short8v a = *(const short8v*)(kpl + mt*256);
        f32x4 s = __builtin_amdgcn_mfma_f32_16x16x32_bf16(a, bq, z, 0, 0, 0);
        unsigned int* dst = Pu + (mt >> 1)*256 + (mt & 1)*128 + wbase;
        dst[0] = cvtpk(exp2f(s[0]), exp2f(s[1]));
        dst[1] = cvtpk(exp2f(s[2]), exp2f(s[3]));
    }
    // ---- PV from LDS (vp padded stride 264) ----
    f32x4 o = z;
    const ushortT* vpl = lds + 4112 + l15*264 + l4*8;
#pragma unroll
    for (int ks = 0; ks < 8; ++ks) {
        short8v bp = *(const short8v*)(Pw + ks*512 + l4*128 + l15*8);
        short8v av = *(const short8v*)(vpl + ks*32);
        o = __builtin_amdgcn_mfma_f32_16x16x32_bf16(av, bp, o, 0, 0, 0);
    }
    // row-sum sits in output row m=12 (V pad row of ones): lane 48+l15, reg 0
    float rinv = 1.0f / __shfl(o[0], 48 + l15, 64);
    if (l4 < 3) {
        unsigned int* od = (unsigned int*)(obuf + (long)(row0 + l15)*96 + h*12 + l4*4);
        od[0] = cvtpk(o[0]*rinv, o[1]*rinv);
        od[1] = cvtpk(o[2]*rinv, o[3]*rinv);
    }
}

// ------- K5: out = o @ W0 via MFMA (W0^T bf16 frags from global) -------
__global__ __launch_bounds__(256) void k_out(const ushortT* __restrict__ obuf,
        const ushortT* __restrict__ w0T, float* __restrict__ out) {
    __shared__ ushortT ol[64*104];
    const int tid = threadIdx.x;
    const int r0 = blockIdx.x * 64;
    for (int i = tid; i < 768; i += 256) {
        int r = i / 12, sg = i % 12;
        *reinterpret_cast<uint4*>(&ol[r*104 + sg*8]) =
            *reinterpret_cast<const uint4*>(&obuf[(long)(r0 + r)*96 + sg*8]);
    }
    __syncthreads();
    const int lane = tid & 63, wv = tid >> 6;
    const int l15 = lane & 15, l4 = lane >> 4;
    short8v a[3];
#pragma unroll
    for (int kt = 0; kt < 3; ++kt)
        a[kt] = *(const short8v*)((const short*)ol + (wv*16 + l15)*104 + kt*32 + l4*8);
#pragma unroll
    for (int nt = 0; nt < 6; ++nt) {
        f32x4 acc = {0.f, 0.f, 0.f, 0.f};
#pragma unroll
        for (int kt = 0; kt < 3; ++kt) {
            short8v bw = *(const short8v*)((const short*)w0T + (nt*16 + l15)*96 + kt*32 + l4*8);
            acc = __builtin_amdgcn_mfma_f32_16x16x32_bf16(a[kt], bw, acc, 0, 0, 0);
        }
#pragma unroll
        for (int r = 0; r < 4; ++r)
            out[(long)(r0 + wv*16 + l4*4 + r)*96 + nt*16 + l15] = acc[r];
    }
}

extern "C" void kernel_launch(void* const* d_in, const int* in_sizes, int n_in,
                              void* d_out, int out_size, void* d_ws, size_t ws_size,
                              hipStream_t stream) {
    (void)in_sizes; (void)n_in; (void)out_size; (void)ws_size;
    const float* x    = (const float*)d_in[0];
    const float* Wqkv = (const float*)d_in[1];
    const float* W0   = (const float*)d_in[2];
    const float* E    = (const float*)d_in[3];
    const float* c0w  = (const float*)d_in[4];
    const float* c0b  = (const float*)d_in[5];
    const float* cspw = (const float*)d_in[6];
    const float* cspb = (const float*)d_in[7];
    const float* c1w  = (const float*)d_in[8];
    const float* c1b  = (const float*)d_in[9];
    float* out = (float*)d_out;
    float* ws  = (float*)d_ws;

    ushortT* qkv16  = (ushortT*)ws;
    ushortT* wqT16  = (ushortT*)(ws + 4718592);
    ushortT* w0T16  = (ushortT*)(ws + 4732416);
    ushortT* w1c16  = (ushortT*)(ws + 4737024);
    ushortT* ET16   = (ushortT*)(ws + 4741632);
    ushortT* XT16   = (ushortT*)(ws + 6838784);
    float* a1   = ws + 9984512;
    float* a2   = ws + 13130240;
    ushortT* part16 = (ushortT*)(ws + 9984512);
    ushortT* obuf   = (ushortT*)(ws + 9984512);
    ushortT* kp16   = (ushortT*)(ws + 16275968);
    ushortT* vp16   = (ushortT*)(ws + 16308736);

    k_prep<<<dim3(1204), dim3(256), 0, stream>>>(E, Wqkv, W0, c1w, ET16, wqT16, w0T16, w1c16);
    k_qkv<<<dim3(NROW/64), dim3(256), 0, stream>>>(x, wqT16, qkv16);
    k_dw5<<<dim3(NROW/32), dim3(256), 0, stream>>>(x, c0w, c0b, a1);
    k_dw7<<<dim3(NROW/32), dim3(256), 0, stream>>>(a1, cspw, cspb, a2);
    k_pw_gate<<<dim3(NROW/64), dim3(256), 0, stream>>>(a2, w1c16, c1b, x, qkv16, XT16);
    k_ered<<<dim3(256), dim3(512), 0, stream>>>(ET16, XT16, part16);
    k_ered_fin<<<dim3(384), dim3(256), 0, stream>>>(part16, kp16, vp16);
    k_attn<<<dim3((NROW/64)*NH), dim3(256), 0, stream>>>(qkv16, kp16, vp16, obuf);
    k_out<<<dim3(NROW/64), dim3(256), 0, stream>>>(obuf, w0T16, out);
}

// Round 14
// 132.151 us; speedup vs baseline: 3.3502x; 1.1016x over previous
//
#include <hip/hip_runtime.h>

#define HH_ 128
#define WW_ 128
#define LL_ (HH_*WW_)     // 16384
#define NH 8
#define DHD 12
#define KD 256
#define BB_ 2
#define NROW (BB_*LL_)    // 32768

typedef __attribute__((ext_vector_type(8))) short short8v;
typedef __attribute__((ext_vector_type(4))) float f32x4;
typedef unsigned short ushortT;

__device__ __forceinline__ float4 ld4(const float* p) {
    return *reinterpret_cast<const float4*>(p);
}
__device__ __forceinline__ unsigned int pk2(float a, float b) {
    unsigned int ua = __float_as_uint(a);
    unsigned int ub = __float_as_uint(b);
    ua = (ua + 0x7FFFu + ((ua >> 16) & 1u)) >> 16;
    ub = (ub + 0x7FFFu + ((ub >> 16) & 1u)) >> 16;
    return ua | (ub << 16);
}
__device__ __forceinline__ ushortT bf1(float a) {
    unsigned int u = __float_as_uint(a);
    return (ushortT)((u + 0x7FFFu + ((u >> 16) & 1u)) >> 16);
}
__device__ __forceinline__ float ubf(ushortT v) {
    return __uint_as_float(((unsigned int)v) << 16);
}
// single-instruction packed f32->bf16 (RNE), gfx950
__device__ __forceinline__ unsigned int cvtpk(float a, float b) {
    unsigned int r;
    asm("v_cvt_pk_bf16_f32 %0, %1, %2" : "=v"(r) : "v"(a), "v"(b));
    return r;
}

// ======= K_FRONT: blocks [0,1024) = dw5 (fp32 a1); [1024,2048) = E->ET16;
//                  [2048,2228) = weight prep (wqT/w0T/w1c bf16) =======
__global__ __launch_bounds__(256) void k_front(const float* __restrict__ x,
        const float* __restrict__ c0w, const float* __restrict__ c0b,
        const float* __restrict__ E, const float* __restrict__ Wq,
        const float* __restrict__ W0, const float* __restrict__ w1,
        float* __restrict__ a1, ushortT* __restrict__ ET,
        ushortT* __restrict__ wqT, ushortT* __restrict__ w0T,
        ushortT* __restrict__ w1c) {
    __shared__ __align__(16) float shf[2400];   // 9600B union
    const int tid = threadIdx.x;
    if (blockIdx.x < 1024) {
        // ---- dw5: depthwise 5x5, pad 2, channels-last, fp32 out ----
        float* wl = shf;   // [25][96]
        for (int i = tid; i < 25*96; i += 256) {
            int c = i / 25, t = i % 25;
            wl[t*96 + c] = c0w[i];
        }
        __syncthreads();
        const int c4 = (tid & 7)*4;
        const int px = tid >> 3;
        const int pix0 = blockIdx.x * 32;
        const int b = pix0 >> 14;
        const int y = (pix0 & 16383) >> 7;
        const int xx = (pix0 & 127) + px;
        float4 acc[3];
#pragma unroll
        for (int ch = 0; ch < 3; ++ch) { acc[ch].x=0.f; acc[ch].y=0.f; acc[ch].z=0.f; acc[ch].w=0.f; }
#pragma unroll
        for (int iy = 0; iy < 5; ++iy) {
            int y2 = y + iy - 2;
            if (y2 < 0 || y2 >= HH_) continue;
#pragma unroll
            for (int ix = 0; ix < 5; ++ix) {
                int x2 = xx + ix - 2;
                if (x2 < 0 || x2 >= WW_) continue;
                const float* src = x + ((b << 14) + y2*WW_ + x2)*96;
                const float* wt = &wl[(iy*5 + ix)*96];
#pragma unroll
                for (int ch = 0; ch < 3; ++ch) {
                    float4 xv = ld4(src + ch*32 + c4);
                    float4 wv = ld4(wt + ch*32 + c4);
                    acc[ch].x = fmaf(xv.x, wv.x, acc[ch].x);
                    acc[ch].y = fmaf(xv.y, wv.y, acc[ch].y);
                    acc[ch].z = fmaf(xv.z, wv.z, acc[ch].z);
                    acc[ch].w = fmaf(xv.w, wv.w, acc[ch].w);
                }
            }
        }
        float* dst = a1 + (long)(pix0 + px)*96;
#pragma unroll
        for (int ch = 0; ch < 3; ++ch) {
            float4 bv = ld4(c0b + ch*32 + c4);
            float4 r;
            r.x = acc[ch].x + bv.x; r.y = acc[ch].y + bv.y;
            r.z = acc[ch].z + bv.z; r.w = acc[ch].w + bv.w;
            *reinterpret_cast<float4*>(dst + ch*32 + c4) = r;
        }
    } else if (blockIdx.x < 2048) {
        // ---- E -> ET16[kk][j] bf16 transposed ----
        ushortT* Tz = (ushortT*)shf;   // [64][66]
        const int bid = blockIdx.x - 1024;
        const int jt = bid >> 2, kt = bid & 3;
        const int j0 = jt * 64, kk0 = kt * 64;
        for (int i = tid; i < 64*16; i += 256) {
            int row = i >> 4, s4 = (i & 15) << 2;
            float4 e4 = ld4(&E[(long)(j0 + row)*256 + kk0 + s4]);
            Tz[(s4 + 0)*66 + row] = bf1(e4.x);
            Tz[(s4 + 1)*66 + row] = bf1(e4.y);
            Tz[(s4 + 2)*66 + row] = bf1(e4.z);
            Tz[(s4 + 3)*66 + row] = bf1(e4.w);
        }
        __syncthreads();
        unsigned int* Tu = (unsigned int*)Tz;
        for (int i = tid; i < 64*32; i += 256) {
            int kk = i >> 5, s = i & 31;
            ((unsigned int*)ET)[(((long)(kk0 + kk) << 14) + j0 >> 1) + s] = Tu[kk*33 + s];
        }
    } else {
        int i = (blockIdx.x - 2048)*256 + tid;
        if (i < 27648) {
            int n = i / 96, k = i % 96;
            wqT[n*96 + k] = bf1(Wq[k*288 + n]);
        } else if (i < 36864) {
            int j = i - 27648;
            int n = j / 96, k = j % 96;
            w0T[n*96 + k] = bf1(W0[k*96 + n]);
        } else if (i < 46080) {
            int j = i - 36864;
            w1c[j] = bf1(w1[j]);
        }
    }
}

// ======= K_MID: blocks [0,512) = qkv MFMA; [512,1536) = dw7 (bf16 a2) =======
__global__ __launch_bounds__(256) void k_mid(const float* __restrict__ x,
        const ushortT* __restrict__ wqT, ushortT* __restrict__ qkv16,
        const float* __restrict__ a1, const float* __restrict__ cspw,
        const float* __restrict__ cspb, ushortT* __restrict__ a2_16) {
    __shared__ __align__(16) float shm[4704];   // 18816B union
    const int tid = threadIdx.x;
    if (blockIdx.x < 512) {
        // ---- qkv16 = bf16(x @ Wqkv) via MFMA ----
        ushortT* xb = (ushortT*)shm;   // [64][104]
        const int r0w = blockIdx.x * 64;
        for (int i = tid; i < 64*48; i += 256) {
            int r = i / 48, cp = i % 48;
            const float* sp = x + (long)(r0w + r)*96 + cp*2;
            ((unsigned int*)xb)[r*52 + cp] = pk2(sp[0], sp[1]);
        }
        __syncthreads();
        const int lane = tid & 63, wv = tid >> 6;
        const int l15 = lane & 15, l4 = lane >> 4;
        short8v bx[3];
#pragma unroll
        for (int kt = 0; kt < 3; ++kt)
            bx[kt] = *(const short8v*)((const short*)xb + (wv*16 + l15)*104 + kt*32 + l4*8);
#pragma unroll 2
        for (int mt = 0; mt < 18; ++mt) {
            f32x4 acc = {0.f, 0.f, 0.f, 0.f};
#pragma unroll
            for (int kt = 0; kt < 3; ++kt) {
                short8v a = *(const short8v*)((const short*)wqT + (mt*16 + l15)*96 + kt*32 + l4*8);
                acc = __builtin_amdgcn_mfma_f32_16x16x32_bf16(a, bx[kt], acc, 0, 0, 0);
            }
            unsigned int* q32 = (unsigned int*)(qkv16 + (long)(r0w + wv*16 + l15)*288 + mt*16 + l4*4);
            q32[0] = pk2(acc[0], acc[1]);
            q32[1] = pk2(acc[2], acc[3]);
        }
    } else {
        // ---- dw7: depthwise 7x7 dil 3 pad 9, reads fp32 a1, writes bf16 a2 ----
        float* wl = shm;   // [49][96]
        for (int i = tid; i < 49*96; i += 256) {
            int c = i / 49, t = i % 49;
            wl[t*96 + c] = cspw[i];
        }
        __syncthreads();
        const int c4 = (tid & 7)*4;
        const int px = tid >> 3;
        const int pix0 = (blockIdx.x - 512) * 32;
        const int b = pix0 >> 14;
        const int y = (pix0 & 16383) >> 7;
        const int xx = (pix0 & 127) + px;
        float4 acc[3];
#pragma unroll
        for (int ch = 0; ch < 3; ++ch) { acc[ch].x=0.f; acc[ch].y=0.f; acc[ch].z=0.f; acc[ch].w=0.f; }
#pragma unroll
        for (int iy = 0; iy < 7; ++iy) {
            int y2 = y + iy*3 - 9;
            if (y2 < 0 || y2 >= HH_) continue;
#pragma unroll
            for (int ix = 0; ix < 7; ++ix) {
                int x2 = xx + ix*3 - 9;
                if (x2 < 0 || x2 >= WW_) continue;
                const float* src = a1 + ((b << 14) + y2*WW_ + x2)*96;
                const float* wt = &wl[(iy*7 + ix)*96];
#pragma unroll
                for (int ch = 0; ch < 3; ++ch) {
                    float4 xv = ld4(src + ch*32 + c4);
                    float4 wv = ld4(wt + ch*32 + c4);
                    acc[ch].x = fmaf(xv.x, wv.x, acc[ch].x);
                    acc[ch].y = fmaf(xv.y, wv.y, acc[ch].y);
                    acc[ch].z = fmaf(xv.z, wv.z, acc[ch].z);
                    acc[ch].w = fmaf(xv.w, wv.w, acc[ch].w);
                }
            }
        }
        ushortT* dst = a2_16 + (long)(pix0 + px)*96;
#pragma unroll
        for (int ch = 0; ch < 3; ++ch) {
            float4 bv = ld4(cspb + ch*32 + c4);
            unsigned int* d32 = (unsigned int*)(dst + ch*32 + c4);
            d32[0] = pk2(acc[ch].x + bv.x, acc[ch].y + bv.y);
            d32[1] = pk2(acc[ch].z + bv.z, acc[ch].w + bv.w);
        }
    }
}

// ------- K2c: fused a3 = a2@w1^T + b1 (MFMA); vf = x*a3*v; writes BOTH halves
// of XT[b][cc 192][j] (cc<96 = k transposed, cc>=96 = vf transposed). 64 rows/blk -------
__global__ __launch_bounds__(256) void k_pw_gate(const ushortT* __restrict__ a2_16,
        const ushortT* __restrict__ w1c, const float* __restrict__ b1,
        const float* __restrict__ xin, const ushortT* __restrict__ qkv16,
        ushortT* __restrict__ XT) {
    __shared__ ushortT ab[64*104];     // 13312B
    __shared__ ushortT ktile[96*66];   // 12672B
    __shared__ ushortT vtile[96*66];   // 12672B
    const int tid = threadIdx.x;
    const int r0 = blockIdx.x * 64;
    const int b = r0 >> 14, j0 = r0 & 16383;
    const unsigned int* a2u = (const unsigned int*)a2_16;
    for (int i = tid; i < 64*48; i += 256) {
        int r = i / 48, cp = i % 48;
        ((unsigned int*)ab)[r*52 + cp] = a2u[(long)(r0 + r)*48 + cp];
    }
    const unsigned int* q32 = (const unsigned int*)qkv16;
    for (int i = tid; i < 64*48; i += 256) {
        int row = i / 48, cp = i % 48;
        unsigned int kk2 = q32[(long)(r0 + row)*144 + 48 + cp];
        ktile[(2*cp + 0)*66 + row] = (ushortT)(kk2 & 0xFFFF);
        ktile[(2*cp + 1)*66 + row] = (ushortT)(kk2 >> 16);
    }
    __syncthreads();
    const int lane = tid & 63, wv = tid >> 6;
    const int l15 = lane & 15, l4 = lane >> 4;
    const int row = r0 + wv*16 + l15;
    const int jloc = wv*16 + l15;
    short8v bx[3];
#pragma unroll
    for (int kt = 0; kt < 3; ++kt)
        bx[kt] = *(const short8v*)((const short*)ab + (wv*16 + l15)*104 + kt*32 + l4*8);
#pragma unroll
    for (int mt = 0; mt < 6; ++mt) {
        f32x4 acc = {0.f, 0.f, 0.f, 0.f};
#pragma unroll
        for (int kt = 0; kt < 3; ++kt) {
            short8v a = *(const short8v*)((const short*)w1c + (mt*16 + l15)*96 + kt*32 + l4*8);
            acc = __builtin_amdgcn_mfma_f32_16x16x32_bf16(a, bx[kt], acc, 0, 0, 0);
        }
        const int c0 = mt*16 + l4*4;
        float4 b4 = ld4(&b1[c0]);
        float4 x4 = ld4(&xin[(long)row*96 + c0]);
        uint2 vv = *reinterpret_cast<const uint2*>(qkv16 + (long)row*288 + 192 + c0);
        float v0 = ubf((ushortT)(vv.x & 0xFFFF)), v1 = ubf((ushortT)(vv.x >> 16));
        float v2 = ubf((ushortT)(vv.y & 0xFFFF)), v3 = ubf((ushortT)(vv.y >> 16));
        vtile[(c0 + 0)*66 + jloc] = bf1(x4.x * v0 * (acc[0] + b4.x));
        vtile[(c0 + 1)*66 + jloc] = bf1(x4.y * v1 * (acc[1] + b4.y));
        vtile[(c0 + 2)*66 + jloc] = bf1(x4.z * v2 * (acc[2] + b4.z));
        vtile[(c0 + 3)*66 + jloc] = bf1(x4.w * v3 * (acc[3] + b4.w));
    }
    __syncthreads();
    unsigned int* XTu = (unsigned int*)XT;
    unsigned int* ku = (unsigned int*)ktile;
    unsigned int* vu = (unsigned int*)vtile;
    for (int i = tid; i < 96*32; i += 256) {
        int cc = i >> 5, s = i & 31;
        XTu[((((long)b*192 + cc) << 14) + j0 >> 1) + s] = ku[cc*33 + s];
    }
    for (int i = tid; i < 96*32; i += 256) {
        int cc = i >> 5, s = i & 31;
        XTu[((((long)b*192 + 96 + cc) << 14) + j0 >> 1) + s] = vu[cc*33 + s];
    }
}

// ------- K3a: E-reduction as MFMA split-K GEMM (no LDS) -------
__global__ __launch_bounds__(512, 2) void k_ered(const ushortT* __restrict__ ET,
        const ushortT* __restrict__ XT, ushortT* __restrict__ part16) {
    const int tid = threadIdx.x;
    const int lane = tid & 63, wv = tid >> 6;
    const int l15 = lane & 15, l4 = lane >> 4;
    const int mtg = wv & 3, nth = wv >> 2;
    const int b  = blockIdx.x >> 7;
    const int jc = blockIdx.x & 127;
    const int j0 = jc * 128;
    f32x4 acc[4][6];
#pragma unroll
    for (int mi = 0; mi < 4; ++mi)
#pragma unroll
        for (int ni = 0; ni < 6; ++ni)
            acc[mi][ni] = (f32x4){0.f, 0.f, 0.f, 0.f};
    const ushortT* Ab = ET + ((long)(mtg*64 + l15) << 14) + j0 + l4*8;
    const ushortT* Bb = XT + (((long)b*192 + nth*96 + l15) << 14) + j0 + l4*8;
#pragma unroll
    for (int ks = 0; ks < 4; ++ks) {
        short8v a[4], bx[6];
#pragma unroll
        for (int mi = 0; mi < 4; ++mi)
            a[mi] = *(const short8v*)(Ab + ((long)mi << 18) + ks*32);
#pragma unroll
        for (int ni = 0; ni < 6; ++ni)
            bx[ni] = *(const short8v*)(Bb + ((long)ni << 18) + ks*32);
#pragma unroll
        for (int mi = 0; mi < 4; ++mi)
#pragma unroll
            for (int ni = 0; ni < 6; ++ni)
                acc[mi][ni] = __builtin_amdgcn_mfma_f32_16x16x32_bf16(a[mi], bx[ni], acc[mi][ni], 0, 0, 0);
    }
    const long base = (long)(b*128 + jc)*49152;
#pragma unroll
    for (int mi = 0; mi < 4; ++mi) {
        int kkb = (mtg*4 + mi)*16 + l4*4;
#pragma unroll
        for (int ni = 0; ni < 6; ++ni) {
            int cc = (nth*6 + ni)*16 + l15;
#pragma unroll
            for (int r = 0; r < 4; ++r)
                part16[base + (long)(kkb + r)*192 + cc] = bf1(acc[mi][ni][r]);
        }
    }
}

// ------- K3b: reduce partials -> bf16 kp16[b][h][kk][16] (scaled by 1/sqrt(12)*log2e,
// pads 0), vp16[b][h][16][256] (row 12 = ONES for MFMA row-sum, 13..15 = 0) -------
__global__ __launch_bounds__(256) void k_ered_fin(const ushortT* __restrict__ part16,
        ushortT* __restrict__ kp16, ushortT* __restrict__ vp16) {
    const int idx = blockIdx.x*256 + threadIdx.x;  // 2*2*256*96 = 98304
    const int c  = idx % 96;
    const int kk = (idx / 96) % 256;
    const int m  = (idx / (96*256)) % 2;
    const int b  = idx / (96*256*2);
    float s = 0.f;
    long off = ((long)(b*128)*256 + kk)*192 + m*96 + c;
    for (int jc = 0; jc < 128; ++jc) {
        s += ubf(part16[off]);
        off += 49152;
    }
    const int h = c / DHD, d = c % DHD;
    if (m == 0) {
        kp16[((b*NH + h)*256 + kk)*16 + d] = bf1(s * 0.4164701998f);
        if (d < 4) kp16[((b*NH + h)*256 + kk)*16 + 12 + d] = 0;
    } else {
        vp16[((b*NH + h)*16 + d)*256 + kk] = bf1(s);
        if (d < 4)
            vp16[((b*NH + h)*16 + 12 + d)*256 + kk] = (d == 0) ? (ushortT)0x3F80 : (ushortT)0;
    }
}

// ------- K4 v3: flash-style. Block = 64 rows x ONE head; kp/vp staged in LDS -------
__global__ __launch_bounds__(256, 4) void k_attn(const ushortT* __restrict__ qkv16,
        const ushortT* __restrict__ kp16, const ushortT* __restrict__ vp16,
        ushortT* __restrict__ obuf) {
    __shared__ ushortT lds[24720];
    const int tid = threadIdx.x;
    const int lane = tid & 63, wv = tid >> 6;
    const int l15 = lane & 15, l4 = lane >> 4;
    const int bid = blockIdx.x;
    const int r0 = (bid >> 3) * 64;
    const int h = bid & 7;
    const int b = r0 >> 14;
    {
        const uint4* ksrc = (const uint4*)(kp16 + ((long)(b*NH + h) << 12));
        uint4* kdst = (uint4*)lds;
        kdst[tid] = ksrc[tid];
        kdst[256 + tid] = ksrc[256 + tid];
        const uint4* vsrc = (const uint4*)(vp16 + ((long)(b*NH + h) << 12));
        uint4* vdst = (uint4*)(lds + 4112);
        int r1 = tid >> 5, s1 = tid & 31;
        vdst[r1*33 + s1] = vsrc[tid];
        int j2 = tid + 256;
        int r2 = j2 >> 5, s2 = j2 & 31;
        vdst[r2*33 + s2] = vsrc[j2];
        if (tid < 2) ((uint4*)(lds + 4096))[tid] = (uint4){0u, 0u, 0u, 0u};
    }
    __syncthreads();
    ushortT* Pw = lds + 8336 + wv*4096;
    unsigned int* Pu = (unsigned int*)Pw;
    const int wbase = (l4 >> 1)*64 + l15*4 + (l4 & 1)*2;
    const f32x4 z = {0.f, 0.f, 0.f, 0.f};
    const int row0 = r0 + wv*16;
    short8v bq = {0, 0, 0, 0, 0, 0, 0, 0};
    {
        unsigned int* bq32 = (unsigned int*)&bq;
        const ushortT* qp = qkv16 + (long)(row0 + l15)*288 + h*12;
        if (l4 == 0) {
            uint2 t0 = *reinterpret_cast<const uint2*>(qp);
            uint2 t1 = *reinterpret_cast<const uint2*>(qp + 4);
            bq32[0] = t0.x; bq32[1] = t0.y; bq32[2] = t1.x; bq32[3] = t1.y;
        } else if (l4 == 1) {
            uint2 t0 = *reinterpret_cast<const uint2*>(qp + 8);
            bq32[0] = t0.x; bq32[1] = t0.y;
        }
    }
    const ushortT* kpl = lds + l15*16 + l4*8;
#pragma unroll
    for (int mt = 0; mt < 16; ++mt) {
        short8v a = *(const short8v*)(kpl + mt*256);
        f32x4 s = __builtin_amdgcn_mfma_f32_16x16x32_bf16(a, bq, z, 0, 0, 0);
        unsigned int* dst = Pu + (mt >> 1)*256 + (mt & 1)*128 + wbase;
        dst[0] = cvtpk(exp2f(s[0]), exp2f(s[1]));
        dst[1] = cvtpk(exp2f(s[2]), exp2f(s[3]));
    }
    f32x4 o = z;
    const ushortT* vpl = lds + 4112 + l15*264 + l4*8;
#pragma unroll
    for (int ks = 0; ks < 8; ++ks) {
        short8v bp = *(const short8v*)(Pw + ks*512 + l4*128 + l15*8);
        short8v av = *(const short8v*)(vpl + ks*32);
        o = __builtin_amdgcn_mfma_f32_16x16x32_bf16(av, bp, o, 0, 0, 0);
    }
    float rinv = 1.0f / __shfl(o[0], 48 + l15, 64);
    if (l4 < 3) {
        unsigned int* od = (unsigned int*)(obuf + (long)(row0 + l15)*96 + h*12 + l4*4);
        od[0] = cvtpk(o[0]*rinv, o[1]*rinv);
        od[1] = cvtpk(o[2]*rinv, o[3]*rinv);
    }
}

// ------- K5: out = o @ W0 via MFMA (W0^T bf16 frags from global) -------
__global__ __launch_bounds__(256) void k_out(const ushortT* __restrict__ obuf,
        const ushortT* __restrict__ w0T, float* __restrict__ out) {
    __shared__ ushortT ol[64*104];
    const int tid = threadIdx.x;
    const int r0 = blockIdx.x * 64;
    for (int i = tid; i < 768; i += 256) {
        int r = i / 12, sg = i % 12;
        *reinterpret_cast<uint4*>(&ol[r*104 + sg*8]) =
            *reinterpret_cast<const uint4*>(&obuf[(long)(r0 + r)*96 + sg*8]);
    }
    __syncthreads();
    const int lane = tid & 63, wv = tid >> 6;
    const int l15 = lane & 15, l4 = lane >> 4;
    short8v a[3];
#pragma unroll
    for (int kt = 0; kt < 3; ++kt)
        a[kt] = *(const short8v*)((const short*)ol + (wv*16 + l15)*104 + kt*32 + l4*8);
#pragma unroll
    for (int nt = 0; nt < 6; ++nt) {
        f32x4 acc = {0.f, 0.f, 0.f, 0.f};
#pragma unroll
        for (int kt = 0; kt < 3; ++kt) {
            short8v bw = *(const short8v*)((const short*)w0T + (nt*16 + l15)*96 + kt*32 + l4*8);
            acc = __builtin_amdgcn_mfma_f32_16x16x32_bf16(a[kt], bw, acc, 0, 0, 0);
        }
#pragma unroll
        for (int r = 0; r < 4; ++r)
            out[(long)(r0 + wv*16 + l4*4 + r)*96 + nt*16 + l15] = acc[r];
    }
}

extern "C" void kernel_launch(void* const* d_in, const int* in_sizes, int n_in,
                              void* d_out, int out_size, void* d_ws, size_t ws_size,
                              hipStream_t stream) {
    (void)in_sizes; (void)n_in; (void)out_size; (void)ws_size;
    const float* x    = (const float*)d_in[0];
    const float* Wqkv = (const float*)d_in[1];
    const float* W0   = (const float*)d_in[2];
    const float* E    = (const float*)d_in[3];
    const float* c0w  = (const float*)d_in[4];
    const float* c0b  = (const float*)d_in[5];
    const float* cspw = (const float*)d_in[6];
    const float* cspb = (const float*)d_in[7];
    const float* c1w  = (const float*)d_in[8];
    const float* c1b  = (const float*)d_in[9];
    float* out = (float*)d_out;
    float* ws  = (float*)d_ws;

    ushortT* qkv16  = (ushortT*)ws;
    ushortT* wqT16  = (ushortT*)(ws + 4718592);
    ushortT* w0T16  = (ushortT*)(ws + 4732416);
    ushortT* w1c16  = (ushortT*)(ws + 4737024);
    ushortT* ET16   = (ushortT*)(ws + 4741632);
    ushortT* XT16   = (ushortT*)(ws + 6838784);
    float* a1       = ws + 9984512;
    ushortT* a2_16  = (ushortT*)(ws + 13130240);
    ushortT* part16 = (ushortT*)(ws + 9984512);
    ushortT* obuf   = (ushortT*)(ws + 9984512);
    ushortT* kp16   = (ushortT*)(ws + 16275968);
    ushortT* vp16   = (ushortT*)(ws + 16308736);

    k_front<<<dim3(2228), dim3(256), 0, stream>>>(x, c0w, c0b, E, Wqkv, W0, c1w,
                                                  a1, ET16, wqT16, w0T16, w1c16);
    k_mid<<<dim3(1536), dim3(256), 0, stream>>>(x, wqT16, qkv16, a1, cspw, cspb, a2_16);
    k_pw_gate<<<dim3(NROW/64), dim3(256), 0, stream>>>(a2_16, w1c16, c1b, x, qkv16, XT16);
    k_ered<<<dim3(256), dim3(512), 0, stream>>>(ET16, XT16, part16);
    k_ered_fin<<<dim3(384), dim3(256), 0, stream>>>(part16, kp16, vp16);
    k_attn<<<dim3((NROW/64)*NH), dim3(256), 0, stream>>>(qkv16, kp16, vp16, obuf);
    k_out<<<dim3(NROW/64), dim3(256), 0, stream>>>(obuf, w0T16, out);
}